// Round 9
// baseline (806.847 us; speedup 1.0000x reference)
//
#include <hip/hip_runtime.h>

typedef __attribute__((ext_vector_type(4))) float f32x4;
typedef __attribute__((ext_vector_type(8))) short s16x8;

#define DEVI __device__ __forceinline__

DEVI float b2f(short s) {
  union { float f; unsigned u; } v; v.u = ((unsigned)(unsigned short)s) << 16; return v.f;
}
DEVI short f2b(float f) {
  union { float f; unsigned u; } v; v.f = f;
  unsigned u = v.u;
  u += 0x7FFFu + ((u >> 16) & 1u);   // RNE
  return (short)(u >> 16);
}
// fast GELU: tanh form, exp-based; overflow-safe. err ~4e-4 max, ~1e-5 here.
DEVI float gelu_f(float x) {
  float z2 = 1.5957691216f * x * (1.0f + 0.044715f * x * x);
  float e = __expf(z2);
  float th = 1.0f - 2.0f / (e + 1.0f);
  return 0.5f * x * (1.0f + th);
}
DEVI float sigm_f(float x) { return 1.0f / (1.0f + expf(-x)); }

// async global->LDS, 16B per lane; LDS dest = wave-uniform base + lane*16
DEVI void gld16(const short* g, const short* l) {
  __builtin_amdgcn_global_load_lds((const __attribute__((address_space(1))) void*)g,
                                   (__attribute__((address_space(3))) void*)l, 16, 0, 0);
}

// ---------------------------------------------------------------------------
// BM=256 bf16 GEMM: C[256,N] = A[256,K] * B[N,K]^T (+bias). 512 thr, 8 waves
// (4m x 2n), BK=32. Grid (N/128, 1, batch).
// ---------------------------------------------------------------------------
template<bool BIAS, bool OUT_BF16>
__global__ __launch_bounds__(512)
void gemm256_k(const short* __restrict__ A, const short* __restrict__ B,
               const float* __restrict__ bias, void* __restrict__ Cv,
               int N, int K,
               long long sA, long long sB, long long sC)
{
  __shared__ short As[2][256 * 32];
  __shared__ short Bs[2][128 * 32];
  const int bz = blockIdx.z;
  const int n0 = blockIdx.x * 128;
  const int t = threadIdx.x, lane = t & 63, wave = t >> 6;
  const int wm = wave >> 1, wn = wave & 1;
  const short* Ab = A + bz * sA;
  const short* Bb = B + bz * sB;
  const int lr = lane >> 2;
  const int lc = (lane & 3) * 8;
  const int fr = lane & 15, fs = lane >> 4;

  f32x4 acc[4][4];
#pragma unroll
  for (int i = 0; i < 4; ++i)
#pragma unroll
    for (int j = 0; j < 4; ++j) acc[i][j] = f32x4{0.f, 0.f, 0.f, 0.f};

  auto stage = [&](int b, int k0) {
#pragma unroll
    for (int q = 0; q < 2; ++q)
      gld16(Ab + (long long)(q * 128 + wave * 16 + lr) * K + k0 + lc,
            &As[b][(q * 128 + wave * 16) * 32]);
    gld16(Bb + (long long)(n0 + wave * 16 + lr) * K + k0 + lc,
          &Bs[b][wave * 16 * 32]);
  };

  const int NT = K >> 5;
  stage(0, 0);
  __syncthreads();
  for (int tt = 0; tt < NT; ++tt) {
    const int cur = tt & 1;
    if (tt + 1 < NT) stage(cur ^ 1, (tt + 1) << 5);
    s16x8 af[4], bfv[4];
#pragma unroll
    for (int i = 0; i < 4; ++i) af[i]  = *(const s16x8*)&As[cur][(wm * 64 + i * 16 + fr) * 32 + fs * 8];
#pragma unroll
    for (int j = 0; j < 4; ++j) bfv[j] = *(const s16x8*)&Bs[cur][(wn * 64 + j * 16 + fr) * 32 + fs * 8];
#pragma unroll
    for (int i = 0; i < 4; ++i)
#pragma unroll
      for (int j = 0; j < 4; ++j)
        acc[i][j] = __builtin_amdgcn_mfma_f32_16x16x32_bf16(af[i], bfv[j], acc[i][j], 0, 0, 0);
    if (tt + 1 < NT) __syncthreads();
  }

#pragma unroll
  for (int i = 0; i < 4; ++i) {
    int rowb = wm * 64 + i * 16 + fs * 4;
#pragma unroll
    for (int j = 0; j < 4; ++j) {
      int col = n0 + wn * 64 + j * 16 + fr;
      float bb = BIAS ? bias[col] : 0.0f;
#pragma unroll
      for (int u = 0; u < 4; ++u) {
        float v = acc[i][j][u] + bb;
        long long off = bz * sC + (long long)(rowb + u) * N + col;
        if constexpr (OUT_BF16) ((short*)Cv)[off] = f2b(v);
        else                    ((float*)Cv)[off] = v;
      }
    }
  }
}

// ---------------------------------------------------------------------------
// Fused h1+logits, BM=256 full-N (unchanged from R8).
// ---------------------------------------------------------------------------
__global__ __launch_bounds__(512)
void h1log256_k(const short* __restrict__ inter, const short* __restrict__ Wc1b,
                const float* __restrict__ bc1, const float* __restrict__ Wc2,
                const float* __restrict__ bc2, float* __restrict__ outp)
{
  __shared__ short As[2][256 * 32];
  __shared__ short Bs[2][128 * 32];
  __shared__ float part[256][2];
  const int ib = blockIdx.x;
  const int t = threadIdx.x, lane = t & 63, wave = t >> 6;
  const int wm = wave >> 1, wn = wave & 1;
  const short* Ab = inter + (long long)ib * 98304;
  const int lr = lane >> 2;
  const int lc = (lane & 3) * 8;
  const int fr = lane & 15, fs = lane >> 4;

  float lp[16];
#pragma unroll
  for (int e = 0; e < 16; ++e) lp[e] = 0.f;

  for (int n0 = 0; n0 < 384; n0 += 128) {
    f32x4 acc[4][4];
#pragma unroll
    for (int i = 0; i < 4; ++i)
#pragma unroll
      for (int j = 0; j < 4; ++j) acc[i][j] = f32x4{0.f, 0.f, 0.f, 0.f};

    auto stage = [&](int b, int k0) {
#pragma unroll
      for (int q = 0; q < 2; ++q)
        gld16(Ab + (long long)(q * 128 + wave * 16 + lr) * 384 + k0 + lc,
              &As[b][(q * 128 + wave * 16) * 32]);
      gld16(Wc1b + (long long)(n0 + wave * 16 + lr) * 384 + k0 + lc,
            &Bs[b][wave * 16 * 32]);
    };

    stage(0, 0);
    __syncthreads();
    for (int tt = 0; tt < 12; ++tt) {
      const int cur = tt & 1;
      if (tt + 1 < 12) stage(cur ^ 1, (tt + 1) << 5);
      s16x8 af[4], bfv[4];
#pragma unroll
      for (int i = 0; i < 4; ++i) af[i]  = *(const s16x8*)&As[cur][(wm * 64 + i * 16 + fr) * 32 + fs * 8];
#pragma unroll
      for (int j = 0; j < 4; ++j) bfv[j] = *(const s16x8*)&Bs[cur][(wn * 64 + j * 16 + fr) * 32 + fs * 8];
#pragma unroll
      for (int i = 0; i < 4; ++i)
#pragma unroll
        for (int j = 0; j < 4; ++j)
          acc[i][j] = __builtin_amdgcn_mfma_f32_16x16x32_bf16(af[i], bfv[j], acc[i][j], 0, 0, 0);
      if (tt + 1 < 12) __syncthreads();
    }
#pragma unroll
    for (int i = 0; i < 4; ++i)
#pragma unroll
      for (int j = 0; j < 4; ++j) {
        int col = n0 + wn * 64 + j * 16 + fr;
        float w2 = Wc2[col], b1v = bc1[col];
#pragma unroll
        for (int u = 0; u < 4; ++u)
          lp[i * 4 + u] += gelu_f(acc[i][j][u] + b1v) * w2;
      }
    __syncthreads();
  }
#pragma unroll
  for (int m = 1; m < 16; m <<= 1)
#pragma unroll
    for (int e = 0; e < 16; ++e) lp[e] += __shfl_xor(lp[e], m);
  if (fr == 0) {
#pragma unroll
    for (int e = 0; e < 16; ++e)
      part[wm * 64 + (e >> 2) * 16 + fs * 4 + (e & 3)][wn] = lp[e];
  }
  __syncthreads();
  if (t < 256) outp[ib * 256 + t] = sigm_f(part[t][0] + part[t][1] + bc2[0]);
}

// ---------------------------------------------------------------------------
// Fused GEMM + residual + LayerNorm. Blocks own COMPLETE rows:
// BM=32, BN=384(all), grid=8, 512 thr (8 waves: 2m x 4n, wave tile 16x96).
// delta = A@B^T + bias; u = x + delta; x = LN(u)*g + be  -> x fp32, xb bf16.
// LDS: staging (A 4KB + B 48KB) overlaid by u[32][385] f32 after compute.
// ---------------------------------------------------------------------------
__global__ __launch_bounds__(512)
void gemmln_k(const short* __restrict__ A, const short* __restrict__ B,
              const float* __restrict__ bias,
              const float* __restrict__ xin, float* __restrict__ xout,
              short* __restrict__ xbout,
              const float* __restrict__ g, const float* __restrict__ be,
              int K)
{
  __shared__ __align__(16) char ldsbuf[53248];
  short* As0 = (short*)ldsbuf;            // [2][32*32]   4 KB
  short* Bs0 = (short*)(ldsbuf + 4096);   // [2][384*32]  48 KB
  float (*u)[385] = (float(*)[385])ldsbuf; // overlaid: 32*385*4 = 49280 B

  const int m0 = blockIdx.x * 32;
  const int t = threadIdx.x, lane = t & 63, wave = t >> 6;
  const int wm = wave >> 2, wn = wave & 3;      // 2m x 4n
  const int lr = lane >> 2;
  const int lc = (lane & 3) * 8;
  const int fr = lane & 15, fs = lane >> 4;

  f32x4 acc[6];
#pragma unroll
  for (int j = 0; j < 6; ++j) acc[j] = f32x4{0.f, 0.f, 0.f, 0.f};

  auto stage = [&](int b, int k0) {
#pragma unroll
    for (int q = 0; q < 3; ++q)
      gld16(B + (long long)(wave * 48 + q * 16 + lr) * K + k0 + lc,
            &Bs0[b * 12288 + (wave * 48 + q * 16) * 32]);
    if (wave < 2)
      gld16(A + (long long)(m0 + wave * 16 + lr) * K + k0 + lc,
            &As0[b * 1024 + wave * 16 * 32]);
  };

  const int NT = K >> 5;
  stage(0, 0);
  __syncthreads();
  for (int tt = 0; tt < NT; ++tt) {
    const int cur = tt & 1;
    if (tt + 1 < NT) stage(cur ^ 1, (tt + 1) << 5);
    s16x8 af = *(const s16x8*)&As0[cur * 1024 + (wm * 16 + fr) * 32 + fs * 8];
    s16x8 bfv[6];
#pragma unroll
    for (int j = 0; j < 6; ++j)
      bfv[j] = *(const s16x8*)&Bs0[cur * 12288 + (wn * 96 + j * 16 + fr) * 32 + fs * 8];
#pragma unroll
    for (int j = 0; j < 6; ++j)
      acc[j] = __builtin_amdgcn_mfma_f32_16x16x32_bf16(af, bfv[j], acc[j], 0, 0, 0);
    __syncthreads();   // all waves done reading before restage/overlay
  }

  // write delta + bias into overlaid u  (staging reads all drained above)
#pragma unroll
  for (int j = 0; j < 6; ++j) {
    int col = wn * 96 + j * 16 + fr;
    float bb = bias[col];
#pragma unroll
    for (int q = 0; q < 4; ++q)
      u[wm * 16 + fs * 4 + q][col] = acc[j][q] + bb;
  }
  __syncthreads();

  // LN: 16 threads per row, 24 cols each
  const int r = t >> 4, c16 = t & 15;
  const float* xr = xin + (long long)(m0 + r) * 384;
  float ru[24]; float s = 0.f, ss = 0.f;
#pragma unroll
  for (int e = 0; e < 24; ++e) {
    int col = c16 + 16 * e;
    float uv = u[r][col] + xr[col];
    ru[e] = uv; s += uv; ss += uv * uv;
  }
#pragma unroll
  for (int m = 1; m < 16; m <<= 1) { s += __shfl_xor(s, m); ss += __shfl_xor(ss, m); }
  float mean = s * (1.f / 384.f);
  float var  = ss * (1.f / 384.f) - mean * mean;
  float rstd = rsqrtf(var + 1e-5f);
  float* xo  = xout  + (long long)(m0 + r) * 384;
  short* xbo = xbout + (long long)(m0 + r) * 384;
#pragma unroll
  for (int e = 0; e < 24; ++e) {
    int col = c16 + 16 * e;
    float y = (ru[e] - mean) * rstd * g[col] + be[col];
    xo[col] = y; xbo[col] = f2b(y);
  }
}

// ---------------------------------------------------------------------------
// 64x64-tile bf16 GEMM, BK=32, 2-phase (qkv / ff1 / final GEMMs).
// ---------------------------------------------------------------------------
template<bool BIAS, bool GELU_ACT, bool OUT_BF16>
__global__ __launch_bounds__(256)
void gemm64_k(const short* __restrict__ A, const short* __restrict__ B,
              const float* __restrict__ bias, void* __restrict__ Cv,
              int M, int N, int K)
{
  __shared__ short As[2][64 * 32];
  __shared__ short Bs[2][64 * 32];
  const int n0 = blockIdx.x * 64;
  const int m0 = blockIdx.y * 64;
  const int t = threadIdx.x, lane = t & 63, wave = t >> 6;
  const int wm = wave >> 1, wn = wave & 1;
  const int srow = lane >> 2;
  const int scol = (lane & 3) * 8;
  const int fr = lane & 15, fs = lane >> 4;

  f32x4 acc[2][2];
#pragma unroll
  for (int i = 0; i < 2; ++i)
#pragma unroll
    for (int j = 0; j < 2; ++j) acc[i][j] = f32x4{0.f, 0.f, 0.f, 0.f};

  auto stage = [&](int b, int k0) {
    gld16(A + (long long)(m0 + wave * 16 + srow) * K + k0 + scol, &As[b][wave * 512]);
    gld16(B + (long long)(n0 + wave * 16 + srow) * K + k0 + scol, &Bs[b][wave * 512]);
  };

  const int NT = K >> 5;
  stage(0, 0);
  __syncthreads();
  for (int tt = 0; tt < NT; ++tt) {
    const int cur = tt & 1;
    if (tt + 1 < NT) stage(cur ^ 1, (tt + 1) << 5);
    s16x8 af[2], bfv[2];
#pragma unroll
    for (int i = 0; i < 2; ++i) af[i]  = *(const s16x8*)&As[cur][(wm * 32 + i * 16 + fr) * 32 + fs * 8];
#pragma unroll
    for (int j = 0; j < 2; ++j) bfv[j] = *(const s16x8*)&Bs[cur][(wn * 32 + j * 16 + fr) * 32 + fs * 8];
#pragma unroll
    for (int i = 0; i < 2; ++i)
#pragma unroll
      for (int j = 0; j < 2; ++j)
        acc[i][j] = __builtin_amdgcn_mfma_f32_16x16x32_bf16(af[i], bfv[j], acc[i][j], 0, 0, 0);
    if (tt + 1 < NT) __syncthreads();
  }

#pragma unroll
  for (int i = 0; i < 2; ++i) {
    int rowb = m0 + wm * 32 + i * 16 + fs * 4;
#pragma unroll
    for (int j = 0; j < 2; ++j) {
      int col = n0 + wn * 32 + j * 16 + fr;
      float bb = BIAS ? bias[col] : 0.0f;
#pragma unroll
      for (int u = 0; u < 4; ++u) {
        float v = acc[i][j][u] + bb;
        if constexpr (GELU_ACT) v = gelu_f(v);
        long long off = (long long)(rowb + u) * N + col;
        if constexpr (OUT_BF16) ((short*)Cv)[off] = f2b(v);
        else                    ((float*)Cv)[off] = v;
      }
    }
  }
}

// ---------------------------------------------------------------------------
// Wbil [o][x][y] fp32  ->  WbilT [o][y][x] bf16   (64x64 tiles via LDS)
// ---------------------------------------------------------------------------
__global__ __launch_bounds__(256)
void transpose_k(const float* __restrict__ W, short* __restrict__ WT)
{
  __shared__ short L[64 * 68];
  const int o  = blockIdx.z;
  const int x0 = blockIdx.x * 64, y0 = blockIdx.y * 64;
  const float* Wo = W  + (long long)o * 147456;
  short*      WTo = WT + (long long)o * 147456;
  const int t  = threadIdx.x;
  const int rr = t >> 4;
  const int cc = (t & 15) * 4;
#pragma unroll
  for (int q = 0; q < 4; ++q) {
    int xl = rr + 16 * q;
    float4 v = *(const float4*)(Wo + (x0 + xl) * 384 + y0 + cc);
    short4 p; p.x = f2b(v.x); p.y = f2b(v.y); p.z = f2b(v.z); p.w = f2b(v.w);
    *(short4*)&L[xl * 68 + cc] = p;
  }
  __syncthreads();
#pragma unroll
  for (int q = 0; q < 4; ++q) {
    int yl = rr + 16 * q;
    short4 p;
    p.x = L[(cc + 0) * 68 + yl];
    p.y = L[(cc + 1) * 68 + yl];
    p.z = L[(cc + 2) * 68 + yl];
    p.w = L[(cc + 3) * 68 + yl];
    *(short4*)(WTo + (y0 + yl) * 384 + x0 + cc) = p;
  }
}

// ---------------------------------------------------------------------------
// Convert ALL layer weights fp32->bf16 in ONE dispatch.
// Segments (elem prefix): Wc1 147456 | Wqkv 884736 | Wo 294912 | W1 1179648
//                        | W2 1179648 | Wout 147456  (total 3833856)
// ---------------------------------------------------------------------------
__global__ __launch_bounds__(256)
void convall_k(const float* __restrict__ Wc1, const float* __restrict__ Wqkv,
               const float* __restrict__ Wo, const float* __restrict__ W1,
               const float* __restrict__ W2, const float* __restrict__ Wout,
               short* __restrict__ Dc1, short* __restrict__ Dqkv,
               short* __restrict__ Do, short* __restrict__ D1,
               short* __restrict__ D2, short* __restrict__ Dout)
{
  long long i4 = ((long long)blockIdx.x * 256 + threadIdx.x) * 4;
  const float* s; short* d; long long off;
  if      (i4 <  147456) { s = Wc1;  d = Dc1;  off = 0; }
  else if (i4 < 1032192) { s = Wqkv; d = Dqkv; off = 147456; }
  else if (i4 < 1327104) { s = Wo;   d = Do;   off = 1032192; }
  else if (i4 < 2506752) { s = W1;   d = D1;   off = 1327104; }
  else if (i4 < 3686400) { s = W2;   d = D2;   off = 2506752; }
  else if (i4 < 3833856) { s = Wout; d = Dout; off = 3686400; }
  else return;
  long long l = i4 - off;
  float4 v = *(const float4*)(s + l);
  short4 p; p.x = f2b(v.x); p.y = f2b(v.y); p.z = f2b(v.z); p.w = f2b(v.w);
  *(short4*)(d + l) = p;
}

// ---------------------------------------------------------------------------
// Attention: qkv fp32 [256][1152] -> out bf16 [256][384]. d=48, NH=8.
// K/V staging vectorized (float4).
// ---------------------------------------------------------------------------
__global__ __launch_bounds__(256)
void attn_k(const float* __restrict__ qkv, short* __restrict__ outb)
{
  __shared__ short Ks[256 * 48];
  __shared__ short Vs[256 * 48];
  __shared__ float Ps[32][258];
  const int h  = blockIdx.y;
  const int q0 = blockIdx.x * 32;
  const int t = threadIdx.x, lane = t & 63, wave = t >> 6;
  for (int idx = t; idx < 3072; idx += 256) {
    int j = idx / 12, d4 = (idx - (idx / 12) * 12) * 4;
    const float* base = qkv + j * 1152 + h * 48 + d4;
    float4 kv = *(const float4*)(base + 384);
    float4 vv = *(const float4*)(base + 768);
    short4 pk; pk.x = f2b(kv.x); pk.y = f2b(kv.y); pk.z = f2b(kv.z); pk.w = f2b(kv.w);
    short4 pv; pv.x = f2b(vv.x); pv.y = f2b(vv.y); pv.z = f2b(vv.z); pv.w = f2b(vv.w);
    *(short4*)&Ks[j * 48 + d4] = pk;
    *(short4*)&Vs[j * 48 + d4] = pv;
  }
  __syncthreads();
  const int part = lane & 7;
  const int rl   = wave * 8 + (lane >> 3);
  const int row  = q0 + rl;
  float q[48];
#pragma unroll
  for (int d = 0; d < 48; ++d) q[d] = qkv[row * 1152 + h * 48 + d] * 0.14433756729740644f;
  float mx = -1e30f;
  for (int jj = 0; jj < 32; ++jj) {
    int j = jj * 8 + part;
    float a = 0.f;
#pragma unroll
    for (int dd = 0; dd < 12; ++dd) {
      short4 kk = *(const short4*)&Ks[j * 48 + dd * 4];
      a += q[dd*4+0]*b2f(kk.x) + q[dd*4+1]*b2f(kk.y) + q[dd*4+2]*b2f(kk.z) + q[dd*4+3]*b2f(kk.w);
    }
    Ps[rl][j] = a;
    mx = fmaxf(mx, a);
  }
  mx = fmaxf(mx, __shfl_xor(mx, 1));
  mx = fmaxf(mx, __shfl_xor(mx, 2));
  mx = fmaxf(mx, __shfl_xor(mx, 4));
  float sum = 0.f;
  for (int jj = 0; jj < 32; ++jj) {
    int j = jj * 8 + part;
    float e = expf(Ps[rl][j] - mx);
    Ps[rl][j] = e;
    sum += e;
  }
  sum += __shfl_xor(sum, 1); sum += __shfl_xor(sum, 2); sum += __shfl_xor(sum, 4);
  const float inv = 1.f / sum;
  __syncthreads();
  float o[6] = {0.f, 0.f, 0.f, 0.f, 0.f, 0.f};
  const int vb = part * 6;
  for (int j = 0; j < 256; ++j) {
    float p = Ps[rl][j];
    int base = j * 48 + vb;
#pragma unroll
    for (int dd = 0; dd < 3; ++dd) {
      short2 vv = *(const short2*)&Vs[base + dd * 2];
      o[dd*2]   += p * b2f(vv.x);
      o[dd*2+1] += p * b2f(vv.y);
    }
  }
#pragma unroll
  for (int d = 0; d < 6; ++d) outb[row * 384 + h * 48 + vb + d] = f2b(o[d] * inv);
}

__global__ void init_k(const float* __restrict__ hs, float* __restrict__ x,
                       short* __restrict__ xb, float* __restrict__ rstate)
{
  int i = blockIdx.x * 256 + threadIdx.x;
  if (i < 98304) { float v = hs[i]; x[i] = v; xb[i] = f2b(v); }
  if (i < 384) rstate[i] = 0.f;
}

// ---------------------------------------------------------------------------
// GRU: pool1 (8 partials) -> gih (wide) -> gru_tail (gates+p1+cont, 1 block)
// ---------------------------------------------------------------------------
__global__ __launch_bounds__(384)
void pool1_k(const float* __restrict__ x, float* __restrict__ partial)
{
  const int t = threadIdx.x, p = blockIdx.x;
  float s = 0.f;
  const float* xr = x + p * 32 * 384;
#pragma unroll 4
  for (int i = 0; i < 32; ++i) s += xr[i * 384 + t];
  partial[p * 384 + t] = s;
}

__global__ __launch_bounds__(256)
void gih_k(const float* __restrict__ Wih, const float* __restrict__ bih,
           const float* __restrict__ Whh, const float* __restrict__ bhh,
           const float* __restrict__ partial, const float* __restrict__ rstate,
           float* __restrict__ gi, float* __restrict__ gh)
{
  const int t = threadIdx.x, lane = t & 63, wave = t >> 6;
  const int r = blockIdx.x * 4 + wave;
  float a = 0.f, b = 0.f;
#pragma unroll
  for (int e = 0; e < 6; ++e) {
    int c = lane + 64 * e;
    float pc = 0.f;
#pragma unroll
    for (int p = 0; p < 8; ++p) pc += partial[p * 384 + c];
    pc *= (1.f / 256.f);
    a += Wih[r * 384 + c] * pc;
    b += Whh[r * 384 + c] * rstate[c];
  }
#pragma unroll
  for (int m = 1; m < 64; m <<= 1) { a += __shfl_xor(a, m); b += __shfl_xor(b, m); }
  if (lane == 0) { gi[r] = a + bih[r]; gh[r] = b + bhh[r]; }
}

__global__ __launch_bounds__(512)
void gru_tail_k(const float* __restrict__ gi, const float* __restrict__ gh,
                float* __restrict__ rstate,
                const float* __restrict__ Wp1, const float* __restrict__ bp1,
                const float* __restrict__ Wp2, const float* __restrict__ bp2,
                float* __restrict__ out_cont)
{
  __shared__ float hnew[384], p1s[384];
  const int t = threadIdx.x, lane = t & 63, wave = t >> 6;
  if (t < 384) {
    float r = sigm_f(gi[t] + gh[t]);
    float z = sigm_f(gi[384 + t] + gh[384 + t]);
    float n = tanhf(gi[768 + t] + r * gh[768 + t]);
    float hh = (1.f - z) * n + z * rstate[t];
    rstate[t] = hh;
    hnew[t] = hh;
  }
  __syncthreads();
  for (int r = wave; r < 384; r += 8) {
    float a = 0.f;
#pragma unroll
    for (int e = 0; e < 6; ++e) { int c = lane + 64 * e; a += Wp1[r * 384 + c] * hnew[c]; }
#pragma unroll
    for (int m = 1; m < 64; m <<= 1) a += __shfl_xor(a, m);
    if (lane == 0) p1s[r] = gelu_f(a + bp1[r]);
  }
  __syncthreads();
  if (wave == 0) {
    float a = 0.f;
#pragma unroll
    for (int e = 0; e < 6; ++e) { int c = lane + 64 * e; a += p1s[c] * Wp2[c]; }
#pragma unroll
    for (int m = 1; m < 64; m <<= 1) a += __shfl_xor(a, m);
    if (lane == 0) out_cont[0] = sigm_f(a + bp2[0]);
  }
}

// ---------------------------------------------------------------------------
extern "C" void kernel_launch(void* const* d_in, const int* in_sizes, int n_in,
                              void* d_out, int out_size, void* d_ws, size_t ws_size,
                              hipStream_t stream)
{
  const float* hs   = (const float*)d_in[0];
  const float* Wqkv = (const float*)d_in[1];
  const float* bqkv = (const float*)d_in[2];
  const float* Wo   = (const float*)d_in[3];
  const float* bo   = (const float*)d_in[4];
  const float* W1   = (const float*)d_in[5];
  const float* b1   = (const float*)d_in[6];
  const float* W2   = (const float*)d_in[7];
  const float* b2   = (const float*)d_in[8];
  const float* g1   = (const float*)d_in[9];
  const float* be1  = (const float*)d_in[10];
  const float* g2   = (const float*)d_in[11];
  const float* be2  = (const float*)d_in[12];
  const float* Wbil = (const float*)d_in[13];
  const float* bbil = (const float*)d_in[14];
  const float* Wc1  = (const float*)d_in[15];
  const float* bc1  = (const float*)d_in[16];
  const float* Wc2  = (const float*)d_in[17];
  const float* bc2  = (const float*)d_in[18];
  const float* Wih  = (const float*)d_in[19];
  const float* bih  = (const float*)d_in[20];
  const float* Whh  = (const float*)d_in[21];
  const float* bhh  = (const float*)d_in[22];
  const float* Wp1  = (const float*)d_in[23];
  const float* bp1  = (const float*)d_in[24];
  const float* Wp2  = (const float*)d_in[25];
  const float* bp2  = (const float*)d_in[26];
  const float* Wout = (const float*)d_in[27];
  const float* bout = (const float*)d_in[28];
  float* out = (float*)d_out;

  char* ws = (char*)d_ws;
  size_t off = 0;
  auto alloc = [&](size_t bytes) -> char* {
    char* p = ws + off; off += (bytes + 255) & ~(size_t)255; return p;
  };
  short* wbilT   = (short*)alloc(56623104ULL * 2);
  short* tmp     = (short*)alloc(256ULL * 147456 * 2);
  short* inter   = (short*)alloc(256ULL * 98304 * 2);
  float* x       = (float*)alloc(98304 * 4);
  short* xb      = (short*)alloc(98304 * 2);
  float* qkv     = (float*)alloc(294912 * 4);
  short* attnb   = (short*)alloc(98304 * 2);
  short* ff1b    = (short*)alloc(393216 * 2);
  float* rstate  = (float*)alloc(384 * 4);
  float* partial = (float*)alloc(8 * 384 * 4);
  float* gi      = (float*)alloc(1152 * 4);
  float* gh      = (float*)alloc(1152 * 4);
  short* wc1b    = (short*)alloc(147456 * 2);
  short* wqkvb   = (short*)alloc(884736ULL * 2);
  short* wob     = (short*)alloc(294912ULL * 2);
  short* w1b     = (short*)alloc(1179648ULL * 2);
  short* w2b     = (short*)alloc(1179648ULL * 2);
  short* woutb   = (short*)alloc(147456 * 2);
  (void)ws_size; (void)in_sizes; (void)n_in; (void)out_size;

  dim3 B256(256);
  dim3 B512(512);

  init_k<<<dim3(384), B256, 0, stream>>>(hs, x, xb, rstate);
  transpose_k<<<dim3(6, 6, 384), B256, 0, stream>>>(Wbil, wbilT);
  convall_k<<<dim3(3744), B256, 0, stream>>>(Wc1, Wqkv, Wo, W1, W2, Wout,
                                             wc1b, wqkvb, wob, w1b, w2b, woutb);

  for (int s = 0; s < 2; ++s) {
    for (int l = 0; l < 2; ++l) {
      gemm64_k<true, false, false><<<dim3(18, 4), B256, 0, stream>>>(
          xb, wqkvb + l * 442368, bqkv + l * 1152, qkv, 256, 1152, 384);
      attn_k<<<dim3(8, 8), B256, 0, stream>>>(qkv, attnb);
      gemmln_k<<<dim3(8), B512, 0, stream>>>(
          attnb, wob + l * 147456, bo + l * 384, x, x, xb,
          g1 + l * 384, be1 + l * 384, 384);
      gemm64_k<true, true, true><<<dim3(24, 4), B256, 0, stream>>>(
          xb, w1b + l * 589824, b1 + l * 1536, ff1b, 256, 1536, 384);
      gemmln_k<<<dim3(8), B512, 0, stream>>>(
          ff1b, w2b + l * 589824, b2 + l * 384, x, x, xb,
          g2 + l * 384, be2 + l * 384, 1536);
    }
    // tmp[i, o*384+y] = sum_x X[i,x] * WbilT[o*384+y, x]   (B read ONCE)
    gemm256_k<false, true><<<dim3(1152, 1, 1), B512, 0, stream>>>(
        xb, wbilT, (const float*)nullptr, tmp, 147456, 384, 0, 0, 0);
    // inter[i][j][o] = sum_y X[j,y] * tmp_i[o,y] + bbil[o]
    gemm256_k<true, true><<<dim3(3, 1, 256), B512, 0, stream>>>(
        xb, tmp, bbil, inter, 384, 384, 0, 147456LL, 98304LL);
    // fused h1 + logits
    h1log256_k<<<dim3(256), B512, 0, stream>>>(inter, wc1b, bc1, Wc2, bc2,
                                               out + 98304 + s * 65536);
    // --- GRU controller ---
    pool1_k<<<dim3(8), dim3(384), 0, stream>>>(x, partial);
    gih_k<<<dim3(288), B256, 0, stream>>>(Wih, bih, Whh, bhh, partial, rstate, gi, gh);
    gru_tail_k<<<dim3(1), B512, 0, stream>>>(gi, gh, rstate, Wp1, bp1, Wp2, bp2,
                                             out + 98304 + 131072 + s);
  }
  gemm64_k<true, false, false><<<dim3(6, 4), B256, 0, stream>>>(
      xb, woutb, bout, out, 256, 384, 384);
}

// Round 10
// 727.870 us; speedup vs baseline: 1.1085x; 1.1085x over previous
//
#include <hip/hip_runtime.h>

typedef __attribute__((ext_vector_type(4))) float f32x4;
typedef __attribute__((ext_vector_type(8))) short s16x8;

#define DEVI __device__ __forceinline__

DEVI float b2f(short s) {
  union { float f; unsigned u; } v; v.u = ((unsigned)(unsigned short)s) << 16; return v.f;
}
DEVI short f2b(float f) {
  union { float f; unsigned u; } v; v.f = f;
  unsigned u = v.u;
  u += 0x7FFFu + ((u >> 16) & 1u);   // RNE
  return (short)(u >> 16);
}
// fast GELU: tanh form, exp-based; overflow-safe. err ~4e-4 max, ~1e-5 here.
DEVI float gelu_f(float x) {
  float z2 = 1.5957691216f * x * (1.0f + 0.044715f * x * x);
  float e = __expf(z2);
  float th = 1.0f - 2.0f / (e + 1.0f);
  return 0.5f * x * (1.0f + th);
}
DEVI float sigm_f(float x) { return 1.0f / (1.0f + expf(-x)); }

// async global->LDS, 16B per lane; LDS dest = wave-uniform base + lane*16
DEVI void gld16(const short* g, const short* l) {
  __builtin_amdgcn_global_load_lds((const __attribute__((address_space(1))) void*)g,
                                   (__attribute__((address_space(3))) void*)l, 16, 0, 0);
}

// ---------------------------------------------------------------------------
// BM=256 bf16 GEMM: C[256,N] = A[256,K] * B[N,K]^T (+bias). 512 thr, 8 waves
// (4m x 2n), BK=32. Grid (N/128, 1, batch).
// ---------------------------------------------------------------------------
template<bool BIAS, bool OUT_BF16>
__global__ __launch_bounds__(512)
void gemm256_k(const short* __restrict__ A, const short* __restrict__ B,
               const float* __restrict__ bias, void* __restrict__ Cv,
               int N, int K,
               long long sA, long long sB, long long sC)
{
  __shared__ short As[2][256 * 32];
  __shared__ short Bs[2][128 * 32];
  const int bz = blockIdx.z;
  const int n0 = blockIdx.x * 128;
  const int t = threadIdx.x, lane = t & 63, wave = t >> 6;
  const int wm = wave >> 1, wn = wave & 1;
  const short* Ab = A + bz * sA;
  const short* Bb = B + bz * sB;
  const int lr = lane >> 2;
  const int lc = (lane & 3) * 8;
  const int fr = lane & 15, fs = lane >> 4;

  f32x4 acc[4][4];
#pragma unroll
  for (int i = 0; i < 4; ++i)
#pragma unroll
    for (int j = 0; j < 4; ++j) acc[i][j] = f32x4{0.f, 0.f, 0.f, 0.f};

  auto stage = [&](int b, int k0) {
#pragma unroll
    for (int q = 0; q < 2; ++q)
      gld16(Ab + (long long)(q * 128 + wave * 16 + lr) * K + k0 + lc,
            &As[b][(q * 128 + wave * 16) * 32]);
    gld16(Bb + (long long)(n0 + wave * 16 + lr) * K + k0 + lc,
          &Bs[b][wave * 16 * 32]);
  };

  const int NT = K >> 5;
  stage(0, 0);
  __syncthreads();
  for (int tt = 0; tt < NT; ++tt) {
    const int cur = tt & 1;
    if (tt + 1 < NT) stage(cur ^ 1, (tt + 1) << 5);
    s16x8 af[4], bfv[4];
#pragma unroll
    for (int i = 0; i < 4; ++i) af[i]  = *(const s16x8*)&As[cur][(wm * 64 + i * 16 + fr) * 32 + fs * 8];
#pragma unroll
    for (int j = 0; j < 4; ++j) bfv[j] = *(const s16x8*)&Bs[cur][(wn * 64 + j * 16 + fr) * 32 + fs * 8];
#pragma unroll
    for (int i = 0; i < 4; ++i)
#pragma unroll
      for (int j = 0; j < 4; ++j)
        acc[i][j] = __builtin_amdgcn_mfma_f32_16x16x32_bf16(af[i], bfv[j], acc[i][j], 0, 0, 0);
    if (tt + 1 < NT) __syncthreads();
  }

#pragma unroll
  for (int i = 0; i < 4; ++i) {
    int rowb = wm * 64 + i * 16 + fs * 4;
#pragma unroll
    for (int j = 0; j < 4; ++j) {
      int col = n0 + wn * 64 + j * 16 + fr;
      float bb = BIAS ? bias[col] : 0.0f;
#pragma unroll
      for (int u = 0; u < 4; ++u) {
        float v = acc[i][j][u] + bb;
        long long off = bz * sC + (long long)(rowb + u) * N + col;
        if constexpr (OUT_BF16) ((short*)Cv)[off] = f2b(v);
        else                    ((float*)Cv)[off] = v;
      }
    }
  }
}

// ---------------------------------------------------------------------------
// Fused h1+logits, BM=256 full-N.
// ---------------------------------------------------------------------------
__global__ __launch_bounds__(512)
void h1log256_k(const short* __restrict__ inter, const short* __restrict__ Wc1b,
                const float* __restrict__ bc1, const float* __restrict__ Wc2,
                const float* __restrict__ bc2, float* __restrict__ outp)
{
  __shared__ short As[2][256 * 32];
  __shared__ short Bs[2][128 * 32];
  __shared__ float part[256][2];
  const int ib = blockIdx.x;
  const int t = threadIdx.x, lane = t & 63, wave = t >> 6;
  const int wm = wave >> 1, wn = wave & 1;
  const short* Ab = inter + (long long)ib * 98304;
  const int lr = lane >> 2;
  const int lc = (lane & 3) * 8;
  const int fr = lane & 15, fs = lane >> 4;

  float lp[16];
#pragma unroll
  for (int e = 0; e < 16; ++e) lp[e] = 0.f;

  for (int n0 = 0; n0 < 384; n0 += 128) {
    f32x4 acc[4][4];
#pragma unroll
    for (int i = 0; i < 4; ++i)
#pragma unroll
      for (int j = 0; j < 4; ++j) acc[i][j] = f32x4{0.f, 0.f, 0.f, 0.f};

    auto stage = [&](int b, int k0) {
#pragma unroll
      for (int q = 0; q < 2; ++q)
        gld16(Ab + (long long)(q * 128 + wave * 16 + lr) * 384 + k0 + lc,
              &As[b][(q * 128 + wave * 16) * 32]);
      gld16(Wc1b + (long long)(n0 + wave * 16 + lr) * 384 + k0 + lc,
            &Bs[b][wave * 16 * 32]);
    };

    stage(0, 0);
    __syncthreads();
    for (int tt = 0; tt < 12; ++tt) {
      const int cur = tt & 1;
      if (tt + 1 < 12) stage(cur ^ 1, (tt + 1) << 5);
      s16x8 af[4], bfv[4];
#pragma unroll
      for (int i = 0; i < 4; ++i) af[i]  = *(const s16x8*)&As[cur][(wm * 64 + i * 16 + fr) * 32 + fs * 8];
#pragma unroll
      for (int j = 0; j < 4; ++j) bfv[j] = *(const s16x8*)&Bs[cur][(wn * 64 + j * 16 + fr) * 32 + fs * 8];
#pragma unroll
      for (int i = 0; i < 4; ++i)
#pragma unroll
        for (int j = 0; j < 4; ++j)
          acc[i][j] = __builtin_amdgcn_mfma_f32_16x16x32_bf16(af[i], bfv[j], acc[i][j], 0, 0, 0);
      if (tt + 1 < 12) __syncthreads();
    }
#pragma unroll
    for (int i = 0; i < 4; ++i)
#pragma unroll
      for (int j = 0; j < 4; ++j) {
        int col = n0 + wn * 64 + j * 16 + fr;
        float w2 = Wc2[col], b1v = bc1[col];
#pragma unroll
        for (int u = 0; u < 4; ++u)
          lp[i * 4 + u] += gelu_f(acc[i][j][u] + b1v) * w2;
      }
    __syncthreads();
  }
#pragma unroll
  for (int m = 1; m < 16; m <<= 1)
#pragma unroll
    for (int e = 0; e < 16; ++e) lp[e] += __shfl_xor(lp[e], m);
  if (fr == 0) {
#pragma unroll
    for (int e = 0; e < 16; ++e)
      part[wm * 64 + (e >> 2) * 16 + fs * 4 + (e & 3)][wn] = lp[e];
  }
  __syncthreads();
  if (t < 256) outp[ib * 256 + t] = sigm_f(part[t][0] + part[t][1] + bc2[0]);
}

// ---------------------------------------------------------------------------
// 64x64-tile bf16 GEMM, BK=32, 2-phase (layer GEMMs).
// ---------------------------------------------------------------------------
template<bool BIAS, bool GELU_ACT, bool OUT_BF16>
__global__ __launch_bounds__(256)
void gemm64_k(const short* __restrict__ A, const short* __restrict__ B,
              const float* __restrict__ bias, void* __restrict__ Cv,
              int M, int N, int K)
{
  __shared__ short As[2][64 * 32];
  __shared__ short Bs[2][64 * 32];
  const int n0 = blockIdx.x * 64;
  const int m0 = blockIdx.y * 64;
  const int t = threadIdx.x, lane = t & 63, wave = t >> 6;
  const int wm = wave >> 1, wn = wave & 1;
  const int srow = lane >> 2;
  const int scol = (lane & 3) * 8;
  const int fr = lane & 15, fs = lane >> 4;

  f32x4 acc[2][2];
#pragma unroll
  for (int i = 0; i < 2; ++i)
#pragma unroll
    for (int j = 0; j < 2; ++j) acc[i][j] = f32x4{0.f, 0.f, 0.f, 0.f};

  auto stage = [&](int b, int k0) {
    gld16(A + (long long)(m0 + wave * 16 + srow) * K + k0 + scol, &As[b][wave * 512]);
    gld16(B + (long long)(n0 + wave * 16 + srow) * K + k0 + scol, &Bs[b][wave * 512]);
  };

  const int NT = K >> 5;
  stage(0, 0);
  __syncthreads();
  for (int tt = 0; tt < NT; ++tt) {
    const int cur = tt & 1;
    if (tt + 1 < NT) stage(cur ^ 1, (tt + 1) << 5);
    s16x8 af[2], bfv[2];
#pragma unroll
    for (int i = 0; i < 2; ++i) af[i]  = *(const s16x8*)&As[cur][(wm * 32 + i * 16 + fr) * 32 + fs * 8];
#pragma unroll
    for (int j = 0; j < 2; ++j) bfv[j] = *(const s16x8*)&Bs[cur][(wn * 32 + j * 16 + fr) * 32 + fs * 8];
#pragma unroll
    for (int i = 0; i < 2; ++i)
#pragma unroll
      for (int j = 0; j < 2; ++j)
        acc[i][j] = __builtin_amdgcn_mfma_f32_16x16x32_bf16(af[i], bfv[j], acc[i][j], 0, 0, 0);
    if (tt + 1 < NT) __syncthreads();
  }

#pragma unroll
  for (int i = 0; i < 2; ++i) {
    int rowb = m0 + wm * 32 + i * 16 + fs * 4;
#pragma unroll
    for (int j = 0; j < 2; ++j) {
      int col = n0 + wn * 32 + j * 16 + fr;
      float bb = BIAS ? bias[col] : 0.0f;
#pragma unroll
      for (int u = 0; u < 4; ++u) {
        float v = acc[i][j][u] + bb;
        if constexpr (GELU_ACT) v = gelu_f(v);
        long long off = (long long)(rowb + u) * N + col;
        if constexpr (OUT_BF16) ((short*)Cv)[off] = f2b(v);
        else                    ((float*)Cv)[off] = v;
      }
    }
  }
}

// ---------------------------------------------------------------------------
// Wbil [o][x][y] fp32  ->  WbilT [o][y][x] bf16   (64x64 tiles via LDS)
// ---------------------------------------------------------------------------
__global__ __launch_bounds__(256)
void transpose_k(const float* __restrict__ W, short* __restrict__ WT)
{
  __shared__ short L[64 * 68];
  const int o  = blockIdx.z;
  const int x0 = blockIdx.x * 64, y0 = blockIdx.y * 64;
  const float* Wo = W  + (long long)o * 147456;
  short*      WTo = WT + (long long)o * 147456;
  const int t  = threadIdx.x;
  const int rr = t >> 4;
  const int cc = (t & 15) * 4;
#pragma unroll
  for (int q = 0; q < 4; ++q) {
    int xl = rr + 16 * q;
    float4 v = *(const float4*)(Wo + (x0 + xl) * 384 + y0 + cc);
    short4 p; p.x = f2b(v.x); p.y = f2b(v.y); p.z = f2b(v.z); p.w = f2b(v.w);
    *(short4*)&L[xl * 68 + cc] = p;
  }
  __syncthreads();
#pragma unroll
  for (int q = 0; q < 4; ++q) {
    int yl = rr + 16 * q;
    short4 p;
    p.x = L[(cc + 0) * 68 + yl];
    p.y = L[(cc + 1) * 68 + yl];
    p.z = L[(cc + 2) * 68 + yl];
    p.w = L[(cc + 3) * 68 + yl];
    *(short4*)(WTo + (y0 + yl) * 384 + x0 + cc) = p;
  }
}

// ---------------------------------------------------------------------------
// Convert ALL layer weights fp32->bf16 in ONE dispatch.
// ---------------------------------------------------------------------------
__global__ __launch_bounds__(256)
void convall_k(const float* __restrict__ Wc1, const float* __restrict__ Wqkv,
               const float* __restrict__ Wo, const float* __restrict__ W1,
               const float* __restrict__ W2, const float* __restrict__ Wout,
               short* __restrict__ Dc1, short* __restrict__ Dqkv,
               short* __restrict__ Do, short* __restrict__ D1,
               short* __restrict__ D2, short* __restrict__ Dout)
{
  long long i4 = ((long long)blockIdx.x * 256 + threadIdx.x) * 4;
  const float* s; short* d; long long off;
  if      (i4 <  147456) { s = Wc1;  d = Dc1;  off = 0; }
  else if (i4 < 1032192) { s = Wqkv; d = Dqkv; off = 147456; }
  else if (i4 < 1327104) { s = Wo;   d = Do;   off = 1032192; }
  else if (i4 < 2506752) { s = W1;   d = D1;   off = 1327104; }
  else if (i4 < 3686400) { s = W2;   d = D2;   off = 2506752; }
  else if (i4 < 3833856) { s = Wout; d = Dout; off = 3686400; }
  else return;
  long long l = i4 - off;
  float4 v = *(const float4*)(s + l);
  short4 p; p.x = f2b(v.x); p.y = f2b(v.y); p.z = f2b(v.z); p.w = f2b(v.w);
  *(short4*)(d + l) = p;
}

// ---------------------------------------------------------------------------
// Attention: qkv fp32 [256][1152] -> out bf16 [256][384]. d=48, NH=8.
// K/V staging vectorized (float4).
// ---------------------------------------------------------------------------
__global__ __launch_bounds__(256)
void attn_k(const float* __restrict__ qkv, short* __restrict__ outb)
{
  __shared__ short Ks[256 * 48];
  __shared__ short Vs[256 * 48];
  __shared__ float Ps[32][258];
  const int h  = blockIdx.y;
  const int q0 = blockIdx.x * 32;
  const int t = threadIdx.x, lane = t & 63, wave = t >> 6;
  for (int idx = t; idx < 3072; idx += 256) {
    int j = idx / 12, d4 = (idx - (idx / 12) * 12) * 4;
    const float* base = qkv + j * 1152 + h * 48 + d4;
    float4 kv = *(const float4*)(base + 384);
    float4 vv = *(const float4*)(base + 768);
    short4 pk; pk.x = f2b(kv.x); pk.y = f2b(kv.y); pk.z = f2b(kv.z); pk.w = f2b(kv.w);
    short4 pv; pv.x = f2b(vv.x); pv.y = f2b(vv.y); pv.z = f2b(vv.z); pv.w = f2b(vv.w);
    *(short4*)&Ks[j * 48 + d4] = pk;
    *(short4*)&Vs[j * 48 + d4] = pv;
  }
  __syncthreads();
  const int part = lane & 7;
  const int rl   = wave * 8 + (lane >> 3);
  const int row  = q0 + rl;
  float q[48];
#pragma unroll
  for (int d = 0; d < 48; ++d) q[d] = qkv[row * 1152 + h * 48 + d] * 0.14433756729740644f;
  float mx = -1e30f;
  for (int jj = 0; jj < 32; ++jj) {
    int j = jj * 8 + part;
    float a = 0.f;
#pragma unroll
    for (int dd = 0; dd < 12; ++dd) {
      short4 kk = *(const short4*)&Ks[j * 48 + dd * 4];
      a += q[dd*4+0]*b2f(kk.x) + q[dd*4+1]*b2f(kk.y) + q[dd*4+2]*b2f(kk.z) + q[dd*4+3]*b2f(kk.w);
    }
    Ps[rl][j] = a;
    mx = fmaxf(mx, a);
  }
  mx = fmaxf(mx, __shfl_xor(mx, 1));
  mx = fmaxf(mx, __shfl_xor(mx, 2));
  mx = fmaxf(mx, __shfl_xor(mx, 4));
  float sum = 0.f;
  for (int jj = 0; jj < 32; ++jj) {
    int j = jj * 8 + part;
    float e = expf(Ps[rl][j] - mx);
    Ps[rl][j] = e;
    sum += e;
  }
  sum += __shfl_xor(sum, 1); sum += __shfl_xor(sum, 2); sum += __shfl_xor(sum, 4);
  const float inv = 1.f / sum;
  __syncthreads();
  float o[6] = {0.f, 0.f, 0.f, 0.f, 0.f, 0.f};
  const int vb = part * 6;
  for (int j = 0; j < 256; ++j) {
    float p = Ps[rl][j];
    int base = j * 48 + vb;
#pragma unroll
    for (int dd = 0; dd < 3; ++dd) {
      short2 vv = *(const short2*)&Vs[base + dd * 2];
      o[dd*2]   += p * b2f(vv.x);
      o[dd*2+1] += p * b2f(vv.y);
    }
  }
#pragma unroll
  for (int d = 0; d < 6; ++d) outb[row * 384 + h * 48 + vb + d] = f2b(o[d] * inv);
}

// ---------------------------------------------------------------------------
// LayerNorm(x + delta)*g + b  -> xo fp32, xob bf16.  256 blocks x 128 thr.
// ---------------------------------------------------------------------------
__global__ __launch_bounds__(128)
void ln_k(const float* __restrict__ x, const float* __restrict__ d,
          const float* __restrict__ g, const float* __restrict__ b,
          float* __restrict__ xo, short* __restrict__ xob)
{
  const int row = blockIdx.x, t = threadIdx.x;
  float v[3]; float s = 0.f, ss = 0.f;
#pragma unroll
  for (int i = 0; i < 3; ++i) {
    int c = t + 128 * i;
    float u = x[row * 384 + c] + d[row * 384 + c];
    v[i] = u; s += u; ss += u * u;
  }
#pragma unroll
  for (int m = 1; m < 64; m <<= 1) { s += __shfl_xor(s, m); ss += __shfl_xor(ss, m); }
  __shared__ float sh[4];
  if ((t & 63) == 0) { sh[(t >> 6) * 2] = s; sh[(t >> 6) * 2 + 1] = ss; }
  __syncthreads();
  s = sh[0] + sh[2]; ss = sh[1] + sh[3];
  float mean = s * (1.f / 384.f);
  float var  = ss * (1.f / 384.f) - mean * mean;
  float rstd = rsqrtf(var + 1e-5f);
#pragma unroll
  for (int i = 0; i < 3; ++i) {
    int c = t + 128 * i;
    float y = (v[i] - mean) * rstd * g[c] + b[c];
    xo[row * 384 + c]  = y;
    xob[row * 384 + c] = f2b(y);
  }
}

__global__ void init_k(const float* __restrict__ hs, float* __restrict__ x,
                       short* __restrict__ xb, float* __restrict__ rstate)
{
  int i = blockIdx.x * 256 + threadIdx.x;
  if (i < 98304) { float v = hs[i]; x[i] = v; xb[i] = f2b(v); }
  if (i < 384) rstate[i] = 0.f;
}

// ---------------------------------------------------------------------------
// GRU: pool1 (8 partials) -> gih (wide) -> gru_tail (gates+p1+cont, 1 block)
// ---------------------------------------------------------------------------
__global__ __launch_bounds__(384)
void pool1_k(const float* __restrict__ x, float* __restrict__ partial)
{
  const int t = threadIdx.x, p = blockIdx.x;
  float s = 0.f;
  const float* xr = x + p * 32 * 384;
#pragma unroll 4
  for (int i = 0; i < 32; ++i) s += xr[i * 384 + t];
  partial[p * 384 + t] = s;
}

__global__ __launch_bounds__(256)
void gih_k(const float* __restrict__ Wih, const float* __restrict__ bih,
           const float* __restrict__ Whh, const float* __restrict__ bhh,
           const float* __restrict__ partial, const float* __restrict__ rstate,
           float* __restrict__ gi, float* __restrict__ gh)
{
  const int t = threadIdx.x, lane = t & 63, wave = t >> 6;
  const int r = blockIdx.x * 4 + wave;
  float a = 0.f, b = 0.f;
#pragma unroll
  for (int e = 0; e < 6; ++e) {
    int c = lane + 64 * e;
    float pc = 0.f;
#pragma unroll
    for (int p = 0; p < 8; ++p) pc += partial[p * 384 + c];
    pc *= (1.f / 256.f);
    a += Wih[r * 384 + c] * pc;
    b += Whh[r * 384 + c] * rstate[c];
  }
#pragma unroll
  for (int m = 1; m < 64; m <<= 1) { a += __shfl_xor(a, m); b += __shfl_xor(b, m); }
  if (lane == 0) { gi[r] = a + bih[r]; gh[r] = b + bhh[r]; }
}

__global__ __launch_bounds__(512)
void gru_tail_k(const float* __restrict__ gi, const float* __restrict__ gh,
                float* __restrict__ rstate,
                const float* __restrict__ Wp1, const float* __restrict__ bp1,
                const float* __restrict__ Wp2, const float* __restrict__ bp2,
                float* __restrict__ out_cont)
{
  __shared__ float hnew[384], p1s[384];
  const int t = threadIdx.x, lane = t & 63, wave = t >> 6;
  if (t < 384) {
    float r = sigm_f(gi[t] + gh[t]);
    float z = sigm_f(gi[384 + t] + gh[384 + t]);
    float n = tanhf(gi[768 + t] + r * gh[768 + t]);
    float hh = (1.f - z) * n + z * rstate[t];
    rstate[t] = hh;
    hnew[t] = hh;
  }
  __syncthreads();
  for (int r = wave; r < 384; r += 8) {
    float a = 0.f;
#pragma unroll
    for (int e = 0; e < 6; ++e) { int c = lane + 64 * e; a += Wp1[r * 384 + c] * hnew[c]; }
#pragma unroll
    for (int m = 1; m < 64; m <<= 1) a += __shfl_xor(a, m);
    if (lane == 0) p1s[r] = gelu_f(a + bp1[r]);
  }
  __syncthreads();
  if (wave == 0) {
    float a = 0.f;
#pragma unroll
    for (int e = 0; e < 6; ++e) { int c = lane + 64 * e; a += p1s[c] * Wp2[c]; }
#pragma unroll
    for (int m = 1; m < 64; m <<= 1) a += __shfl_xor(a, m);
    if (lane == 0) out_cont[0] = sigm_f(a + bp2[0]);
  }
}

// ---------------------------------------------------------------------------
extern "C" void kernel_launch(void* const* d_in, const int* in_sizes, int n_in,
                              void* d_out, int out_size, void* d_ws, size_t ws_size,
                              hipStream_t stream)
{
  const float* hs   = (const float*)d_in[0];
  const float* Wqkv = (const float*)d_in[1];
  const float* bqkv = (const float*)d_in[2];
  const float* Wo   = (const float*)d_in[3];
  const float* bo   = (const float*)d_in[4];
  const float* W1   = (const float*)d_in[5];
  const float* b1   = (const float*)d_in[6];
  const float* W2   = (const float*)d_in[7];
  const float* b2   = (const float*)d_in[8];
  const float* g1   = (const float*)d_in[9];
  const float* be1  = (const float*)d_in[10];
  const float* g2   = (const float*)d_in[11];
  const float* be2  = (const float*)d_in[12];
  const float* Wbil = (const float*)d_in[13];
  const float* bbil = (const float*)d_in[14];
  const float* Wc1  = (const float*)d_in[15];
  const float* bc1  = (const float*)d_in[16];
  const float* Wc2  = (const float*)d_in[17];
  const float* bc2  = (const float*)d_in[18];
  const float* Wih  = (const float*)d_in[19];
  const float* bih  = (const float*)d_in[20];
  const float* Whh  = (const float*)d_in[21];
  const float* bhh  = (const float*)d_in[22];
  const float* Wp1  = (const float*)d_in[23];
  const float* bp1  = (const float*)d_in[24];
  const float* Wp2  = (const float*)d_in[25];
  const float* bp2  = (const float*)d_in[26];
  const float* Wout = (const float*)d_in[27];
  const float* bout = (const float*)d_in[28];
  float* out = (float*)d_out;

  char* ws = (char*)d_ws;
  size_t off = 0;
  auto alloc = [&](size_t bytes) -> char* {
    char* p = ws + off; off += (bytes + 255) & ~(size_t)255; return p;
  };
  short* wbilT   = (short*)alloc(56623104ULL * 2);
  short* tmp     = (short*)alloc(256ULL * 147456 * 2);
  short* inter   = (short*)alloc(256ULL * 98304 * 2);
  float* x       = (float*)alloc(98304 * 4);
  short* xb      = (short*)alloc(98304 * 2);
  float* qkv     = (float*)alloc(294912 * 4);
  short* attnb   = (short*)alloc(98304 * 2);
  float* delta   = (float*)alloc(98304 * 4);
  short* ff1b    = (short*)alloc(393216 * 2);
  float* rstate  = (float*)alloc(384 * 4);
  float* partial = (float*)alloc(8 * 384 * 4);
  float* gi      = (float*)alloc(1152 * 4);
  float* gh      = (float*)alloc(1152 * 4);
  short* wc1b    = (short*)alloc(147456 * 2);
  short* wqkvb   = (short*)alloc(884736ULL * 2);
  short* wob     = (short*)alloc(294912ULL * 2);
  short* w1b     = (short*)alloc(1179648ULL * 2);
  short* w2b     = (short*)alloc(1179648ULL * 2);
  short* woutb   = (short*)alloc(147456 * 2);
  (void)ws_size; (void)in_sizes; (void)n_in; (void)out_size;

  dim3 B256(256);
  dim3 B512(512);

  init_k<<<dim3(384), B256, 0, stream>>>(hs, x, xb, rstate);
  transpose_k<<<dim3(6, 6, 384), B256, 0, stream>>>(Wbil, wbilT);
  convall_k<<<dim3(3744), B256, 0, stream>>>(Wc1, Wqkv, Wo, W1, W2, Wout,
                                             wc1b, wqkvb, wob, w1b, w2b, woutb);

  for (int s = 0; s < 2; ++s) {
    for (int l = 0; l < 2; ++l) {
      gemm64_k<true, false, false><<<dim3(18, 4), B256, 0, stream>>>(
          xb, wqkvb + l * 442368, bqkv + l * 1152, qkv, 256, 1152, 384);
      attn_k<<<dim3(8, 8), B256, 0, stream>>>(qkv, attnb);
      gemm64_k<true, false, false><<<dim3(6, 4), B256, 0, stream>>>(
          attnb, wob + l * 147456, bo + l * 384, delta, 256, 384, 384);
      ln_k<<<dim3(256), dim3(128), 0, stream>>>(x, delta, g1 + l * 384, be1 + l * 384, x, xb);
      gemm64_k<true, true, true><<<dim3(24, 4), B256, 0, stream>>>(
          xb, w1b + l * 589824, b1 + l * 1536, ff1b, 256, 1536, 384);
      gemm64_k<true, false, false><<<dim3(6, 4), B256, 0, stream>>>(
          ff1b, w2b + l * 589824, b2 + l * 384, delta, 256, 384, 1536);
      ln_k<<<dim3(256), dim3(128), 0, stream>>>(x, delta, g2 + l * 384, be2 + l * 384, x, xb);
    }
    // tmp[i, o*384+y] = sum_x X[i,x] * WbilT[o*384+y, x]   (B read ONCE)
    gemm256_k<false, true><<<dim3(1152, 1, 1), B512, 0, stream>>>(
        xb, wbilT, (const float*)nullptr, tmp, 147456, 384, 0, 0, 0);
    // inter[i][j][o] = sum_y X[j,y] * tmp_i[o,y] + bbil[o]
    gemm256_k<true, true><<<dim3(3, 1, 256), B512, 0, stream>>>(
        xb, tmp, bbil, inter, 384, 384, 0, 147456LL, 98304LL);
    // fused h1 + logits
    h1log256_k<<<dim3(256), B512, 0, stream>>>(inter, wc1b, bc1, Wc2, bc2,
                                               out + 98304 + s * 65536);
    // --- GRU controller ---
    pool1_k<<<dim3(8), dim3(384), 0, stream>>>(x, partial);
    gih_k<<<dim3(288), B256, 0, stream>>>(Wih, bih, Whh, bhh, partial, rstate, gi, gh);
    gru_tail_k<<<dim3(1), B512, 0, stream>>>(gi, gh, rstate, Wp1, bp1, Wp2, bp2,
                                             out + 98304 + 131072 + s);
  }
  gemm64_k<true, false, false><<<dim3(6, 4), B256, 0, stream>>>(
      xb, woutb, bout, out, 256, 384, 384);
}

// Round 11
// 642.779 us; speedup vs baseline: 1.2552x; 1.1324x over previous
//
#include <hip/hip_runtime.h>

typedef __attribute__((ext_vector_type(4))) float f32x4;
typedef __attribute__((ext_vector_type(8))) short s16x8;

#define DEVI __device__ __forceinline__

DEVI float b2f(short s) {
  union { float f; unsigned u; } v; v.u = ((unsigned)(unsigned short)s) << 16; return v.f;
}
DEVI short f2b(float f) {
  union { float f; unsigned u; } v; v.f = f;
  unsigned u = v.u;
  u += 0x7FFFu + ((u >> 16) & 1u);   // RNE
  return (short)(u >> 16);
}
// fast GELU: tanh form, exp-based; overflow-safe. err ~4e-4 max, ~1e-5 here.
DEVI float gelu_f(float x) {
  float z2 = 1.5957691216f * x * (1.0f + 0.044715f * x * x);
  float e = __expf(z2);
  float th = 1.0f - 2.0f / (e + 1.0f);
  return 0.5f * x * (1.0f + th);
}
DEVI float sigm_f(float x) { return 1.0f / (1.0f + expf(-x)); }

// async global->LDS, 16B per lane; LDS dest = wave-uniform base + lane*16
DEVI void gld16(const short* g, const short* l) {
  __builtin_amdgcn_global_load_lds((const __attribute__((address_space(1))) void*)g,
                                   (__attribute__((address_space(3))) void*)l, 16, 0, 0);
}

// ---------------------------------------------------------------------------
// BM=256 bf16 GEMM: C[256,N] = A[256,K] * B[N,K]^T (+bias). 512 thr, 8 waves
// (4m x 2n), BK=32. Grid (N/128, 1, batch).
// ---------------------------------------------------------------------------
template<bool BIAS, bool OUT_BF16>
__global__ __launch_bounds__(512)
void gemm256_k(const short* __restrict__ A, const short* __restrict__ B,
               const float* __restrict__ bias, void* __restrict__ Cv,
               int N, int K,
               long long sA, long long sB, long long sC)
{
  __shared__ short As[2][256 * 32];
  __shared__ short Bs[2][128 * 32];
  const int bz = blockIdx.z;
  const int n0 = blockIdx.x * 128;
  const int t = threadIdx.x, lane = t & 63, wave = t >> 6;
  const int wm = wave >> 1, wn = wave & 1;
  const short* Ab = A + bz * sA;
  const short* Bb = B + bz * sB;
  const int lr = lane >> 2;
  const int lc = (lane & 3) * 8;
  const int fr = lane & 15, fs = lane >> 4;

  f32x4 acc[4][4];
#pragma unroll
  for (int i = 0; i < 4; ++i)
#pragma unroll
    for (int j = 0; j < 4; ++j) acc[i][j] = f32x4{0.f, 0.f, 0.f, 0.f};

  auto stage = [&](int b, int k0) {
#pragma unroll
    for (int q = 0; q < 2; ++q)
      gld16(Ab + (long long)(q * 128 + wave * 16 + lr) * K + k0 + lc,
            &As[b][(q * 128 + wave * 16) * 32]);
    gld16(Bb + (long long)(n0 + wave * 16 + lr) * K + k0 + lc,
          &Bs[b][wave * 16 * 32]);
  };

  const int NT = K >> 5;
  stage(0, 0);
  __syncthreads();
  for (int tt = 0; tt < NT; ++tt) {
    const int cur = tt & 1;
    if (tt + 1 < NT) stage(cur ^ 1, (tt + 1) << 5);
    s16x8 af[4], bfv[4];
#pragma unroll
    for (int i = 0; i < 4; ++i) af[i]  = *(const s16x8*)&As[cur][(wm * 64 + i * 16 + fr) * 32 + fs * 8];
#pragma unroll
    for (int j = 0; j < 4; ++j) bfv[j] = *(const s16x8*)&Bs[cur][(wn * 64 + j * 16 + fr) * 32 + fs * 8];
#pragma unroll
    for (int i = 0; i < 4; ++i)
#pragma unroll
      for (int j = 0; j < 4; ++j)
        acc[i][j] = __builtin_amdgcn_mfma_f32_16x16x32_bf16(af[i], bfv[j], acc[i][j], 0, 0, 0);
    if (tt + 1 < NT) __syncthreads();
  }

#pragma unroll
  for (int i = 0; i < 4; ++i) {
    int rowb = wm * 64 + i * 16 + fs * 4;
#pragma unroll
    for (int j = 0; j < 4; ++j) {
      int col = n0 + wn * 64 + j * 16 + fr;
      float bb = BIAS ? bias[col] : 0.0f;
#pragma unroll
      for (int u = 0; u < 4; ++u) {
        float v = acc[i][j][u] + bb;
        long long off = bz * sC + (long long)(rowb + u) * N + col;
        if constexpr (OUT_BF16) ((short*)Cv)[off] = f2b(v);
        else                    ((float*)Cv)[off] = v;
      }
    }
  }
}

// ---------------------------------------------------------------------------
// Fused h1+logits, BM=256 full-N.
// ---------------------------------------------------------------------------
__global__ __launch_bounds__(512)
void h1log256_k(const short* __restrict__ inter, const short* __restrict__ Wc1b,
                const float* __restrict__ bc1, const float* __restrict__ Wc2,
                const float* __restrict__ bc2, float* __restrict__ outp)
{
  __shared__ short As[2][256 * 32];
  __shared__ short Bs[2][128 * 32];
  __shared__ float part[256][2];
  const int ib = blockIdx.x;
  const int t = threadIdx.x, lane = t & 63, wave = t >> 6;
  const int wm = wave >> 1, wn = wave & 1;
  const short* Ab = inter + (long long)ib * 98304;
  const int lr = lane >> 2;
  const int lc = (lane & 3) * 8;
  const int fr = lane & 15, fs = lane >> 4;

  float lp[16];
#pragma unroll
  for (int e = 0; e < 16; ++e) lp[e] = 0.f;

  for (int n0 = 0; n0 < 384; n0 += 128) {
    f32x4 acc[4][4];
#pragma unroll
    for (int i = 0; i < 4; ++i)
#pragma unroll
      for (int j = 0; j < 4; ++j) acc[i][j] = f32x4{0.f, 0.f, 0.f, 0.f};

    auto stage = [&](int b, int k0) {
#pragma unroll
      for (int q = 0; q < 2; ++q)
        gld16(Ab + (long long)(q * 128 + wave * 16 + lr) * 384 + k0 + lc,
              &As[b][(q * 128 + wave * 16) * 32]);
      gld16(Wc1b + (long long)(n0 + wave * 16 + lr) * 384 + k0 + lc,
            &Bs[b][wave * 16 * 32]);
    };

    stage(0, 0);
    __syncthreads();
    for (int tt = 0; tt < 12; ++tt) {
      const int cur = tt & 1;
      if (tt + 1 < 12) stage(cur ^ 1, (tt + 1) << 5);
      s16x8 af[4], bfv[4];
#pragma unroll
      for (int i = 0; i < 4; ++i) af[i]  = *(const s16x8*)&As[cur][(wm * 64 + i * 16 + fr) * 32 + fs * 8];
#pragma unroll
      for (int j = 0; j < 4; ++j) bfv[j] = *(const s16x8*)&Bs[cur][(wn * 64 + j * 16 + fr) * 32 + fs * 8];
#pragma unroll
      for (int i = 0; i < 4; ++i)
#pragma unroll
        for (int j = 0; j < 4; ++j)
          acc[i][j] = __builtin_amdgcn_mfma_f32_16x16x32_bf16(af[i], bfv[j], acc[i][j], 0, 0, 0);
      if (tt + 1 < 12) __syncthreads();
    }
#pragma unroll
    for (int i = 0; i < 4; ++i)
#pragma unroll
      for (int j = 0; j < 4; ++j) {
        int col = n0 + wn * 64 + j * 16 + fr;
        float w2 = Wc2[col], b1v = bc1[col];
#pragma unroll
        for (int u = 0; u < 4; ++u)
          lp[i * 4 + u] += gelu_f(acc[i][j][u] + b1v) * w2;
      }
    __syncthreads();
  }
#pragma unroll
  for (int m = 1; m < 16; m <<= 1)
#pragma unroll
    for (int e = 0; e < 16; ++e) lp[e] += __shfl_xor(lp[e], m);
  if (fr == 0) {
#pragma unroll
    for (int e = 0; e < 16; ++e)
      part[wm * 64 + (e >> 2) * 16 + fs * 4 + (e & 3)][wn] = lp[e];
  }
  __syncthreads();
  if (t < 256) outp[ib * 256 + t] = sigm_f(part[t][0] + part[t][1] + bc2[0]);
}

// ---------------------------------------------------------------------------
// 64x64-tile bf16 GEMM, BK=32, 2-phase (layer GEMMs).
// ---------------------------------------------------------------------------
template<bool BIAS, bool GELU_ACT, bool OUT_BF16>
__global__ __launch_bounds__(256)
void gemm64_k(const short* __restrict__ A, const short* __restrict__ B,
              const float* __restrict__ bias, void* __restrict__ Cv,
              int M, int N, int K)
{
  __shared__ short As[2][64 * 32];
  __shared__ short Bs[2][64 * 32];
  const int n0 = blockIdx.x * 64;
  const int m0 = blockIdx.y * 64;
  const int t = threadIdx.x, lane = t & 63, wave = t >> 6;
  const int wm = wave >> 1, wn = wave & 1;
  const int srow = lane >> 2;
  const int scol = (lane & 3) * 8;
  const int fr = lane & 15, fs = lane >> 4;

  f32x4 acc[2][2];
#pragma unroll
  for (int i = 0; i < 2; ++i)
#pragma unroll
    for (int j = 0; j < 2; ++j) acc[i][j] = f32x4{0.f, 0.f, 0.f, 0.f};

  auto stage = [&](int b, int k0) {
    gld16(A + (long long)(m0 + wave * 16 + srow) * K + k0 + scol, &As[b][wave * 512]);
    gld16(B + (long long)(n0 + wave * 16 + srow) * K + k0 + scol, &Bs[b][wave * 512]);
  };

  const int NT = K >> 5;
  stage(0, 0);
  __syncthreads();
  for (int tt = 0; tt < NT; ++tt) {
    const int cur = tt & 1;
    if (tt + 1 < NT) stage(cur ^ 1, (tt + 1) << 5);
    s16x8 af[2], bfv[2];
#pragma unroll
    for (int i = 0; i < 2; ++i) af[i]  = *(const s16x8*)&As[cur][(wm * 32 + i * 16 + fr) * 32 + fs * 8];
#pragma unroll
    for (int j = 0; j < 2; ++j) bfv[j] = *(const s16x8*)&Bs[cur][(wn * 32 + j * 16 + fr) * 32 + fs * 8];
#pragma unroll
    for (int i = 0; i < 2; ++i)
#pragma unroll
      for (int j = 0; j < 2; ++j)
        acc[i][j] = __builtin_amdgcn_mfma_f32_16x16x32_bf16(af[i], bfv[j], acc[i][j], 0, 0, 0);
    if (tt + 1 < NT) __syncthreads();
  }

#pragma unroll
  for (int i = 0; i < 2; ++i) {
    int rowb = m0 + wm * 32 + i * 16 + fs * 4;
#pragma unroll
    for (int j = 0; j < 2; ++j) {
      int col = n0 + wn * 32 + j * 16 + fr;
      float bb = BIAS ? bias[col] : 0.0f;
#pragma unroll
      for (int u = 0; u < 4; ++u) {
        float v = acc[i][j][u] + bb;
        if constexpr (GELU_ACT) v = gelu_f(v);
        long long off = (long long)(rowb + u) * N + col;
        if constexpr (OUT_BF16) ((short*)Cv)[off] = f2b(v);
        else                    ((float*)Cv)[off] = v;
      }
    }
  }
}

// ---------------------------------------------------------------------------
// Wbil [o][x][y] fp32  ->  WbilT [o][y][x] bf16   (64x64 tiles via LDS)
// ---------------------------------------------------------------------------
__global__ __launch_bounds__(256)
void transpose_k(const float* __restrict__ W, short* __restrict__ WT)
{
  __shared__ short L[64 * 68];
  const int o  = blockIdx.z;
  const int x0 = blockIdx.x * 64, y0 = blockIdx.y * 64;
  const float* Wo = W  + (long long)o * 147456;
  short*      WTo = WT + (long long)o * 147456;
  const int t  = threadIdx.x;
  const int rr = t >> 4;
  const int cc = (t & 15) * 4;
#pragma unroll
  for (int q = 0; q < 4; ++q) {
    int xl = rr + 16 * q;
    float4 v = *(const float4*)(Wo + (x0 + xl) * 384 + y0 + cc);
    short4 p; p.x = f2b(v.x); p.y = f2b(v.y); p.z = f2b(v.z); p.w = f2b(v.w);
    *(short4*)&L[xl * 68 + cc] = p;
  }
  __syncthreads();
#pragma unroll
  for (int q = 0; q < 4; ++q) {
    int yl = rr + 16 * q;
    short4 p;
    p.x = L[(cc + 0) * 68 + yl];
    p.y = L[(cc + 1) * 68 + yl];
    p.z = L[(cc + 2) * 68 + yl];
    p.w = L[(cc + 3) * 68 + yl];
    *(short4*)(WTo + (y0 + yl) * 384 + x0 + cc) = p;
  }
}

// ---------------------------------------------------------------------------
// Convert ALL layer weights fp32->bf16 in ONE dispatch.
// ---------------------------------------------------------------------------
__global__ __launch_bounds__(256)
void convall_k(const float* __restrict__ Wc1, const float* __restrict__ Wqkv,
               const float* __restrict__ Wo, const float* __restrict__ W1,
               const float* __restrict__ W2, const float* __restrict__ Wout,
               short* __restrict__ Dc1, short* __restrict__ Dqkv,
               short* __restrict__ Do, short* __restrict__ D1,
               short* __restrict__ D2, short* __restrict__ Dout)
{
  long long i4 = ((long long)blockIdx.x * 256 + threadIdx.x) * 4;
  const float* s; short* d; long long off;
  if      (i4 <  147456) { s = Wc1;  d = Dc1;  off = 0; }
  else if (i4 < 1032192) { s = Wqkv; d = Dqkv; off = 147456; }
  else if (i4 < 1327104) { s = Wo;   d = Do;   off = 1032192; }
  else if (i4 < 2506752) { s = W1;   d = D1;   off = 1327104; }
  else if (i4 < 3686400) { s = W2;   d = D2;   off = 2506752; }
  else if (i4 < 3833856) { s = Wout; d = Dout; off = 3686400; }
  else return;
  long long l = i4 - off;
  float4 v = *(const float4*)(s + l);
  short4 p; p.x = f2b(v.x); p.y = f2b(v.y); p.z = f2b(v.z); p.w = f2b(v.w);
  *(short4*)(d + l) = p;
}

// ---------------------------------------------------------------------------
// Attention: qkv fp32 [256][1152] -> out bf16 [256][384]. d=48, NH=8.
// K/V staging vectorized (float4).
// ---------------------------------------------------------------------------
__global__ __launch_bounds__(256)
void attn_k(const float* __restrict__ qkv, short* __restrict__ outb)
{
  __shared__ short Ks[256 * 48];
  __shared__ short Vs[256 * 48];
  __shared__ float Ps[32][258];
  const int h  = blockIdx.y;
  const int q0 = blockIdx.x * 32;
  const int t = threadIdx.x, lane = t & 63, wave = t >> 6;
  for (int idx = t; idx < 3072; idx += 256) {
    int j = idx / 12, d4 = (idx - (idx / 12) * 12) * 4;
    const float* base = qkv + j * 1152 + h * 48 + d4;
    float4 kv = *(const float4*)(base + 384);
    float4 vv = *(const float4*)(base + 768);
    short4 pk; pk.x = f2b(kv.x); pk.y = f2b(kv.y); pk.z = f2b(kv.z); pk.w = f2b(kv.w);
    short4 pv; pv.x = f2b(vv.x); pv.y = f2b(vv.y); pv.z = f2b(vv.z); pv.w = f2b(vv.w);
    *(short4*)&Ks[j * 48 + d4] = pk;
    *(short4*)&Vs[j * 48 + d4] = pv;
  }
  __syncthreads();
  const int part = lane & 7;
  const int rl   = wave * 8 + (lane >> 3);
  const int row  = q0 + rl;
  float q[48];
#pragma unroll
  for (int d = 0; d < 48; ++d) q[d] = qkv[row * 1152 + h * 48 + d] * 0.14433756729740644f;
  float mx = -1e30f;
  for (int jj = 0; jj < 32; ++jj) {
    int j = jj * 8 + part;
    float a = 0.f;
#pragma unroll
    for (int dd = 0; dd < 12; ++dd) {
      short4 kk = *(const short4*)&Ks[j * 48 + dd * 4];
      a += q[dd*4+0]*b2f(kk.x) + q[dd*4+1]*b2f(kk.y) + q[dd*4+2]*b2f(kk.z) + q[dd*4+3]*b2f(kk.w);
    }
    Ps[rl][j] = a;
    mx = fmaxf(mx, a);
  }
  mx = fmaxf(mx, __shfl_xor(mx, 1));
  mx = fmaxf(mx, __shfl_xor(mx, 2));
  mx = fmaxf(mx, __shfl_xor(mx, 4));
  float sum = 0.f;
  for (int jj = 0; jj < 32; ++jj) {
    int j = jj * 8 + part;
    float e = expf(Ps[rl][j] - mx);
    Ps[rl][j] = e;
    sum += e;
  }
  sum += __shfl_xor(sum, 1); sum += __shfl_xor(sum, 2); sum += __shfl_xor(sum, 4);
  const float inv = 1.f / sum;
  __syncthreads();
  float o[6] = {0.f, 0.f, 0.f, 0.f, 0.f, 0.f};
  const int vb = part * 6;
  for (int j = 0; j < 256; ++j) {
    float p = Ps[rl][j];
    int base = j * 48 + vb;
#pragma unroll
    for (int dd = 0; dd < 3; ++dd) {
      short2 vv = *(const short2*)&Vs[base + dd * 2];
      o[dd*2]   += p * b2f(vv.x);
      o[dd*2+1] += p * b2f(vv.y);
    }
  }
#pragma unroll
  for (int d = 0; d < 6; ++d) outb[row * 384 + h * 48 + vb + d] = f2b(o[d] * inv);
}

// ---------------------------------------------------------------------------
// LayerNorm(x + delta_bf16)*g + b  -> xo fp32, xob bf16.  256 blocks x 128 thr.
// ---------------------------------------------------------------------------
__global__ __launch_bounds__(128)
void ln_k(const float* __restrict__ x, const short* __restrict__ d,
          const float* __restrict__ g, const float* __restrict__ b,
          float* __restrict__ xo, short* __restrict__ xob)
{
  const int row = blockIdx.x, t = threadIdx.x;
  float v[3]; float s = 0.f, ss = 0.f;
#pragma unroll
  for (int i = 0; i < 3; ++i) {
    int c = t + 128 * i;
    float u = x[row * 384 + c] + b2f(d[row * 384 + c]);
    v[i] = u; s += u; ss += u * u;
  }
#pragma unroll
  for (int m = 1; m < 64; m <<= 1) { s += __shfl_xor(s, m); ss += __shfl_xor(ss, m); }
  __shared__ float sh[4];
  if ((t & 63) == 0) { sh[(t >> 6) * 2] = s; sh[(t >> 6) * 2 + 1] = ss; }
  __syncthreads();
  s = sh[0] + sh[2]; ss = sh[1] + sh[3];
  float mean = s * (1.f / 384.f);
  float var  = ss * (1.f / 384.f) - mean * mean;
  float rstd = rsqrtf(var + 1e-5f);
#pragma unroll
  for (int i = 0; i < 3; ++i) {
    int c = t + 128 * i;
    float y = (v[i] - mean) * rstd * g[c] + b[c];
    xo[row * 384 + c]  = y;
    xob[row * 384 + c] = f2b(y);
  }
}

__global__ void init_k(const float* __restrict__ hs, float* __restrict__ x,
                       short* __restrict__ xb, float* __restrict__ rstate)
{
  int i = blockIdx.x * 256 + threadIdx.x;
  if (i < 98304) { float v = hs[i]; x[i] = v; xb[i] = f2b(v); }
  if (i < 384) rstate[i] = 0.f;
}

// ---------------------------------------------------------------------------
// GRU, wide (R8-proven): pool1 -> gih -> gru2 -> p1 (96 blocks) -> cont
// ---------------------------------------------------------------------------
__global__ __launch_bounds__(384)
void pool1_k(const float* __restrict__ x, float* __restrict__ partial)
{
  const int t = threadIdx.x, p = blockIdx.x;
  float s = 0.f;
  const float* xr = x + p * 32 * 384;
#pragma unroll 4
  for (int i = 0; i < 32; ++i) s += xr[i * 384 + t];
  partial[p * 384 + t] = s;
}

__global__ __launch_bounds__(256)
void gih_k(const float* __restrict__ Wih, const float* __restrict__ bih,
           const float* __restrict__ Whh, const float* __restrict__ bhh,
           const float* __restrict__ partial, const float* __restrict__ rstate,
           float* __restrict__ gi, float* __restrict__ gh)
{
  const int t = threadIdx.x, lane = t & 63, wave = t >> 6;
  const int r = blockIdx.x * 4 + wave;
  float a = 0.f, b = 0.f;
#pragma unroll
  for (int e = 0; e < 6; ++e) {
    int c = lane + 64 * e;
    float pc = 0.f;
#pragma unroll
    for (int p = 0; p < 8; ++p) pc += partial[p * 384 + c];
    pc *= (1.f / 256.f);
    a += Wih[r * 384 + c] * pc;
    b += Whh[r * 384 + c] * rstate[c];
  }
#pragma unroll
  for (int m = 1; m < 64; m <<= 1) { a += __shfl_xor(a, m); b += __shfl_xor(b, m); }
  if (lane == 0) { gi[r] = a + bih[r]; gh[r] = b + bhh[r]; }
}

__global__ __launch_bounds__(384)
void gru2_k(const float* __restrict__ gi, const float* __restrict__ gh,
            float* __restrict__ rstate, float* __restrict__ hnew)
{
  const int t = threadIdx.x;
  float r = sigm_f(gi[t] + gh[t]);
  float z = sigm_f(gi[384 + t] + gh[384 + t]);
  float n = tanhf(gi[768 + t] + r * gh[768 + t]);
  float h = (1.f - z) * n + z * rstate[t];
  rstate[t] = h;
  hnew[t] = h;
}

__global__ __launch_bounds__(256)
void p1_k(const float* __restrict__ Wp1, const float* __restrict__ bp1,
          const float* __restrict__ hnew, float* __restrict__ p1)
{
  const int t = threadIdx.x, lane = t & 63, wave = t >> 6;
  const int r = blockIdx.x * 4 + wave;
  float a = 0.f;
#pragma unroll
  for (int e = 0; e < 6; ++e) { int c = lane + 64 * e; a += Wp1[r * 384 + c] * hnew[c]; }
#pragma unroll
  for (int m = 1; m < 64; m <<= 1) a += __shfl_xor(a, m);
  if (lane == 0) p1[r] = gelu_f(a + bp1[r]);
}

__global__ __launch_bounds__(64)
void cont_k(const float* __restrict__ p1, const float* __restrict__ Wp2,
            const float* __restrict__ bp2, float* __restrict__ out_cont)
{
  const int lane = threadIdx.x;
  float a = 0.f;
#pragma unroll
  for (int e = 0; e < 6; ++e) { int c = lane + 64 * e; a += p1[c] * Wp2[c]; }
#pragma unroll
  for (int m = 1; m < 64; m <<= 1) a += __shfl_xor(a, m);
  if (lane == 0) out_cont[0] = sigm_f(a + bp2[0]);
}

// ---------------------------------------------------------------------------
extern "C" void kernel_launch(void* const* d_in, const int* in_sizes, int n_in,
                              void* d_out, int out_size, void* d_ws, size_t ws_size,
                              hipStream_t stream)
{
  const float* hs   = (const float*)d_in[0];
  const float* Wqkv = (const float*)d_in[1];
  const float* bqkv = (const float*)d_in[2];
  const float* Wo   = (const float*)d_in[3];
  const float* bo   = (const float*)d_in[4];
  const float* W1   = (const float*)d_in[5];
  const float* b1   = (const float*)d_in[6];
  const float* W2   = (const float*)d_in[7];
  const float* b2   = (const float*)d_in[8];
  const float* g1   = (const float*)d_in[9];
  const float* be1  = (const float*)d_in[10];
  const float* g2   = (const float*)d_in[11];
  const float* be2  = (const float*)d_in[12];
  const float* Wbil = (const float*)d_in[13];
  const float* bbil = (const float*)d_in[14];
  const float* Wc1  = (const float*)d_in[15];
  const float* bc1  = (const float*)d_in[16];
  const float* Wc2  = (const float*)d_in[17];
  const float* bc2  = (const float*)d_in[18];
  const float* Wih  = (const float*)d_in[19];
  const float* bih  = (const float*)d_in[20];
  const float* Whh  = (const float*)d_in[21];
  const float* bhh  = (const float*)d_in[22];
  const float* Wp1  = (const float*)d_in[23];
  const float* bp1  = (const float*)d_in[24];
  const float* Wp2  = (const float*)d_in[25];
  const float* bp2  = (const float*)d_in[26];
  const float* Wout = (const float*)d_in[27];
  const float* bout = (const float*)d_in[28];
  float* out = (float*)d_out;

  char* ws = (char*)d_ws;
  size_t off = 0;
  auto alloc = [&](size_t bytes) -> char* {
    char* p = ws + off; off += (bytes + 255) & ~(size_t)255; return p;
  };
  short* wbilT   = (short*)alloc(56623104ULL * 2);
  short* tmp     = (short*)alloc(256ULL * 147456 * 2);
  short* inter   = (short*)alloc(256ULL * 98304 * 2);
  float* x       = (float*)alloc(98304 * 4);
  short* xb      = (short*)alloc(98304 * 2);
  float* qkv     = (float*)alloc(294912 * 4);
  short* attnb   = (short*)alloc(98304 * 2);
  short* deltab  = (short*)alloc(98304 * 2);
  short* ff1b    = (short*)alloc(393216 * 2);
  float* rstate  = (float*)alloc(384 * 4);
  float* partial = (float*)alloc(8 * 384 * 4);
  float* gi      = (float*)alloc(1152 * 4);
  float* gh      = (float*)alloc(1152 * 4);
  float* hnew    = (float*)alloc(384 * 4);
  float* p1buf   = (float*)alloc(384 * 4);
  short* wc1b    = (short*)alloc(147456 * 2);
  short* wqkvb   = (short*)alloc(884736ULL * 2);
  short* wob     = (short*)alloc(294912ULL * 2);
  short* w1b     = (short*)alloc(1179648ULL * 2);
  short* w2b     = (short*)alloc(1179648ULL * 2);
  short* woutb   = (short*)alloc(147456 * 2);
  (void)ws_size; (void)in_sizes; (void)n_in; (void)out_size;

  dim3 B256(256);
  dim3 B512(512);

  init_k<<<dim3(384), B256, 0, stream>>>(hs, x, xb, rstate);
  transpose_k<<<dim3(6, 6, 384), B256, 0, stream>>>(Wbil, wbilT);
  convall_k<<<dim3(3744), B256, 0, stream>>>(Wc1, Wqkv, Wo, W1, W2, Wout,
                                             wc1b, wqkvb, wob, w1b, w2b, woutb);

  for (int s = 0; s < 2; ++s) {
    for (int l = 0; l < 2; ++l) {
      gemm64_k<true, false, false><<<dim3(18, 4), B256, 0, stream>>>(
          xb, wqkvb + l * 442368, bqkv + l * 1152, qkv, 256, 1152, 384);
      attn_k<<<dim3(8, 8), B256, 0, stream>>>(qkv, attnb);
      gemm64_k<true, false, true><<<dim3(6, 4), B256, 0, stream>>>(
          attnb, wob + l * 147456, bo + l * 384, deltab, 256, 384, 384);
      ln_k<<<dim3(256), dim3(128), 0, stream>>>(x, deltab, g1 + l * 384, be1 + l * 384, x, xb);
      gemm64_k<true, true, true><<<dim3(24, 4), B256, 0, stream>>>(
          xb, w1b + l * 589824, b1 + l * 1536, ff1b, 256, 1536, 384);
      gemm64_k<true, false, true><<<dim3(6, 4), B256, 0, stream>>>(
          ff1b, w2b + l * 589824, b2 + l * 384, deltab, 256, 384, 1536);
      ln_k<<<dim3(256), dim3(128), 0, stream>>>(x, deltab, g2 + l * 384, be2 + l * 384, x, xb);
    }
    // tmp[i, o*384+y] = sum_x X[i,x] * WbilT[o*384+y, x]   (B read ONCE)
    gemm256_k<false, true><<<dim3(1152, 1, 1), B512, 0, stream>>>(
        xb, wbilT, (const float*)nullptr, tmp, 147456, 384, 0, 0, 0);
    // inter[i][j][o] = sum_y X[j,y] * tmp_i[o,y] + bbil[o]
    gemm256_k<true, true><<<dim3(3, 1, 256), B512, 0, stream>>>(
        xb, tmp, bbil, inter, 384, 384, 0, 147456LL, 98304LL);
    // fused h1 + logits
    h1log256_k<<<dim3(256), B512, 0, stream>>>(inter, wc1b, bc1, Wc2, bc2,
                                               out + 98304 + s * 65536);
    // --- GRU controller (wide) ---
    pool1_k<<<dim3(8), dim3(384), 0, stream>>>(x, partial);
    gih_k<<<dim3(288), B256, 0, stream>>>(Wih, bih, Whh, bhh, partial, rstate, gi, gh);
    gru2_k<<<dim3(1), dim3(384), 0, stream>>>(gi, gh, rstate, hnew);
    p1_k<<<dim3(96), B256, 0, stream>>>(Wp1, bp1, hnew, p1buf);
    cont_k<<<dim3(1), dim3(64), 0, stream>>>(p1buf, Wp2, bp2, out + 98304 + 131072 + s);
  }
  gemm64_k<true, false, false><<<dim3(6, 4), B256, 0, stream>>>(
      xb, woutb, bout, out, 256, 384, 384);
}

// Round 12
// 619.349 us; speedup vs baseline: 1.3027x; 1.0378x over previous
//
#include <hip/hip_runtime.h>

typedef __attribute__((ext_vector_type(4))) float f32x4;
typedef __attribute__((ext_vector_type(8))) short s16x8;

#define DEVI __device__ __forceinline__

DEVI float b2f(short s) {
  union { float f; unsigned u; } v; v.u = ((unsigned)(unsigned short)s) << 16; return v.f;
}
DEVI short f2b(float f) {
  union { float f; unsigned u; } v; v.f = f;
  unsigned u = v.u;
  u += 0x7FFFu + ((u >> 16) & 1u);   // RNE
  return (short)(u >> 16);
}
// fast GELU: tanh form, exp-based; overflow-safe. err ~4e-4 max, ~1e-5 here.
DEVI float gelu_f(float x) {
  float z2 = 1.5957691216f * x * (1.0f + 0.044715f * x * x);
  float e = __expf(z2);
  float th = 1.0f - 2.0f / (e + 1.0f);
  return 0.5f * x * (1.0f + th);
}
DEVI float sigm_f(float x) { return 1.0f / (1.0f + expf(-x)); }

// async global->LDS, 16B per lane; LDS dest = wave-uniform base + lane*16
DEVI void gld16(const short* g, const short* l) {
  __builtin_amdgcn_global_load_lds((const __attribute__((address_space(1))) void*)g,
                                   (__attribute__((address_space(3))) void*)l, 16, 0, 0);
}

// ---------------------------------------------------------------------------
// BM=256 bf16 GEMM: C[256,N] = A[256,K] * B[N,K]^T (+bias). 512 thr, 8 waves
// (4m x 2n), BK=32. Grid (N/128, 1, batch).
// ---------------------------------------------------------------------------
template<bool BIAS, bool OUT_BF16>
__global__ __launch_bounds__(512)
void gemm256_k(const short* __restrict__ A, const short* __restrict__ B,
               const float* __restrict__ bias, void* __restrict__ Cv,
               int N, int K,
               long long sA, long long sB, long long sC)
{
  __shared__ short As[2][256 * 32];
  __shared__ short Bs[2][128 * 32];
  const int bz = blockIdx.z;
  const int n0 = blockIdx.x * 128;
  const int t = threadIdx.x, lane = t & 63, wave = t >> 6;
  const int wm = wave >> 1, wn = wave & 1;
  const short* Ab = A + bz * sA;
  const short* Bb = B + bz * sB;
  const int lr = lane >> 2;
  const int lc = (lane & 3) * 8;
  const int fr = lane & 15, fs = lane >> 4;

  f32x4 acc[4][4];
#pragma unroll
  for (int i = 0; i < 4; ++i)
#pragma unroll
    for (int j = 0; j < 4; ++j) acc[i][j] = f32x4{0.f, 0.f, 0.f, 0.f};

  auto stage = [&](int b, int k0) {
#pragma unroll
    for (int q = 0; q < 2; ++q)
      gld16(Ab + (long long)(q * 128 + wave * 16 + lr) * K + k0 + lc,
            &As[b][(q * 128 + wave * 16) * 32]);
    gld16(Bb + (long long)(n0 + wave * 16 + lr) * K + k0 + lc,
          &Bs[b][wave * 16 * 32]);
  };

  const int NT = K >> 5;
  stage(0, 0);
  __syncthreads();
  for (int tt = 0; tt < NT; ++tt) {
    const int cur = tt & 1;
    if (tt + 1 < NT) stage(cur ^ 1, (tt + 1) << 5);
    s16x8 af[4], bfv[4];
#pragma unroll
    for (int i = 0; i < 4; ++i) af[i]  = *(const s16x8*)&As[cur][(wm * 64 + i * 16 + fr) * 32 + fs * 8];
#pragma unroll
    for (int j = 0; j < 4; ++j) bfv[j] = *(const s16x8*)&Bs[cur][(wn * 64 + j * 16 + fr) * 32 + fs * 8];
#pragma unroll
    for (int i = 0; i < 4; ++i)
#pragma unroll
      for (int j = 0; j < 4; ++j)
        acc[i][j] = __builtin_amdgcn_mfma_f32_16x16x32_bf16(af[i], bfv[j], acc[i][j], 0, 0, 0);
    if (tt + 1 < NT) __syncthreads();
  }

#pragma unroll
  for (int i = 0; i < 4; ++i) {
    int rowb = wm * 64 + i * 16 + fs * 4;
#pragma unroll
    for (int j = 0; j < 4; ++j) {
      int col = n0 + wn * 64 + j * 16 + fr;
      float bb = BIAS ? bias[col] : 0.0f;
#pragma unroll
      for (int u = 0; u < 4; ++u) {
        float v = acc[i][j][u] + bb;
        long long off = bz * sC + (long long)(rowb + u) * N + col;
        if constexpr (OUT_BF16) ((short*)Cv)[off] = f2b(v);
        else                    ((float*)Cv)[off] = v;
      }
    }
  }
}

// ---------------------------------------------------------------------------
// Fused h1+logits, BM=256 full-N.
// ---------------------------------------------------------------------------
__global__ __launch_bounds__(512)
void h1log256_k(const short* __restrict__ inter, const short* __restrict__ Wc1b,
                const float* __restrict__ bc1, const float* __restrict__ Wc2,
                const float* __restrict__ bc2, float* __restrict__ outp)
{
  __shared__ short As[2][256 * 32];
  __shared__ short Bs[2][128 * 32];
  __shared__ float part[256][2];
  const int ib = blockIdx.x;
  const int t = threadIdx.x, lane = t & 63, wave = t >> 6;
  const int wm = wave >> 1, wn = wave & 1;
  const short* Ab = inter + (long long)ib * 98304;
  const int lr = lane >> 2;
  const int lc = (lane & 3) * 8;
  const int fr = lane & 15, fs = lane >> 4;

  float lp[16];
#pragma unroll
  for (int e = 0; e < 16; ++e) lp[e] = 0.f;

  for (int n0 = 0; n0 < 384; n0 += 128) {
    f32x4 acc[4][4];
#pragma unroll
    for (int i = 0; i < 4; ++i)
#pragma unroll
      for (int j = 0; j < 4; ++j) acc[i][j] = f32x4{0.f, 0.f, 0.f, 0.f};

    auto stage = [&](int b, int k0) {
#pragma unroll
      for (int q = 0; q < 2; ++q)
        gld16(Ab + (long long)(q * 128 + wave * 16 + lr) * 384 + k0 + lc,
              &As[b][(q * 128 + wave * 16) * 32]);
      gld16(Wc1b + (long long)(n0 + wave * 16 + lr) * 384 + k0 + lc,
            &Bs[b][wave * 16 * 32]);
    };

    stage(0, 0);
    __syncthreads();
    for (int tt = 0; tt < 12; ++tt) {
      const int cur = tt & 1;
      if (tt + 1 < 12) stage(cur ^ 1, (tt + 1) << 5);
      s16x8 af[4], bfv[4];
#pragma unroll
      for (int i = 0; i < 4; ++i) af[i]  = *(const s16x8*)&As[cur][(wm * 64 + i * 16 + fr) * 32 + fs * 8];
#pragma unroll
      for (int j = 0; j < 4; ++j) bfv[j] = *(const s16x8*)&Bs[cur][(wn * 64 + j * 16 + fr) * 32 + fs * 8];
#pragma unroll
      for (int i = 0; i < 4; ++i)
#pragma unroll
        for (int j = 0; j < 4; ++j)
          acc[i][j] = __builtin_amdgcn_mfma_f32_16x16x32_bf16(af[i], bfv[j], acc[i][j], 0, 0, 0);
      if (tt + 1 < 12) __syncthreads();
    }
#pragma unroll
    for (int i = 0; i < 4; ++i)
#pragma unroll
      for (int j = 0; j < 4; ++j) {
        int col = n0 + wn * 64 + j * 16 + fr;
        float w2 = Wc2[col], b1v = bc1[col];
#pragma unroll
        for (int u = 0; u < 4; ++u)
          lp[i * 4 + u] += gelu_f(acc[i][j][u] + b1v) * w2;
      }
    __syncthreads();
  }
#pragma unroll
  for (int m = 1; m < 16; m <<= 1)
#pragma unroll
    for (int e = 0; e < 16; ++e) lp[e] += __shfl_xor(lp[e], m);
  if (fr == 0) {
#pragma unroll
    for (int e = 0; e < 16; ++e)
      part[wm * 64 + (e >> 2) * 16 + fs * 4 + (e & 3)][wn] = lp[e];
  }
  __syncthreads();
  if (t < 256) outp[ib * 256 + t] = sigm_f(part[t][0] + part[t][1] + bc2[0]);
}

// ---------------------------------------------------------------------------
// 64x64-tile bf16 GEMM, BK=64, XOR-swizzled LDS (rule #21: linear gld16 dest,
// inverse-swizzled global source, swizzled ds_read). Halves the K-loop
// round-trip count vs BK=32. K % 64 == 0.
// ---------------------------------------------------------------------------
template<bool BIAS, bool GELU_ACT, bool OUT_BF16>
__global__ __launch_bounds__(256)
void gemm64_k(const short* __restrict__ A, const short* __restrict__ B,
              const float* __restrict__ bias, void* __restrict__ Cv,
              int M, int N, int K)
{
  __shared__ short As[2][64 * 64];
  __shared__ short Bs[2][64 * 64];
  const int n0 = blockIdx.x * 64;
  const int m0 = blockIdx.y * 64;
  const int t = threadIdx.x, lane = t & 63, wave = t >> 6;
  const int wm = wave >> 1, wn = wave & 1;
  const int srow = lane >> 3;                  // 0..7 row within 8-row chunk
  const int scol = ((lane & 7) ^ srow) * 8;    // inverse-swizzled source col
  const int fr = lane & 15, fs = lane >> 4;

  f32x4 acc[2][2];
#pragma unroll
  for (int i = 0; i < 2; ++i)
#pragma unroll
    for (int j = 0; j < 2; ++j) acc[i][j] = f32x4{0.f, 0.f, 0.f, 0.f};

  auto stage = [&](int b, int k0) {
#pragma unroll
    for (int q = 0; q < 2; ++q) {
      int c = wave * 2 + q;                    // 8-row chunk 0..7
      gld16(A + (long long)(m0 + c * 8 + srow) * K + k0 + scol, &As[b][c * 512]);
      gld16(B + (long long)(n0 + c * 8 + srow) * K + k0 + scol, &Bs[b][c * 512]);
    }
  };

  const int NT = K >> 6;
  stage(0, 0);
  __syncthreads();
  for (int tt = 0; tt < NT; ++tt) {
    const int cur = tt & 1;
    if (tt + 1 < NT) stage(cur ^ 1, (tt + 1) << 6);
    s16x8 af[2][2], bfv[2][2];
#pragma unroll
    for (int i = 0; i < 2; ++i) {
      int row = wm * 32 + i * 16 + fr;
#pragma unroll
      for (int s = 0; s < 2; ++s)
        af[i][s] = *(const s16x8*)&As[cur][row * 64 + (((s * 4 + fs) ^ (fr & 7)) * 8)];
    }
#pragma unroll
    for (int j = 0; j < 2; ++j) {
      int row = wn * 32 + j * 16 + fr;
#pragma unroll
      for (int s = 0; s < 2; ++s)
        bfv[j][s] = *(const s16x8*)&Bs[cur][row * 64 + (((s * 4 + fs) ^ (fr & 7)) * 8)];
    }
#pragma unroll
    for (int s = 0; s < 2; ++s)
#pragma unroll
      for (int i = 0; i < 2; ++i)
#pragma unroll
        for (int j = 0; j < 2; ++j)
          acc[i][j] = __builtin_amdgcn_mfma_f32_16x16x32_bf16(af[i][s], bfv[j][s], acc[i][j], 0, 0, 0);
    if (tt + 1 < NT) __syncthreads();
  }

#pragma unroll
  for (int i = 0; i < 2; ++i) {
    int rowb = m0 + wm * 32 + i * 16 + fs * 4;
#pragma unroll
    for (int j = 0; j < 2; ++j) {
      int col = n0 + wn * 32 + j * 16 + fr;
      float bb = BIAS ? bias[col] : 0.0f;
#pragma unroll
      for (int u = 0; u < 4; ++u) {
        float v = acc[i][j][u] + bb;
        if constexpr (GELU_ACT) v = gelu_f(v);
        long long off = (long long)(rowb + u) * N + col;
        if constexpr (OUT_BF16) ((short*)Cv)[off] = f2b(v);
        else                    ((float*)Cv)[off] = v;
      }
    }
  }
}

// ---------------------------------------------------------------------------
// Wbil [o][x][y] fp32  ->  WbilT [o][y][x] bf16   (64x64 tiles via LDS)
// ---------------------------------------------------------------------------
__global__ __launch_bounds__(256)
void transpose_k(const float* __restrict__ W, short* __restrict__ WT)
{
  __shared__ short L[64 * 68];
  const int o  = blockIdx.z;
  const int x0 = blockIdx.x * 64, y0 = blockIdx.y * 64;
  const float* Wo = W  + (long long)o * 147456;
  short*      WTo = WT + (long long)o * 147456;
  const int t  = threadIdx.x;
  const int rr = t >> 4;
  const int cc = (t & 15) * 4;
#pragma unroll
  for (int q = 0; q < 4; ++q) {
    int xl = rr + 16 * q;
    float4 v = *(const float4*)(Wo + (x0 + xl) * 384 + y0 + cc);
    short4 p; p.x = f2b(v.x); p.y = f2b(v.y); p.z = f2b(v.z); p.w = f2b(v.w);
    *(short4*)&L[xl * 68 + cc] = p;
  }
  __syncthreads();
#pragma unroll
  for (int q = 0; q < 4; ++q) {
    int yl = rr + 16 * q;
    short4 p;
    p.x = L[(cc + 0) * 68 + yl];
    p.y = L[(cc + 1) * 68 + yl];
    p.z = L[(cc + 2) * 68 + yl];
    p.w = L[(cc + 3) * 68 + yl];
    *(short4*)(WTo + (y0 + yl) * 384 + x0 + cc) = p;
  }
}

// ---------------------------------------------------------------------------
// Convert ALL layer weights fp32->bf16 in ONE dispatch.
// ---------------------------------------------------------------------------
__global__ __launch_bounds__(256)
void convall_k(const float* __restrict__ Wc1, const float* __restrict__ Wqkv,
               const float* __restrict__ Wo, const float* __restrict__ W1,
               const float* __restrict__ W2, const float* __restrict__ Wout,
               short* __restrict__ Dc1, short* __restrict__ Dqkv,
               short* __restrict__ Do, short* __restrict__ D1,
               short* __restrict__ D2, short* __restrict__ Dout)
{
  long long i4 = ((long long)blockIdx.x * 256 + threadIdx.x) * 4;
  const float* s; short* d; long long off;
  if      (i4 <  147456) { s = Wc1;  d = Dc1;  off = 0; }
  else if (i4 < 1032192) { s = Wqkv; d = Dqkv; off = 147456; }
  else if (i4 < 1327104) { s = Wo;   d = Do;   off = 1032192; }
  else if (i4 < 2506752) { s = W1;   d = D1;   off = 1327104; }
  else if (i4 < 3686400) { s = W2;   d = D2;   off = 2506752; }
  else if (i4 < 3833856) { s = Wout; d = Dout; off = 3686400; }
  else return;
  long long l = i4 - off;
  float4 v = *(const float4*)(s + l);
  short4 p; p.x = f2b(v.x); p.y = f2b(v.y); p.z = f2b(v.z); p.w = f2b(v.w);
  *(short4*)(d + l) = p;
}

// ---------------------------------------------------------------------------
// Attention: qkv fp32 [256][1152] -> out bf16 [256][384]. d=48, NH=8.
// K/V staging vectorized (float4).
// ---------------------------------------------------------------------------
__global__ __launch_bounds__(256)
void attn_k(const float* __restrict__ qkv, short* __restrict__ outb)
{
  __shared__ short Ks[256 * 48];
  __shared__ short Vs[256 * 48];
  __shared__ float Ps[32][258];
  const int h  = blockIdx.y;
  const int q0 = blockIdx.x * 32;
  const int t = threadIdx.x, lane = t & 63, wave = t >> 6;
  for (int idx = t; idx < 3072; idx += 256) {
    int j = idx / 12, d4 = (idx - (idx / 12) * 12) * 4;
    const float* base = qkv + j * 1152 + h * 48 + d4;
    float4 kv = *(const float4*)(base + 384);
    float4 vv = *(const float4*)(base + 768);
    short4 pk; pk.x = f2b(kv.x); pk.y = f2b(kv.y); pk.z = f2b(kv.z); pk.w = f2b(kv.w);
    short4 pv; pv.x = f2b(vv.x); pv.y = f2b(vv.y); pv.z = f2b(vv.z); pv.w = f2b(vv.w);
    *(short4*)&Ks[j * 48 + d4] = pk;
    *(short4*)&Vs[j * 48 + d4] = pv;
  }
  __syncthreads();
  const int part = lane & 7;
  const int rl   = wave * 8 + (lane >> 3);
  const int row  = q0 + rl;
  float q[48];
#pragma unroll
  for (int d = 0; d < 48; ++d) q[d] = qkv[row * 1152 + h * 48 + d] * 0.14433756729740644f;
  float mx = -1e30f;
  for (int jj = 0; jj < 32; ++jj) {
    int j = jj * 8 + part;
    float a = 0.f;
#pragma unroll
    for (int dd = 0; dd < 12; ++dd) {
      short4 kk = *(const short4*)&Ks[j * 48 + dd * 4];
      a += q[dd*4+0]*b2f(kk.x) + q[dd*4+1]*b2f(kk.y) + q[dd*4+2]*b2f(kk.z) + q[dd*4+3]*b2f(kk.w);
    }
    Ps[rl][j] = a;
    mx = fmaxf(mx, a);
  }
  mx = fmaxf(mx, __shfl_xor(mx, 1));
  mx = fmaxf(mx, __shfl_xor(mx, 2));
  mx = fmaxf(mx, __shfl_xor(mx, 4));
  float sum = 0.f;
  for (int jj = 0; jj < 32; ++jj) {
    int j = jj * 8 + part;
    float e = expf(Ps[rl][j] - mx);
    Ps[rl][j] = e;
    sum += e;
  }
  sum += __shfl_xor(sum, 1); sum += __shfl_xor(sum, 2); sum += __shfl_xor(sum, 4);
  const float inv = 1.f / sum;
  __syncthreads();
  float o[6] = {0.f, 0.f, 0.f, 0.f, 0.f, 0.f};
  const int vb = part * 6;
  for (int j = 0; j < 256; ++j) {
    float p = Ps[rl][j];
    int base = j * 48 + vb;
#pragma unroll
    for (int dd = 0; dd < 3; ++dd) {
      short2 vv = *(const short2*)&Vs[base + dd * 2];
      o[dd*2]   += p * b2f(vv.x);
      o[dd*2+1] += p * b2f(vv.y);
    }
  }
#pragma unroll
  for (int d = 0; d < 6; ++d) outb[row * 384 + h * 48 + vb + d] = f2b(o[d] * inv);
}

// ---------------------------------------------------------------------------
// LayerNorm(x + delta_bf16)*g + b  -> xo fp32, xob bf16.  256 blocks x 128 thr.
// ---------------------------------------------------------------------------
__global__ __launch_bounds__(128)
void ln_k(const float* __restrict__ x, const short* __restrict__ d,
          const float* __restrict__ g, const float* __restrict__ b,
          float* __restrict__ xo, short* __restrict__ xob)
{
  const int row = blockIdx.x, t = threadIdx.x;
  float v[3]; float s = 0.f, ss = 0.f;
#pragma unroll
  for (int i = 0; i < 3; ++i) {
    int c = t + 128 * i;
    float u = x[row * 384 + c] + b2f(d[row * 384 + c]);
    v[i] = u; s += u; ss += u * u;
  }
#pragma unroll
  for (int m = 1; m < 64; m <<= 1) { s += __shfl_xor(s, m); ss += __shfl_xor(ss, m); }
  __shared__ float sh[4];
  if ((t & 63) == 0) { sh[(t >> 6) * 2] = s; sh[(t >> 6) * 2 + 1] = ss; }
  __syncthreads();
  s = sh[0] + sh[2]; ss = sh[1] + sh[3];
  float mean = s * (1.f / 384.f);
  float var  = ss * (1.f / 384.f) - mean * mean;
  float rstd = rsqrtf(var + 1e-5f);
#pragma unroll
  for (int i = 0; i < 3; ++i) {
    int c = t + 128 * i;
    float y = (v[i] - mean) * rstd * g[c] + b[c];
    xo[row * 384 + c]  = y;
    xob[row * 384 + c] = f2b(y);
  }
}

__global__ void init_k(const float* __restrict__ hs, float* __restrict__ x,
                       short* __restrict__ xb, float* __restrict__ rstate)
{
  int i = blockIdx.x * 256 + threadIdx.x;
  if (i < 98304) { float v = hs[i]; x[i] = v; xb[i] = f2b(v); }
  if (i < 384) rstate[i] = 0.f;
}

// ---------------------------------------------------------------------------
// GRU, wide: pool1 -> gih -> gru2 -> p1 (96 blocks) -> cont
// ---------------------------------------------------------------------------
__global__ __launch_bounds__(384)
void pool1_k(const float* __restrict__ x, float* __restrict__ partial)
{
  const int t = threadIdx.x, p = blockIdx.x;
  float s = 0.f;
  const float* xr = x + p * 32 * 384;
#pragma unroll 4
  for (int i = 0; i < 32; ++i) s += xr[i * 384 + t];
  partial[p * 384 + t] = s;
}

__global__ __launch_bounds__(256)
void gih_k(const float* __restrict__ Wih, const float* __restrict__ bih,
           const float* __restrict__ Whh, const float* __restrict__ bhh,
           const float* __restrict__ partial, const float* __restrict__ rstate,
           float* __restrict__ gi, float* __restrict__ gh)
{
  const int t = threadIdx.x, lane = t & 63, wave = t >> 6;
  const int r = blockIdx.x * 4 + wave;
  float a = 0.f, b = 0.f;
#pragma unroll
  for (int e = 0; e < 6; ++e) {
    int c = lane + 64 * e;
    float pc = 0.f;
#pragma unroll
    for (int p = 0; p < 8; ++p) pc += partial[p * 384 + c];
    pc *= (1.f / 256.f);
    a += Wih[r * 384 + c] * pc;
    b += Whh[r * 384 + c] * rstate[c];
  }
#pragma unroll
  for (int m = 1; m < 64; m <<= 1) { a += __shfl_xor(a, m); b += __shfl_xor(b, m); }
  if (lane == 0) { gi[r] = a + bih[r]; gh[r] = b + bhh[r]; }
}

__global__ __launch_bounds__(384)
void gru2_k(const float* __restrict__ gi, const float* __restrict__ gh,
            float* __restrict__ rstate, float* __restrict__ hnew)
{
  const int t = threadIdx.x;
  float r = sigm_f(gi[t] + gh[t]);
  float z = sigm_f(gi[384 + t] + gh[384 + t]);
  float n = tanhf(gi[768 + t] + r * gh[768 + t]);
  float h = (1.f - z) * n + z * rstate[t];
  rstate[t] = h;
  hnew[t] = h;
}

__global__ __launch_bounds__(256)
void p1_k(const float* __restrict__ Wp1, const float* __restrict__ bp1,
          const float* __restrict__ hnew, float* __restrict__ p1)
{
  const int t = threadIdx.x, lane = t & 63, wave = t >> 6;
  const int r = blockIdx.x * 4 + wave;
  float a = 0.f;
#pragma unroll
  for (int e = 0; e < 6; ++e) { int c = lane + 64 * e; a += Wp1[r * 384 + c] * hnew[c]; }
#pragma unroll
  for (int m = 1; m < 64; m <<= 1) a += __shfl_xor(a, m);
  if (lane == 0) p1[r] = gelu_f(a + bp1[r]);
}

__global__ __launch_bounds__(64)
void cont_k(const float* __restrict__ p1, const float* __restrict__ Wp2,
            const float* __restrict__ bp2, float* __restrict__ out_cont)
{
  const int lane = threadIdx.x;
  float a = 0.f;
#pragma unroll
  for (int e = 0; e < 6; ++e) { int c = lane + 64 * e; a += p1[c] * Wp2[c]; }
#pragma unroll
  for (int m = 1; m < 64; m <<= 1) a += __shfl_xor(a, m);
  if (lane == 0) out_cont[0] = sigm_f(a + bp2[0]);
}

// ---------------------------------------------------------------------------
extern "C" void kernel_launch(void* const* d_in, const int* in_sizes, int n_in,
                              void* d_out, int out_size, void* d_ws, size_t ws_size,
                              hipStream_t stream)
{
  const float* hs   = (const float*)d_in[0];
  const float* Wqkv = (const float*)d_in[1];
  const float* bqkv = (const float*)d_in[2];
  const float* Wo   = (const float*)d_in[3];
  const float* bo   = (const float*)d_in[4];
  const float* W1   = (const float*)d_in[5];
  const float* b1   = (const float*)d_in[6];
  const float* W2   = (const float*)d_in[7];
  const float* b2   = (const float*)d_in[8];
  const float* g1   = (const float*)d_in[9];
  const float* be1  = (const float*)d_in[10];
  const float* g2   = (const float*)d_in[11];
  const float* be2  = (const float*)d_in[12];
  const float* Wbil = (const float*)d_in[13];
  const float* bbil = (const float*)d_in[14];
  const float* Wc1  = (const float*)d_in[15];
  const float* bc1  = (const float*)d_in[16];
  const float* Wc2  = (const float*)d_in[17];
  const float* bc2  = (const float*)d_in[18];
  const float* Wih  = (const float*)d_in[19];
  const float* bih  = (const float*)d_in[20];
  const float* Whh  = (const float*)d_in[21];
  const float* bhh  = (const float*)d_in[22];
  const float* Wp1  = (const float*)d_in[23];
  const float* bp1  = (const float*)d_in[24];
  const float* Wp2  = (const float*)d_in[25];
  const float* bp2  = (const float*)d_in[26];
  const float* Wout = (const float*)d_in[27];
  const float* bout = (const float*)d_in[28];
  float* out = (float*)d_out;

  char* ws = (char*)d_ws;
  size_t off = 0;
  auto alloc = [&](size_t bytes) -> char* {
    char* p = ws + off; off += (bytes + 255) & ~(size_t)255; return p;
  };
  short* wbilT   = (short*)alloc(56623104ULL * 2);
  short* tmp     = (short*)alloc(256ULL * 147456 * 2);
  short* inter   = (short*)alloc(256ULL * 98304 * 2);
  float* x       = (float*)alloc(98304 * 4);
  short* xb      = (short*)alloc(98304 * 2);
  float* qkv     = (float*)alloc(294912 * 4);
  short* attnb   = (short*)alloc(98304 * 2);
  short* deltab  = (short*)alloc(98304 * 2);
  short* ff1b    = (short*)alloc(393216 * 2);
  float* rstate  = (float*)alloc(384 * 4);
  float* partial = (float*)alloc(8 * 384 * 4);
  float* gi      = (float*)alloc(1152 * 4);
  float* gh      = (float*)alloc(1152 * 4);
  float* hnew    = (float*)alloc(384 * 4);
  float* p1buf   = (float*)alloc(384 * 4);
  short* wc1b    = (short*)alloc(147456 * 2);
  short* wqkvb   = (short*)alloc(884736ULL * 2);
  short* wob     = (short*)alloc(294912ULL * 2);
  short* w1b     = (short*)alloc(1179648ULL * 2);
  short* w2b     = (short*)alloc(1179648ULL * 2);
  short* woutb   = (short*)alloc(147456 * 2);
  (void)ws_size; (void)in_sizes; (void)n_in; (void)out_size;

  dim3 B256(256);
  dim3 B512(512);

  init_k<<<dim3(384), B256, 0, stream>>>(hs, x, xb, rstate);
  transpose_k<<<dim3(6, 6, 384), B256, 0, stream>>>(Wbil, wbilT);
  convall_k<<<dim3(3744), B256, 0, stream>>>(Wc1, Wqkv, Wo, W1, W2, Wout,
                                             wc1b, wqkvb, wob, w1b, w2b, woutb);

  for (int s = 0; s < 2; ++s) {
    for (int l = 0; l < 2; ++l) {
      gemm64_k<true, false, false><<<dim3(18, 4), B256, 0, stream>>>(
          xb, wqkvb + l * 442368, bqkv + l * 1152, qkv, 256, 1152, 384);
      attn_k<<<dim3(8, 8), B256, 0, stream>>>(qkv, attnb);
      gemm64_k<true, false, true><<<dim3(6, 4), B256, 0, stream>>>(
          attnb, wob + l * 147456, bo + l * 384, deltab, 256, 384, 384);
      ln_k<<<dim3(256), dim3(128), 0, stream>>>(x, deltab, g1 + l * 384, be1 + l * 384, x, xb);
      gemm64_k<true, true, true><<<dim3(24, 4), B256, 0, stream>>>(
          xb, w1b + l * 589824, b1 + l * 1536, ff1b, 256, 1536, 384);
      gemm64_k<true, false, true><<<dim3(6, 4), B256, 0, stream>>>(
          ff1b, w2b + l * 589824, b2 + l * 384, deltab, 256, 384, 1536);
      ln_k<<<dim3(256), dim3(128), 0, stream>>>(x, deltab, g2 + l * 384, be2 + l * 384, x, xb);
    }
    // tmp[i, o*384+y] = sum_x X[i,x] * WbilT[o*384+y, x]   (B read ONCE)
    gemm256_k<false, true><<<dim3(1152, 1, 1), B512, 0, stream>>>(
        xb, wbilT, (const float*)nullptr, tmp, 147456, 384, 0, 0, 0);
    // inter[i][j][o] = sum_y X[j,y] * tmp_i[o,y] + bbil[o]
    gemm256_k<true, true><<<dim3(3, 1, 256), B512, 0, stream>>>(
        xb, tmp, bbil, inter, 384, 384, 0, 147456LL, 98304LL);
    // fused h1 + logits
    h1log256_k<<<dim3(256), B512, 0, stream>>>(inter, wc1b, bc1, Wc2, bc2,
                                               out + 98304 + s * 65536);
    // --- GRU controller (wide) ---
    pool1_k<<<dim3(8), dim3(384), 0, stream>>>(x, partial);
    gih_k<<<dim3(288), B256, 0, stream>>>(Wih, bih, Whh, bhh, partial, rstate, gi, gh);
    gru2_k<<<dim3(1), dim3(384), 0, stream>>>(gi, gh, rstate, hnew);
    p1_k<<<dim3(96), B256, 0, stream>>>(Wp1, bp1, hnew, p1buf);
    cont_k<<<dim3(1), dim3(64), 0, stream>>>(p1buf, Wp2, bp2, out + 98304 + 131072 + s);
  }
  gemm64_k<true, false, false><<<dim3(6, 4), B256, 0, stream>>>(
      xb, woutb, bout, out, 256, 384, 384);
}

// Round 13
// 607.381 us; speedup vs baseline: 1.3284x; 1.0197x over previous
//
#include <hip/hip_runtime.h>

typedef __attribute__((ext_vector_type(4))) float f32x4;
typedef __attribute__((ext_vector_type(8))) short s16x8;

#define DEVI __device__ __forceinline__

DEVI float b2f(short s) {
  union { float f; unsigned u; } v; v.u = ((unsigned)(unsigned short)s) << 16; return v.f;
}
DEVI short f2b(float f) {
  union { float f; unsigned u; } v; v.f = f;
  unsigned u = v.u;
  u += 0x7FFFu + ((u >> 16) & 1u);   // RNE
  return (short)(u >> 16);
}
// fast GELU: tanh form, exp-based; overflow-safe. err ~4e-4 max, ~1e-5 here.
DEVI float gelu_f(float x) {
  float z2 = 1.5957691216f * x * (1.0f + 0.044715f * x * x);
  float e = __expf(z2);
  float th = 1.0f - 2.0f / (e + 1.0f);
  return 0.5f * x * (1.0f + th);
}
DEVI float sigm_f(float x) { return 1.0f / (1.0f + expf(-x)); }

// async global->LDS, 16B per lane; LDS dest = wave-uniform base + lane*16
DEVI void gld16(const short* g, const short* l) {
  __builtin_amdgcn_global_load_lds((const __attribute__((address_space(1))) void*)g,
                                   (__attribute__((address_space(3))) void*)l, 16, 0, 0);
}

// ---------------------------------------------------------------------------
// BM=256 bf16 GEMM: C[256,N] = A[256,K] * B[N,K]^T (+bias). 512 thr, 8 waves
// (4m x 2n), BK=32. Grid (N/128, 1, batch). Kept BK=32: grids of 768-1152
// blocks rely on 2-3 blocks/CU (48KB LDS) for latency hiding.
// ---------------------------------------------------------------------------
template<bool BIAS, bool OUT_BF16>
__global__ __launch_bounds__(512)
void gemm256_k(const short* __restrict__ A, const short* __restrict__ B,
               const float* __restrict__ bias, void* __restrict__ Cv,
               int N, int K,
               long long sA, long long sB, long long sC)
{
  __shared__ short As[2][256 * 32];
  __shared__ short Bs[2][128 * 32];
  const int bz = blockIdx.z;
  const int n0 = blockIdx.x * 128;
  const int t = threadIdx.x, lane = t & 63, wave = t >> 6;
  const int wm = wave >> 1, wn = wave & 1;
  const short* Ab = A + bz * sA;
  const short* Bb = B + bz * sB;
  const int lr = lane >> 2;
  const int lc = (lane & 3) * 8;
  const int fr = lane & 15, fs = lane >> 4;

  f32x4 acc[4][4];
#pragma unroll
  for (int i = 0; i < 4; ++i)
#pragma unroll
    for (int j = 0; j < 4; ++j) acc[i][j] = f32x4{0.f, 0.f, 0.f, 0.f};

  auto stage = [&](int b, int k0) {
#pragma unroll
    for (int q = 0; q < 2; ++q)
      gld16(Ab + (long long)(q * 128 + wave * 16 + lr) * K + k0 + lc,
            &As[b][(q * 128 + wave * 16) * 32]);
    gld16(Bb + (long long)(n0 + wave * 16 + lr) * K + k0 + lc,
          &Bs[b][wave * 16 * 32]);
  };

  const int NT = K >> 5;
  stage(0, 0);
  __syncthreads();
  for (int tt = 0; tt < NT; ++tt) {
    const int cur = tt & 1;
    if (tt + 1 < NT) stage(cur ^ 1, (tt + 1) << 5);
    s16x8 af[4], bfv[4];
#pragma unroll
    for (int i = 0; i < 4; ++i) af[i]  = *(const s16x8*)&As[cur][(wm * 64 + i * 16 + fr) * 32 + fs * 8];
#pragma unroll
    for (int j = 0; j < 4; ++j) bfv[j] = *(const s16x8*)&Bs[cur][(wn * 64 + j * 16 + fr) * 32 + fs * 8];
#pragma unroll
    for (int i = 0; i < 4; ++i)
#pragma unroll
      for (int j = 0; j < 4; ++j)
        acc[i][j] = __builtin_amdgcn_mfma_f32_16x16x32_bf16(af[i], bfv[j], acc[i][j], 0, 0, 0);
    if (tt + 1 < NT) __syncthreads();
  }

#pragma unroll
  for (int i = 0; i < 4; ++i) {
    int rowb = wm * 64 + i * 16 + fs * 4;
#pragma unroll
    for (int j = 0; j < 4; ++j) {
      int col = n0 + wn * 64 + j * 16 + fr;
      float bb = BIAS ? bias[col] : 0.0f;
#pragma unroll
      for (int u = 0; u < 4; ++u) {
        float v = acc[i][j][u] + bb;
        long long off = bz * sC + (long long)(rowb + u) * N + col;
        if constexpr (OUT_BF16) ((short*)Cv)[off] = f2b(v);
        else                    ((float*)Cv)[off] = v;
      }
    }
  }
}

// ---------------------------------------------------------------------------
// Fused h1+logits, BM=256 full-N. BK=64 double-buffered, XOR-swizzled LDS
// (rule #21). grid=256 -> 1 block/CU, so 98KB LDS costs no occupancy.
// 3 n0-passes x 6 K-iters (was 12).
// ---------------------------------------------------------------------------
__global__ __launch_bounds__(512)
void h1log256_k(const short* __restrict__ inter, const short* __restrict__ Wc1b,
                const float* __restrict__ bc1, const float* __restrict__ Wc2,
                const float* __restrict__ bc2, float* __restrict__ outp)
{
  __shared__ short As[2][256 * 64];
  __shared__ short Bs[2][128 * 64];
  __shared__ float part[256][2];
  const int ib = blockIdx.x;
  const int t = threadIdx.x, lane = t & 63, wave = t >> 6;
  const int wm = wave >> 1, wn = wave & 1;
  const short* Ab = inter + (long long)ib * 98304;
  const int srow = lane >> 3;                  // 0..7 row within 8-row chunk
  const int scol = ((lane & 7) ^ srow) * 8;    // inverse-swizzled source col
  const int fr = lane & 15, fs = lane >> 4;

  float lp[16];
#pragma unroll
  for (int e = 0; e < 16; ++e) lp[e] = 0.f;

  for (int n0 = 0; n0 < 384; n0 += 128) {
    f32x4 acc[4][4];
#pragma unroll
    for (int i = 0; i < 4; ++i)
#pragma unroll
      for (int j = 0; j < 4; ++j) acc[i][j] = f32x4{0.f, 0.f, 0.f, 0.f};

    auto stage = [&](int b, int k0) {
      // A: 32 8-row chunks; each wave stages 4. B: 16 chunks; each wave 2.
#pragma unroll
      for (int q = 0; q < 4; ++q) {
        int c = wave * 4 + q;
        gld16(Ab + (long long)(c * 8 + srow) * 384 + k0 + scol, &As[b][c * 512]);
      }
#pragma unroll
      for (int q = 0; q < 2; ++q) {
        int c = wave * 2 + q;
        gld16(Wc1b + (long long)(n0 + c * 8 + srow) * 384 + k0 + scol, &Bs[b][c * 512]);
      }
    };

    stage(0, 0);
    __syncthreads();
    for (int tt = 0; tt < 6; ++tt) {
      const int cur = tt & 1;
      if (tt + 1 < 6) stage(cur ^ 1, (tt + 1) << 6);
      s16x8 af[4][2], bfv[4][2];
#pragma unroll
      for (int i = 0; i < 4; ++i) {
        int row = wm * 64 + i * 16 + fr;
#pragma unroll
        for (int s = 0; s < 2; ++s)
          af[i][s] = *(const s16x8*)&As[cur][row * 64 + (((s * 4 + fs) ^ (fr & 7)) * 8)];
      }
#pragma unroll
      for (int j = 0; j < 4; ++j) {
        int row = wn * 64 + j * 16 + fr;
#pragma unroll
        for (int s = 0; s < 2; ++s)
          bfv[j][s] = *(const s16x8*)&Bs[cur][row * 64 + (((s * 4 + fs) ^ (fr & 7)) * 8)];
      }
#pragma unroll
      for (int s = 0; s < 2; ++s)
#pragma unroll
        for (int i = 0; i < 4; ++i)
#pragma unroll
          for (int j = 0; j < 4; ++j)
            acc[i][j] = __builtin_amdgcn_mfma_f32_16x16x32_bf16(af[i][s], bfv[j][s], acc[i][j], 0, 0, 0);
      __syncthreads();   // also covers the n0-loop restage hazard
    }
#pragma unroll
    for (int i = 0; i < 4; ++i)
#pragma unroll
      for (int j = 0; j < 4; ++j) {
        int col = n0 + wn * 64 + j * 16 + fr;
        float w2 = Wc2[col], b1v = bc1[col];
#pragma unroll
        for (int u = 0; u < 4; ++u)
          lp[i * 4 + u] += gelu_f(acc[i][j][u] + b1v) * w2;
      }
  }
#pragma unroll
  for (int m = 1; m < 16; m <<= 1)
#pragma unroll
    for (int e = 0; e < 16; ++e) lp[e] += __shfl_xor(lp[e], m);
  if (fr == 0) {
#pragma unroll
    for (int e = 0; e < 16; ++e)
      part[wm * 64 + (e >> 2) * 16 + fs * 4 + (e & 3)][wn] = lp[e];
  }
  __syncthreads();
  if (t < 256) outp[ib * 256 + t] = sigm_f(part[t][0] + part[t][1] + bc2[0]);
}

// ---------------------------------------------------------------------------
// 64x64-tile bf16 GEMM, BK=64, XOR-swizzled LDS (layer GEMMs).
// ---------------------------------------------------------------------------
template<bool BIAS, bool GELU_ACT, bool OUT_BF16>
__global__ __launch_bounds__(256)
void gemm64_k(const short* __restrict__ A, const short* __restrict__ B,
              const float* __restrict__ bias, void* __restrict__ Cv,
              int M, int N, int K)
{
  __shared__ short As[2][64 * 64];
  __shared__ short Bs[2][64 * 64];
  const int n0 = blockIdx.x * 64;
  const int m0 = blockIdx.y * 64;
  const int t = threadIdx.x, lane = t & 63, wave = t >> 6;
  const int wm = wave >> 1, wn = wave & 1;
  const int srow = lane >> 3;
  const int scol = ((lane & 7) ^ srow) * 8;
  const int fr = lane & 15, fs = lane >> 4;

  f32x4 acc[2][2];
#pragma unroll
  for (int i = 0; i < 2; ++i)
#pragma unroll
    for (int j = 0; j < 2; ++j) acc[i][j] = f32x4{0.f, 0.f, 0.f, 0.f};

  auto stage = [&](int b, int k0) {
#pragma unroll
    for (int q = 0; q < 2; ++q) {
      int c = wave * 2 + q;
      gld16(A + (long long)(m0 + c * 8 + srow) * K + k0 + scol, &As[b][c * 512]);
      gld16(B + (long long)(n0 + c * 8 + srow) * K + k0 + scol, &Bs[b][c * 512]);
    }
  };

  const int NT = K >> 6;
  stage(0, 0);
  __syncthreads();
  for (int tt = 0; tt < NT; ++tt) {
    const int cur = tt & 1;
    if (tt + 1 < NT) stage(cur ^ 1, (tt + 1) << 6);
    s16x8 af[2][2], bfv[2][2];
#pragma unroll
    for (int i = 0; i < 2; ++i) {
      int row = wm * 32 + i * 16 + fr;
#pragma unroll
      for (int s = 0; s < 2; ++s)
        af[i][s] = *(const s16x8*)&As[cur][row * 64 + (((s * 4 + fs) ^ (fr & 7)) * 8)];
    }
#pragma unroll
    for (int j = 0; j < 2; ++j) {
      int row = wn * 32 + j * 16 + fr;
#pragma unroll
      for (int s = 0; s < 2; ++s)
        bfv[j][s] = *(const s16x8*)&Bs[cur][row * 64 + (((s * 4 + fs) ^ (fr & 7)) * 8)];
    }
#pragma unroll
    for (int s = 0; s < 2; ++s)
#pragma unroll
      for (int i = 0; i < 2; ++i)
#pragma unroll
        for (int j = 0; j < 2; ++j)
          acc[i][j] = __builtin_amdgcn_mfma_f32_16x16x32_bf16(af[i][s], bfv[j][s], acc[i][j], 0, 0, 0);
    if (tt + 1 < NT) __syncthreads();
  }

#pragma unroll
  for (int i = 0; i < 2; ++i) {
    int rowb = m0 + wm * 32 + i * 16 + fs * 4;
#pragma unroll
    for (int j = 0; j < 2; ++j) {
      int col = n0 + wn * 32 + j * 16 + fr;
      float bb = BIAS ? bias[col] : 0.0f;
#pragma unroll
      for (int u = 0; u < 4; ++u) {
        float v = acc[i][j][u] + bb;
        if constexpr (GELU_ACT) v = gelu_f(v);
        long long off = (long long)(rowb + u) * N + col;
        if constexpr (OUT_BF16) ((short*)Cv)[off] = f2b(v);
        else                    ((float*)Cv)[off] = v;
      }
    }
  }
}

// ---------------------------------------------------------------------------
// Wbil [o][x][y] fp32  ->  WbilT [o][y][x] bf16   (64x64 tiles via LDS)
// ---------------------------------------------------------------------------
__global__ __launch_bounds__(256)
void transpose_k(const float* __restrict__ W, short* __restrict__ WT)
{
  __shared__ short L[64 * 68];
  const int o  = blockIdx.z;
  const int x0 = blockIdx.x * 64, y0 = blockIdx.y * 64;
  const float* Wo = W  + (long long)o * 147456;
  short*      WTo = WT + (long long)o * 147456;
  const int t  = threadIdx.x;
  const int rr = t >> 4;
  const int cc = (t & 15) * 4;
#pragma unroll
  for (int q = 0; q < 4; ++q) {
    int xl = rr + 16 * q;
    float4 v = *(const float4*)(Wo + (x0 + xl) * 384 + y0 + cc);
    short4 p; p.x = f2b(v.x); p.y = f2b(v.y); p.z = f2b(v.z); p.w = f2b(v.w);
    *(short4*)&L[xl * 68 + cc] = p;
  }
  __syncthreads();
#pragma unroll
  for (int q = 0; q < 4; ++q) {
    int yl = rr + 16 * q;
    short4 p;
    p.x = L[(cc + 0) * 68 + yl];
    p.y = L[(cc + 1) * 68 + yl];
    p.z = L[(cc + 2) * 68 + yl];
    p.w = L[(cc + 3) * 68 + yl];
    *(short4*)(WTo + (y0 + yl) * 384 + x0 + cc) = p;
  }
}

// ---------------------------------------------------------------------------
// Convert ALL layer weights fp32->bf16 in ONE dispatch.
// ---------------------------------------------------------------------------
__global__ __launch_bounds__(256)
void convall_k(const float* __restrict__ Wc1, const float* __restrict__ Wqkv,
               const float* __restrict__ Wo, const float* __restrict__ W1,
               const float* __restrict__ W2, const float* __restrict__ Wout,
               short* __restrict__ Dc1, short* __restrict__ Dqkv,
               short* __restrict__ Do, short* __restrict__ D1,
               short* __restrict__ D2, short* __restrict__ Dout)
{
  long long i4 = ((long long)blockIdx.x * 256 + threadIdx.x) * 4;
  const float* s; short* d; long long off;
  if      (i4 <  147456) { s = Wc1;  d = Dc1;  off = 0; }
  else if (i4 < 1032192) { s = Wqkv; d = Dqkv; off = 147456; }
  else if (i4 < 1327104) { s = Wo;   d = Do;   off = 1032192; }
  else if (i4 < 2506752) { s = W1;   d = D1;   off = 1327104; }
  else if (i4 < 3686400) { s = W2;   d = D2;   off = 2506752; }
  else if (i4 < 3833856) { s = Wout; d = Dout; off = 3686400; }
  else return;
  long long l = i4 - off;
  float4 v = *(const float4*)(s + l);
  short4 p; p.x = f2b(v.x); p.y = f2b(v.y); p.z = f2b(v.z); p.w = f2b(v.w);
  *(short4*)(d + l) = p;
}

// ---------------------------------------------------------------------------
// Attention: qkv fp32 [256][1152] -> out bf16 [256][384]. d=48, NH=8.
// ---------------------------------------------------------------------------
__global__ __launch_bounds__(256)
void attn_k(const float* __restrict__ qkv, short* __restrict__ outb)
{
  __shared__ short Ks[256 * 48];
  __shared__ short Vs[256 * 48];
  __shared__ float Ps[32][258];
  const int h  = blockIdx.y;
  const int q0 = blockIdx.x * 32;
  const int t = threadIdx.x, lane = t & 63, wave = t >> 6;
  for (int idx = t; idx < 3072; idx += 256) {
    int j = idx / 12, d4 = (idx - (idx / 12) * 12) * 4;
    const float* base = qkv + j * 1152 + h * 48 + d4;
    float4 kv = *(const float4*)(base + 384);
    float4 vv = *(const float4*)(base + 768);
    short4 pk; pk.x = f2b(kv.x); pk.y = f2b(kv.y); pk.z = f2b(kv.z); pk.w = f2b(kv.w);
    short4 pv; pv.x = f2b(vv.x); pv.y = f2b(vv.y); pv.z = f2b(vv.z); pv.w = f2b(vv.w);
    *(short4*)&Ks[j * 48 + d4] = pk;
    *(short4*)&Vs[j * 48 + d4] = pv;
  }
  __syncthreads();
  const int part = lane & 7;
  const int rl   = wave * 8 + (lane >> 3);
  const int row  = q0 + rl;
  float q[48];
#pragma unroll
  for (int d = 0; d < 48; ++d) q[d] = qkv[row * 1152 + h * 48 + d] * 0.14433756729740644f;
  float mx = -1e30f;
  for (int jj = 0; jj < 32; ++jj) {
    int j = jj * 8 + part;
    float a = 0.f;
#pragma unroll
    for (int dd = 0; dd < 12; ++dd) {
      short4 kk = *(const short4*)&Ks[j * 48 + dd * 4];
      a += q[dd*4+0]*b2f(kk.x) + q[dd*4+1]*b2f(kk.y) + q[dd*4+2]*b2f(kk.z) + q[dd*4+3]*b2f(kk.w);
    }
    Ps[rl][j] = a;
    mx = fmaxf(mx, a);
  }
  mx = fmaxf(mx, __shfl_xor(mx, 1));
  mx = fmaxf(mx, __shfl_xor(mx, 2));
  mx = fmaxf(mx, __shfl_xor(mx, 4));
  float sum = 0.f;
  for (int jj = 0; jj < 32; ++jj) {
    int j = jj * 8 + part;
    float e = expf(Ps[rl][j] - mx);
    Ps[rl][j] = e;
    sum += e;
  }
  sum += __shfl_xor(sum, 1); sum += __shfl_xor(sum, 2); sum += __shfl_xor(sum, 4);
  const float inv = 1.f / sum;
  __syncthreads();
  float o[6] = {0.f, 0.f, 0.f, 0.f, 0.f, 0.f};
  const int vb = part * 6;
  for (int j = 0; j < 256; ++j) {
    float p = Ps[rl][j];
    int base = j * 48 + vb;
#pragma unroll
    for (int dd = 0; dd < 3; ++dd) {
      short2 vv = *(const short2*)&Vs[base + dd * 2];
      o[dd*2]   += p * b2f(vv.x);
      o[dd*2+1] += p * b2f(vv.y);
    }
  }
#pragma unroll
  for (int d = 0; d < 6; ++d) outb[row * 384 + h * 48 + vb + d] = f2b(o[d] * inv);
}

// ---------------------------------------------------------------------------
// LayerNorm(x + delta_bf16)*g + b  -> xo fp32, xob bf16.  256 blocks x 128 thr.
// ---------------------------------------------------------------------------
__global__ __launch_bounds__(128)
void ln_k(const float* __restrict__ x, const short* __restrict__ d,
          const float* __restrict__ g, const float* __restrict__ b,
          float* __restrict__ xo, short* __restrict__ xob)
{
  const int row = blockIdx.x, t = threadIdx.x;
  float v[3]; float s = 0.f, ss = 0.f;
#pragma unroll
  for (int i = 0; i < 3; ++i) {
    int c = t + 128 * i;
    float u = x[row * 384 + c] + b2f(d[row * 384 + c]);
    v[i] = u; s += u; ss += u * u;
  }
#pragma unroll
  for (int m = 1; m < 64; m <<= 1) { s += __shfl_xor(s, m); ss += __shfl_xor(ss, m); }
  __shared__ float sh[4];
  if ((t & 63) == 0) { sh[(t >> 6) * 2] = s; sh[(t >> 6) * 2 + 1] = ss; }
  __syncthreads();
  s = sh[0] + sh[2]; ss = sh[1] + sh[3];
  float mean = s * (1.f / 384.f);
  float var  = ss * (1.f / 384.f) - mean * mean;
  float rstd = rsqrtf(var + 1e-5f);
#pragma unroll
  for (int i = 0; i < 3; ++i) {
    int c = t + 128 * i;
    float y = (v[i] - mean) * rstd * g[c] + b[c];
    xo[row * 384 + c]  = y;
    xob[row * 384 + c] = f2b(y);
  }
}

__global__ void init_k(const float* __restrict__ hs, float* __restrict__ x,
                       short* __restrict__ xb, float* __restrict__ rstate)
{
  int i = blockIdx.x * 256 + threadIdx.x;
  if (i < 98304) { float v = hs[i]; x[i] = v; xb[i] = f2b(v); }
  if (i < 384) rstate[i] = 0.f;
}

// ---------------------------------------------------------------------------
// GRU, wide: pool1 -> gih -> gru2 -> p1 (96 blocks) -> cont
// ---------------------------------------------------------------------------
__global__ __launch_bounds__(384)
void pool1_k(const float* __restrict__ x, float* __restrict__ partial)
{
  const int t = threadIdx.x, p = blockIdx.x;
  float s = 0.f;
  const float* xr = x + p * 32 * 384;
#pragma unroll 4
  for (int i = 0; i < 32; ++i) s += xr[i * 384 + t];
  partial[p * 384 + t] = s;
}

__global__ __launch_bounds__(256)
void gih_k(const float* __restrict__ Wih, const float* __restrict__ bih,
           const float* __restrict__ Whh, const float* __restrict__ bhh,
           const float* __restrict__ partial, const float* __restrict__ rstate,
           float* __restrict__ gi, float* __restrict__ gh)
{
  const int t = threadIdx.x, lane = t & 63, wave = t >> 6;
  const int r = blockIdx.x * 4 + wave;
  float a = 0.f, b = 0.f;
#pragma unroll
  for (int e = 0; e < 6; ++e) {
    int c = lane + 64 * e;
    float pc = 0.f;
#pragma unroll
    for (int p = 0; p < 8; ++p) pc += partial[p * 384 + c];
    pc *= (1.f / 256.f);
    a += Wih[r * 384 + c] * pc;
    b += Whh[r * 384 + c] * rstate[c];
  }
#pragma unroll
  for (int m = 1; m < 64; m <<= 1) { a += __shfl_xor(a, m); b += __shfl_xor(b, m); }
  if (lane == 0) { gi[r] = a + bih[r]; gh[r] = b + bhh[r]; }
}

__global__ __launch_bounds__(384)
void gru2_k(const float* __restrict__ gi, const float* __restrict__ gh,
            float* __restrict__ rstate, float* __restrict__ hnew)
{
  const int t = threadIdx.x;
  float r = sigm_f(gi[t] + gh[t]);
  float z = sigm_f(gi[384 + t] + gh[384 + t]);
  float n = tanhf(gi[768 + t] + r * gh[768 + t]);
  float h = (1.f - z) * n + z * rstate[t];
  rstate[t] = h;
  hnew[t] = h;
}

__global__ __launch_bounds__(256)
void p1_k(const float* __restrict__ Wp1, const float* __restrict__ bp1,
          const float* __restrict__ hnew, float* __restrict__ p1)
{
  const int t = threadIdx.x, lane = t & 63, wave = t >> 6;
  const int r = blockIdx.x * 4 + wave;
  float a = 0.f;
#pragma unroll
  for (int e = 0; e < 6; ++e) { int c = lane + 64 * e; a += Wp1[r * 384 + c] * hnew[c]; }
#pragma unroll
  for (int m = 1; m < 64; m <<= 1) a += __shfl_xor(a, m);
  if (lane == 0) p1[r] = gelu_f(a + bp1[r]);
}

__global__ __launch_bounds__(64)
void cont_k(const float* __restrict__ p1, const float* __restrict__ Wp2,
            const float* __restrict__ bp2, float* __restrict__ out_cont)
{
  const int lane = threadIdx.x;
  float a = 0.f;
#pragma unroll
  for (int e = 0; e < 6; ++e) { int c = lane + 64 * e; a += p1[c] * Wp2[c]; }
#pragma unroll
  for (int m = 1; m < 64; m <<= 1) a += __shfl_xor(a, m);
  if (lane == 0) out_cont[0] = sigm_f(a + bp2[0]);
}

// ---------------------------------------------------------------------------
extern "C" void kernel_launch(void* const* d_in, const int* in_sizes, int n_in,
                              void* d_out, int out_size, void* d_ws, size_t ws_size,
                              hipStream_t stream)
{
  const float* hs   = (const float*)d_in[0];
  const float* Wqkv = (const float*)d_in[1];
  const float* bqkv = (const float*)d_in[2];
  const float* Wo   = (const float*)d_in[3];
  const float* bo   = (const float*)d_in[4];
  const float* W1   = (const float*)d_in[5];
  const float* b1   = (const float*)d_in[6];
  const float* W2   = (const float*)d_in[7];
  const float* b2   = (const float*)d_in[8];
  const float* g1   = (const float*)d_in[9];
  const float* be1  = (const float*)d_in[10];
  const float* g2   = (const float*)d_in[11];
  const float* be2  = (const float*)d_in[12];
  const float* Wbil = (const float*)d_in[13];
  const float* bbil = (const float*)d_in[14];
  const float* Wc1  = (const float*)d_in[15];
  const float* bc1  = (const float*)d_in[16];
  const float* Wc2  = (const float*)d_in[17];
  const float* bc2  = (const float*)d_in[18];
  const float* Wih  = (const float*)d_in[19];
  const float* bih  = (const float*)d_in[20];
  const float* Whh  = (const float*)d_in[21];
  const float* bhh  = (const float*)d_in[22];
  const float* Wp1  = (const float*)d_in[23];
  const float* bp1  = (const float*)d_in[24];
  const float* Wp2  = (const float*)d_in[25];
  const float* bp2  = (const float*)d_in[26];
  const float* Wout = (const float*)d_in[27];
  const float* bout = (const float*)d_in[28];
  float* out = (float*)d_out;

  char* ws = (char*)d_ws;
  size_t off = 0;
  auto alloc = [&](size_t bytes) -> char* {
    char* p = ws + off; off += (bytes + 255) & ~(size_t)255; return p;
  };
  short* wbilT   = (short*)alloc(56623104ULL * 2);
  short* tmp     = (short*)alloc(256ULL * 147456 * 2);
  short* inter   = (short*)alloc(256ULL * 98304 * 2);
  float* x       = (float*)alloc(98304 * 4);
  short* xb      = (short*)alloc(98304 * 2);
  float* qkv     = (float*)alloc(294912 * 4);
  short* attnb   = (short*)alloc(98304 * 2);
  short* deltab  = (short*)alloc(98304 * 2);
  short* ff1b    = (short*)alloc(393216 * 2);
  float* rstate  = (float*)alloc(384 * 4);
  float* partial = (float*)alloc(8 * 384 * 4);
  float* gi      = (float*)alloc(1152 * 4);
  float* gh      = (float*)alloc(1152 * 4);
  float* hnew    = (float*)alloc(384 * 4);
  float* p1buf   = (float*)alloc(384 * 4);
  short* wc1b    = (short*)alloc(147456 * 2);
  short* wqkvb   = (short*)alloc(884736ULL * 2);
  short* wob     = (short*)alloc(294912ULL * 2);
  short* w1b     = (short*)alloc(1179648ULL * 2);
  short* w2b     = (short*)alloc(1179648ULL * 2);
  short* woutb   = (short*)alloc(147456 * 2);
  (void)ws_size; (void)in_sizes; (void)n_in; (void)out_size;

  dim3 B256(256);
  dim3 B512(512);

  init_k<<<dim3(384), B256, 0, stream>>>(hs, x, xb, rstate);
  transpose_k<<<dim3(6, 6, 384), B256, 0, stream>>>(Wbil, wbilT);
  convall_k<<<dim3(3744), B256, 0, stream>>>(Wc1, Wqkv, Wo, W1, W2, Wout,
                                             wc1b, wqkvb, wob, w1b, w2b, woutb);

  for (int s = 0; s < 2; ++s) {
    for (int l = 0; l < 2; ++l) {
      gemm64_k<true, false, false><<<dim3(18, 4), B256, 0, stream>>>(
          xb, wqkvb + l * 442368, bqkv + l * 1152, qkv, 256, 1152, 384);
      attn_k<<<dim3(8, 8), B256, 0, stream>>>(qkv, attnb);
      gemm64_k<true, false, true><<<dim3(6, 4), B256, 0, stream>>>(
          attnb, wob + l * 147456, bo + l * 384, deltab, 256, 384, 384);
      ln_k<<<dim3(256), dim3(128), 0, stream>>>(x, deltab, g1 + l * 384, be1 + l * 384, x, xb);
      gemm64_k<true, true, true><<<dim3(24, 4), B256, 0, stream>>>(
          xb, w1b + l * 589824, b1 + l * 1536, ff1b, 256, 1536, 384);
      gemm64_k<true, false, true><<<dim3(6, 4), B256, 0, stream>>>(
          ff1b, w2b + l * 589824, b2 + l * 384, deltab, 256, 384, 1536);
      ln_k<<<dim3(256), dim3(128), 0, stream>>>(x, deltab, g2 + l * 384, be2 + l * 384, x, xb);
    }
    // tmp[i, o*384+y] = sum_x X[i,x] * WbilT[o*384+y, x]   (B read ONCE)
    gemm256_k<false, true><<<dim3(1152, 1, 1), B512, 0, stream>>>(
        xb, wbilT, (const float*)nullptr, tmp, 147456, 384, 0, 0, 0);
    // inter[i][j][o] = sum_y X[j,y] * tmp_i[o,y] + bbil[o]
    gemm256_k<true, true><<<dim3(3, 1, 256), B512, 0, stream>>>(
        xb, tmp, bbil, inter, 384, 384, 0, 147456LL, 98304LL);
    // fused h1 + logits
    h1log256_k<<<dim3(256), B512, 0, stream>>>(inter, wc1b, bc1, Wc2, bc2,
                                               out + 98304 + s * 65536);
    // --- GRU controller (wide) ---
    pool1_k<<<dim3(8), dim3(384), 0, stream>>>(x, partial);
    gih_k<<<dim3(288), B256, 0, stream>>>(Wih, bih, Whh, bhh, partial, rstate, gi, gh);
    gru2_k<<<dim3(1), dim3(384), 0, stream>>>(gi, gh, rstate, hnew);
    p1_k<<<dim3(96), B256, 0, stream>>>(Wp1, bp1, hnew, p1buf);
    cont_k<<<dim3(1), dim3(64), 0, stream>>>(p1buf, Wp2, bp2, out + 98304 + 131072 + s);
  }
  gemm64_k<true, false, false><<<dim3(6, 4), B256, 0, stream>>>(
      xb, woutb, bout, out, 256, 384, 384);
}

// Round 14
// 593.674 us; speedup vs baseline: 1.3591x; 1.0231x over previous
//
#include <hip/hip_runtime.h>

typedef __attribute__((ext_vector_type(4))) float f32x4;
typedef __attribute__((ext_vector_type(8))) short s16x8;

#define DEVI __device__ __forceinline__

DEVI float b2f(short s) {
  union { float f; unsigned u; } v; v.u = ((unsigned)(unsigned short)s) << 16; return v.f;
}
DEVI short f2b(float f) {
  union { float f; unsigned u; } v; v.f = f;
  unsigned u = v.u;
  u += 0x7FFFu + ((u >> 16) & 1u);   // RNE
  return (short)(u >> 16);
}
// fast GELU: tanh form, exp-based; overflow-safe. err ~4e-4 max, ~1e-5 here.
DEVI float gelu_f(float x) {
  float z2 = 1.5957691216f * x * (1.0f + 0.044715f * x * x);
  float e = __expf(z2);
  float th = 1.0f - 2.0f / (e + 1.0f);
  return 0.5f * x * (1.0f + th);
}
DEVI float sigm_f(float x) { return 1.0f / (1.0f + expf(-x)); }

// async global->LDS, 16B per lane; LDS dest = wave-uniform base + lane*16
DEVI void gld16(const short* g, const short* l) {
  __builtin_amdgcn_global_load_lds((const __attribute__((address_space(1))) void*)g,
                                   (__attribute__((address_space(3))) void*)l, 16, 0, 0);
}

// ---------------------------------------------------------------------------
// BM=256 bf16 GEMM + piggybacked pool1: blocks [0,nblk) do GEMM; blocks
// >= nblk do pool1 (partial row-sums of x, 8 blocks x 32 rows).
// 512 thr, 8 waves (4m x 2n), BK=32.
// ---------------------------------------------------------------------------
template<bool BIAS, bool OUT_BF16>
__global__ __launch_bounds__(512)
void gemm256pool_k(const short* __restrict__ A, const short* __restrict__ B,
                   const float* __restrict__ bias, void* __restrict__ Cv,
                   int N, int K, int nblk,
                   const float* __restrict__ xfull, float* __restrict__ partial)
{
  const int t = threadIdx.x;
  if ((int)blockIdx.x >= nblk) {
    // pool1 role: 8 blocks, 384 cols, 32 rows each
    const int p = blockIdx.x - nblk;
    if (t < 384) {
      float s = 0.f;
      const float* xr = xfull + p * 32 * 384;
#pragma unroll 4
      for (int i = 0; i < 32; ++i) s += xr[i * 384 + t];
      partial[p * 384 + t] = s;
    }
    return;
  }
  __shared__ short As[2][256 * 32];
  __shared__ short Bs[2][128 * 32];
  const int n0 = blockIdx.x * 128;
  const int lane = t & 63, wave = t >> 6;
  const int wm = wave >> 1, wn = wave & 1;
  const int lr = lane >> 2;
  const int lc = (lane & 3) * 8;
  const int fr = lane & 15, fs = lane >> 4;

  f32x4 acc[4][4];
#pragma unroll
  for (int i = 0; i < 4; ++i)
#pragma unroll
    for (int j = 0; j < 4; ++j) acc[i][j] = f32x4{0.f, 0.f, 0.f, 0.f};

  auto stage = [&](int b, int k0) {
#pragma unroll
    for (int q = 0; q < 2; ++q)
      gld16(A + (long long)(q * 128 + wave * 16 + lr) * K + k0 + lc,
            &As[b][(q * 128 + wave * 16) * 32]);
    gld16(B + (long long)(n0 + wave * 16 + lr) * K + k0 + lc,
          &Bs[b][wave * 16 * 32]);
  };

  const int NT = K >> 5;
  stage(0, 0);
  __syncthreads();
  for (int tt = 0; tt < NT; ++tt) {
    const int cur = tt & 1;
    if (tt + 1 < NT) stage(cur ^ 1, (tt + 1) << 5);
    s16x8 af[4], bfv[4];
#pragma unroll
    for (int i = 0; i < 4; ++i) af[i]  = *(const s16x8*)&As[cur][(wm * 64 + i * 16 + fr) * 32 + fs * 8];
#pragma unroll
    for (int j = 0; j < 4; ++j) bfv[j] = *(const s16x8*)&Bs[cur][(wn * 64 + j * 16 + fr) * 32 + fs * 8];
#pragma unroll
    for (int i = 0; i < 4; ++i)
#pragma unroll
      for (int j = 0; j < 4; ++j)
        acc[i][j] = __builtin_amdgcn_mfma_f32_16x16x32_bf16(af[i], bfv[j], acc[i][j], 0, 0, 0);
    if (tt + 1 < NT) __syncthreads();
  }

#pragma unroll
  for (int i = 0; i < 4; ++i) {
    int rowb = wm * 64 + i * 16 + fs * 4;
#pragma unroll
    for (int j = 0; j < 4; ++j) {
      int col = n0 + wn * 64 + j * 16 + fr;
      float bb = BIAS ? bias[col] : 0.0f;
#pragma unroll
      for (int u = 0; u < 4; ++u) {
        float v = acc[i][j][u] + bb;
        long long off = (long long)(rowb + u) * N + col;
        if constexpr (OUT_BF16) ((short*)Cv)[off] = f2b(v);
        else                    ((float*)Cv)[off] = v;
      }
    }
  }
}

// ---------------------------------------------------------------------------
// BM=256 bf16 GEMM (batched, for inter). 512 thr, BK=32.
// ---------------------------------------------------------------------------
template<bool BIAS, bool OUT_BF16>
__global__ __launch_bounds__(512)
void gemm256_k(const short* __restrict__ A, const short* __restrict__ B,
               const float* __restrict__ bias, void* __restrict__ Cv,
               int N, int K,
               long long sA, long long sB, long long sC)
{
  __shared__ short As[2][256 * 32];
  __shared__ short Bs[2][128 * 32];
  const int bz = blockIdx.z;
  const int n0 = blockIdx.x * 128;
  const int t = threadIdx.x, lane = t & 63, wave = t >> 6;
  const int wm = wave >> 1, wn = wave & 1;
  const short* Ab = A + bz * sA;
  const short* Bb = B + bz * sB;
  const int lr = lane >> 2;
  const int lc = (lane & 3) * 8;
  const int fr = lane & 15, fs = lane >> 4;

  f32x4 acc[4][4];
#pragma unroll
  for (int i = 0; i < 4; ++i)
#pragma unroll
    for (int j = 0; j < 4; ++j) acc[i][j] = f32x4{0.f, 0.f, 0.f, 0.f};

  auto stage = [&](int b, int k0) {
#pragma unroll
    for (int q = 0; q < 2; ++q)
      gld16(Ab + (long long)(q * 128 + wave * 16 + lr) * K + k0 + lc,
            &As[b][(q * 128 + wave * 16) * 32]);
    gld16(Bb + (long long)(n0 + wave * 16 + lr) * K + k0 + lc,
          &Bs[b][wave * 16 * 32]);
  };

  const int NT = K >> 5;
  stage(0, 0);
  __syncthreads();
  for (int tt = 0; tt < NT; ++tt) {
    const int cur = tt & 1;
    if (tt + 1 < NT) stage(cur ^ 1, (tt + 1) << 5);
    s16x8 af[4], bfv[4];
#pragma unroll
    for (int i = 0; i < 4; ++i) af[i]  = *(const s16x8*)&As[cur][(wm * 64 + i * 16 + fr) * 32 + fs * 8];
#pragma unroll
    for (int j = 0; j < 4; ++j) bfv[j] = *(const s16x8*)&Bs[cur][(wn * 64 + j * 16 + fr) * 32 + fs * 8];
#pragma unroll
    for (int i = 0; i < 4; ++i)
#pragma unroll
      for (int j = 0; j < 4; ++j)
        acc[i][j] = __builtin_amdgcn_mfma_f32_16x16x32_bf16(af[i], bfv[j], acc[i][j], 0, 0, 0);
    if (tt + 1 < NT) __syncthreads();
  }

#pragma unroll
  for (int i = 0; i < 4; ++i) {
    int rowb = wm * 64 + i * 16 + fs * 4;
#pragma unroll
    for (int j = 0; j < 4; ++j) {
      int col = n0 + wn * 64 + j * 16 + fr;
      float bb = BIAS ? bias[col] : 0.0f;
#pragma unroll
      for (int u = 0; u < 4; ++u) {
        float v = acc[i][j][u] + bb;
        long long off = bz * sC + (long long)(rowb + u) * N + col;
        if constexpr (OUT_BF16) ((short*)Cv)[off] = f2b(v);
        else                    ((float*)Cv)[off] = v;
      }
    }
  }
}

// ---------------------------------------------------------------------------
// Fused h1+logits (blocks 0..255, BK=64 swizzled) + piggybacked gih
// (blocks 256..399: gi/gh = Wih.pooled + bih, Whh.rstate + bhh; 8 rows/blk).
// ---------------------------------------------------------------------------
__global__ __launch_bounds__(512)
void h1log256_k(const short* __restrict__ inter, const short* __restrict__ Wc1b,
                const float* __restrict__ bc1, const float* __restrict__ Wc2,
                const float* __restrict__ bc2, float* __restrict__ outp,
                const float* __restrict__ Wih, const float* __restrict__ bih,
                const float* __restrict__ Whh, const float* __restrict__ bhh,
                const float* __restrict__ partial, const float* __restrict__ rs0,
                float* __restrict__ gi, float* __restrict__ gh)
{
  const int t = threadIdx.x, lane = t & 63, wave = t >> 6;
  if ((int)blockIdx.x >= 256) {
    // gih role: 144 blocks x 8 waves, 1 row per wave
    const int r = (blockIdx.x - 256) * 8 + wave;   // 0..1151
    float a = 0.f, b = 0.f;
#pragma unroll
    for (int e = 0; e < 6; ++e) {
      int c = lane + 64 * e;
      float pc = 0.f;
#pragma unroll
      for (int p = 0; p < 8; ++p) pc += partial[p * 384 + c];
      pc *= (1.f / 256.f);
      a += Wih[r * 384 + c] * pc;
      b += Whh[r * 384 + c] * rs0[c];
    }
#pragma unroll
    for (int m = 1; m < 64; m <<= 1) { a += __shfl_xor(a, m); b += __shfl_xor(b, m); }
    if (lane == 0) { gi[r] = a + bih[r]; gh[r] = b + bhh[r]; }
    return;
  }
  __shared__ short As[2][256 * 64];
  __shared__ short Bs[2][128 * 64];
  __shared__ float part[256][2];
  const int ib = blockIdx.x;
  const int wm = wave >> 1, wn = wave & 1;
  const short* Ab = inter + (long long)ib * 98304;
  const int srow = lane >> 3;
  const int scol = ((lane & 7) ^ srow) * 8;
  const int fr = lane & 15, fs = lane >> 4;

  float lp[16];
#pragma unroll
  for (int e = 0; e < 16; ++e) lp[e] = 0.f;

  for (int n0 = 0; n0 < 384; n0 += 128) {
    f32x4 acc[4][4];
#pragma unroll
    for (int i = 0; i < 4; ++i)
#pragma unroll
      for (int j = 0; j < 4; ++j) acc[i][j] = f32x4{0.f, 0.f, 0.f, 0.f};

    auto stage = [&](int b, int k0) {
#pragma unroll
      for (int q = 0; q < 4; ++q) {
        int c = wave * 4 + q;
        gld16(Ab + (long long)(c * 8 + srow) * 384 + k0 + scol, &As[b][c * 512]);
      }
#pragma unroll
      for (int q = 0; q < 2; ++q) {
        int c = wave * 2 + q;
        gld16(Wc1b + (long long)(n0 + c * 8 + srow) * 384 + k0 + scol, &Bs[b][c * 512]);
      }
    };

    stage(0, 0);
    __syncthreads();
    for (int tt = 0; tt < 6; ++tt) {
      const int cur = tt & 1;
      if (tt + 1 < 6) stage(cur ^ 1, (tt + 1) << 6);
      s16x8 af[4][2], bfv[4][2];
#pragma unroll
      for (int i = 0; i < 4; ++i) {
        int row = wm * 64 + i * 16 + fr;
#pragma unroll
        for (int s = 0; s < 2; ++s)
          af[i][s] = *(const s16x8*)&As[cur][row * 64 + (((s * 4 + fs) ^ (fr & 7)) * 8)];
      }
#pragma unroll
      for (int j = 0; j < 4; ++j) {
        int row = wn * 64 + j * 16 + fr;
#pragma unroll
        for (int s = 0; s < 2; ++s)
          bfv[j][s] = *(const s16x8*)&Bs[cur][row * 64 + (((s * 4 + fs) ^ (fr & 7)) * 8)];
      }
#pragma unroll
      for (int s = 0; s < 2; ++s)
#pragma unroll
        for (int i = 0; i < 4; ++i)
#pragma unroll
          for (int j = 0; j < 4; ++j)
            acc[i][j] = __builtin_amdgcn_mfma_f32_16x16x32_bf16(af[i][s], bfv[j][s], acc[i][j], 0, 0, 0);
      __syncthreads();
    }
#pragma unroll
    for (int i = 0; i < 4; ++i)
#pragma unroll
      for (int j = 0; j < 4; ++j) {
        int col = n0 + wn * 64 + j * 16 + fr;
        float w2 = Wc2[col], b1v = bc1[col];
#pragma unroll
        for (int u = 0; u < 4; ++u)
          lp[i * 4 + u] += gelu_f(acc[i][j][u] + b1v) * w2;
      }
  }
#pragma unroll
  for (int m = 1; m < 16; m <<= 1)
#pragma unroll
    for (int e = 0; e < 16; ++e) lp[e] += __shfl_xor(lp[e], m);
  if (fr == 0) {
#pragma unroll
    for (int e = 0; e < 16; ++e)
      part[wm * 64 + (e >> 2) * 16 + fs * 4 + (e & 3)][wn] = lp[e];
  }
  __syncthreads();
  if (t < 256) outp[ib * 256 + t] = sigm_f(part[t][0] + part[t][1] + bc2[0]);
}

// ---------------------------------------------------------------------------
// 64x64-tile bf16 GEMM, BK=64, XOR-swizzled LDS (layer GEMMs).
// ---------------------------------------------------------------------------
template<bool BIAS, bool GELU_ACT, bool OUT_BF16>
__global__ __launch_bounds__(256)
void gemm64_k(const short* __restrict__ A, const short* __restrict__ B,
              const float* __restrict__ bias, void* __restrict__ Cv,
              int M, int N, int K)
{
  __shared__ short As[2][64 * 64];
  __shared__ short Bs[2][64 * 64];
  const int n0 = blockIdx.x * 64;
  const int m0 = blockIdx.y * 64;
  const int t = threadIdx.x, lane = t & 63, wave = t >> 6;
  const int wm = wave >> 1, wn = wave & 1;
  const int srow = lane >> 3;
  const int scol = ((lane & 7) ^ srow) * 8;
  const int fr = lane & 15, fs = lane >> 4;

  f32x4 acc[2][2];
#pragma unroll
  for (int i = 0; i < 2; ++i)
#pragma unroll
    for (int j = 0; j < 2; ++j) acc[i][j] = f32x4{0.f, 0.f, 0.f, 0.f};

  auto stage = [&](int b, int k0) {
#pragma unroll
    for (int q = 0; q < 2; ++q) {
      int c = wave * 2 + q;
      gld16(A + (long long)(m0 + c * 8 + srow) * K + k0 + scol, &As[b][c * 512]);
      gld16(B + (long long)(n0 + c * 8 + srow) * K + k0 + scol, &Bs[b][c * 512]);
    }
  };

  const int NT = K >> 6;
  stage(0, 0);
  __syncthreads();
  for (int tt = 0; tt < NT; ++tt) {
    const int cur = tt & 1;
    if (tt + 1 < NT) stage(cur ^ 1, (tt + 1) << 6);
    s16x8 af[2][2], bfv[2][2];
#pragma unroll
    for (int i = 0; i < 2; ++i) {
      int row = wm * 32 + i * 16 + fr;
#pragma unroll
      for (int s = 0; s < 2; ++s)
        af[i][s] = *(const s16x8*)&As[cur][row * 64 + (((s * 4 + fs) ^ (fr & 7)) * 8)];
    }
#pragma unroll
    for (int j = 0; j < 2; ++j) {
      int row = wn * 32 + j * 16 + fr;
#pragma unroll
      for (int s = 0; s < 2; ++s)
        bfv[j][s] = *(const s16x8*)&Bs[cur][row * 64 + (((s * 4 + fs) ^ (fr & 7)) * 8)];
    }
#pragma unroll
    for (int s = 0; s < 2; ++s)
#pragma unroll
      for (int i = 0; i < 2; ++i)
#pragma unroll
        for (int j = 0; j < 2; ++j)
          acc[i][j] = __builtin_amdgcn_mfma_f32_16x16x32_bf16(af[i][s], bfv[j][s], acc[i][j], 0, 0, 0);
    if (tt + 1 < NT) __syncthreads();
  }

#pragma unroll
  for (int i = 0; i < 2; ++i) {
    int rowb = m0 + wm * 32 + i * 16 + fs * 4;
#pragma unroll
    for (int j = 0; j < 2; ++j) {
      int col = n0 + wn * 32 + j * 16 + fr;
      float bb = BIAS ? bias[col] : 0.0f;
#pragma unroll
      for (int u = 0; u < 4; ++u) {
        float v = acc[i][j][u] + bb;
        if constexpr (GELU_ACT) v = gelu_f(v);
        long long off = (long long)(rowb + u) * N + col;
        if constexpr (OUT_BF16) ((short*)Cv)[off] = f2b(v);
        else                    ((float*)Cv)[off] = v;
      }
    }
  }
}

// ---------------------------------------------------------------------------
// Wbil [o][x][y] fp32  ->  WbilT [o][y][x] bf16   (64x64 tiles via LDS)
// ---------------------------------------------------------------------------
__global__ __launch_bounds__(256)
void transpose_k(const float* __restrict__ W, short* __restrict__ WT)
{
  __shared__ short L[64 * 68];
  const int o  = blockIdx.z;
  const int x0 = blockIdx.x * 64, y0 = blockIdx.y * 64;
  const float* Wo = W  + (long long)o * 147456;
  short*      WTo = WT + (long long)o * 147456;
  const int t  = threadIdx.x;
  const int rr = t >> 4;
  const int cc = (t & 15) * 4;
#pragma unroll
  for (int q = 0; q < 4; ++q) {
    int xl = rr + 16 * q;
    float4 v = *(const float4*)(Wo + (x0 + xl) * 384 + y0 + cc);
    short4 p; p.x = f2b(v.x); p.y = f2b(v.y); p.z = f2b(v.z); p.w = f2b(v.w);
    *(short4*)&L[xl * 68 + cc] = p;
  }
  __syncthreads();
#pragma unroll
  for (int q = 0; q < 4; ++q) {
    int yl = rr + 16 * q;
    short4 p;
    p.x = L[(cc + 0) * 68 + yl];
    p.y = L[(cc + 1) * 68 + yl];
    p.z = L[(cc + 2) * 68 + yl];
    p.w = L[(cc + 3) * 68 + yl];
    *(short4*)(WTo + (y0 + yl) * 384 + x0 + cc) = p;
  }
}

// ---------------------------------------------------------------------------
// Convert ALL layer weights fp32->bf16 in ONE dispatch.
// ---------------------------------------------------------------------------
__global__ __launch_bounds__(256)
void convall_k(const float* __restrict__ Wc1, const float* __restrict__ Wqkv,
               const float* __restrict__ Wo, const float* __restrict__ W1,
               const float* __restrict__ W2, const float* __restrict__ Wout,
               short* __restrict__ Dc1, short* __restrict__ Dqkv,
               short* __restrict__ Do, short* __restrict__ D1,
               short* __restrict__ D2, short* __restrict__ Dout)
{
  long long i4 = ((long long)blockIdx.x * 256 + threadIdx.x) * 4;
  const float* s; short* d; long long off;
  if      (i4 <  147456) { s = Wc1;  d = Dc1;  off = 0; }
  else if (i4 < 1032192) { s = Wqkv; d = Dqkv; off = 147456; }
  else if (i4 < 1327104) { s = Wo;   d = Do;   off = 1032192; }
  else if (i4 < 2506752) { s = W1;   d = D1;   off = 1327104; }
  else if (i4 < 3686400) { s = W2;   d = D2;   off = 2506752; }
  else if (i4 < 3833856) { s = Wout; d = Dout; off = 3686400; }
  else return;
  long long l = i4 - off;
  float4 v = *(const float4*)(s + l);
  short4 p; p.x = f2b(v.x); p.y = f2b(v.y); p.z = f2b(v.z); p.w = f2b(v.w);
  *(short4*)(d + l) = p;
}

// ---------------------------------------------------------------------------
// Attention: qkv fp32 [256][1152] -> out bf16 [256][384]. d=48, NH=8.
// ---------------------------------------------------------------------------
__global__ __launch_bounds__(256)
void attn_k(const float* __restrict__ qkv, short* __restrict__ outb)
{
  __shared__ short Ks[256 * 48];
  __shared__ short Vs[256 * 48];
  __shared__ float Ps[32][258];
  const int h  = blockIdx.y;
  const int q0 = blockIdx.x * 32;
  const int t = threadIdx.x, lane = t & 63, wave = t >> 6;
  for (int idx = t; idx < 3072; idx += 256) {
    int j = idx / 12, d4 = (idx - (idx / 12) * 12) * 4;
    const float* base = qkv + j * 1152 + h * 48 + d4;
    float4 kv = *(const float4*)(base + 384);
    float4 vv = *(const float4*)(base + 768);
    short4 pk; pk.x = f2b(kv.x); pk.y = f2b(kv.y); pk.z = f2b(kv.z); pk.w = f2b(kv.w);
    short4 pv; pv.x = f2b(vv.x); pv.y = f2b(vv.y); pv.z = f2b(vv.z); pv.w = f2b(vv.w);
    *(short4*)&Ks[j * 48 + d4] = pk;
    *(short4*)&Vs[j * 48 + d4] = pv;
  }
  __syncthreads();
  const int part = lane & 7;
  const int rl   = wave * 8 + (lane >> 3);
  const int row  = q0 + rl;
  float q[48];
#pragma unroll
  for (int d = 0; d < 48; ++d) q[d] = qkv[row * 1152 + h * 48 + d] * 0.14433756729740644f;
  float mx = -1e30f;
  for (int jj = 0; jj < 32; ++jj) {
    int j = jj * 8 + part;
    float a = 0.f;
#pragma unroll
    for (int dd = 0; dd < 12; ++dd) {
      short4 kk = *(const short4*)&Ks[j * 48 + dd * 4];
      a += q[dd*4+0]*b2f(kk.x) + q[dd*4+1]*b2f(kk.y) + q[dd*4+2]*b2f(kk.z) + q[dd*4+3]*b2f(kk.w);
    }
    Ps[rl][j] = a;
    mx = fmaxf(mx, a);
  }
  mx = fmaxf(mx, __shfl_xor(mx, 1));
  mx = fmaxf(mx, __shfl_xor(mx, 2));
  mx = fmaxf(mx, __shfl_xor(mx, 4));
  float sum = 0.f;
  for (int jj = 0; jj < 32; ++jj) {
    int j = jj * 8 + part;
    float e = expf(Ps[rl][j] - mx);
    Ps[rl][j] = e;
    sum += e;
  }
  sum += __shfl_xor(sum, 1); sum += __shfl_xor(sum, 2); sum += __shfl_xor(sum, 4);
  const float inv = 1.f / sum;
  __syncthreads();
  float o[6] = {0.f, 0.f, 0.f, 0.f, 0.f, 0.f};
  const int vb = part * 6;
  for (int j = 0; j < 256; ++j) {
    float p = Ps[rl][j];
    int base = j * 48 + vb;
#pragma unroll
    for (int dd = 0; dd < 3; ++dd) {
      short2 vv = *(const short2*)&Vs[base + dd * 2];
      o[dd*2]   += p * b2f(vv.x);
      o[dd*2+1] += p * b2f(vv.y);
    }
  }
#pragma unroll
  for (int d = 0; d < 6; ++d) outb[row * 384 + h * 48 + vb + d] = f2b(o[d] * inv);
}

// ---------------------------------------------------------------------------
// LayerNorm(x + delta_bf16)*g + b  -> xo fp32, xob bf16.  256 blocks x 128 thr.
// ---------------------------------------------------------------------------
__global__ __launch_bounds__(128)
void ln_k(const float* __restrict__ x, const short* __restrict__ d,
          const float* __restrict__ g, const float* __restrict__ b,
          float* __restrict__ xo, short* __restrict__ xob)
{
  const int row = blockIdx.x, t = threadIdx.x;
  float v[3]; float s = 0.f, ss = 0.f;
#pragma unroll
  for (int i = 0; i < 3; ++i) {
    int c = t + 128 * i;
    float u = x[row * 384 + c] + b2f(d[row * 384 + c]);
    v[i] = u; s += u; ss += u * u;
  }
#pragma unroll
  for (int m = 1; m < 64; m <<= 1) { s += __shfl_xor(s, m); ss += __shfl_xor(ss, m); }
  __shared__ float sh[4];
  if ((t & 63) == 0) { sh[(t >> 6) * 2] = s; sh[(t >> 6) * 2 + 1] = ss; }
  __syncthreads();
  s = sh[0] + sh[2]; ss = sh[1] + sh[3];
  float mean = s * (1.f / 384.f);
  float var  = ss * (1.f / 384.f) - mean * mean;
  float rstd = rsqrtf(var + 1e-5f);
#pragma unroll
  for (int i = 0; i < 3; ++i) {
    int c = t + 128 * i;
    float y = (v[i] - mean) * rstd * g[c] + b[c];
    xo[row * 384 + c]  = y;
    xob[row * 384 + c] = f2b(y);
  }
}

__global__ void init_k(const float* __restrict__ hs, float* __restrict__ x,
                       short* __restrict__ xb, float* __restrict__ rstate)
{
  int i = blockIdx.x * 256 + threadIdx.x;
  if (i < 98304) { float v = hs[i]; x[i] = v; xb[i] = f2b(v); }
  if (i < 768) rstate[i] = 0.f;   // both ping-pong halves
}

// ---------------------------------------------------------------------------
// p1m: merged GRU gates + p1. Each block recomputes hnew[0..383] in LDS
// (redundant, cheap); 4 rows of p1 per block; block 0 writes rs1.
// ---------------------------------------------------------------------------
__global__ __launch_bounds__(256)
void p1m_k(const float* __restrict__ gi, const float* __restrict__ gh,
           const float* __restrict__ rs0, float* __restrict__ rs1,
           const float* __restrict__ Wp1, const float* __restrict__ bp1,
           float* __restrict__ p1)
{
  __shared__ float hn[384];
  const int t = threadIdx.x, lane = t & 63, wave = t >> 6;
  for (int c = t; c < 384; c += 256) {
    float r = sigm_f(gi[c] + gh[c]);
    float z = sigm_f(gi[384 + c] + gh[384 + c]);
    float n = tanhf(gi[768 + c] + r * gh[768 + c]);
    hn[c] = (1.f - z) * n + z * rs0[c];
  }
  __syncthreads();
  const int r = blockIdx.x * 4 + wave;
  float a = 0.f;
#pragma unroll
  for (int e = 0; e < 6; ++e) { int c = lane + 64 * e; a += Wp1[r * 384 + c] * hn[c]; }
#pragma unroll
  for (int m = 1; m < 64; m <<= 1) a += __shfl_xor(a, m);
  if (lane == 0) p1[r] = gelu_f(a + bp1[r]);
  if (blockIdx.x == 0)
    for (int c = t; c < 384; c += 256) rs1[c] = hn[c];
}

__global__ __launch_bounds__(64)
void cont_k(const float* __restrict__ p1, const float* __restrict__ Wp2,
            const float* __restrict__ bp2, float* __restrict__ out_cont)
{
  const int lane = threadIdx.x;
  float a = 0.f;
#pragma unroll
  for (int e = 0; e < 6; ++e) { int c = lane + 64 * e; a += p1[c] * Wp2[c]; }
#pragma unroll
  for (int m = 1; m < 64; m <<= 1) a += __shfl_xor(a, m);
  if (lane == 0) out_cont[0] = sigm_f(a + bp2[0]);
}

// ---------------------------------------------------------------------------
extern "C" void kernel_launch(void* const* d_in, const int* in_sizes, int n_in,
                              void* d_out, int out_size, void* d_ws, size_t ws_size,
                              hipStream_t stream)
{
  const float* hs   = (const float*)d_in[0];
  const float* Wqkv = (const float*)d_in[1];
  const float* bqkv = (const float*)d_in[2];
  const float* Wo   = (const float*)d_in[3];
  const float* bo   = (const float*)d_in[4];
  const float* W1   = (const float*)d_in[5];
  const float* b1   = (const float*)d_in[6];
  const float* W2   = (const float*)d_in[7];
  const float* b2   = (const float*)d_in[8];
  const float* g1   = (const float*)d_in[9];
  const float* be1  = (const float*)d_in[10];
  const float* g2   = (const float*)d_in[11];
  const float* be2  = (const float*)d_in[12];
  const float* Wbil = (const float*)d_in[13];
  const float* bbil = (const float*)d_in[14];
  const float* Wc1  = (const float*)d_in[15];
  const float* bc1  = (const float*)d_in[16];
  const float* Wc2  = (const float*)d_in[17];
  const float* bc2  = (const float*)d_in[18];
  const float* Wih  = (const float*)d_in[19];
  const float* bih  = (const float*)d_in[20];
  const float* Whh  = (const float*)d_in[21];
  const float* bhh  = (const float*)d_in[22];
  const float* Wp1  = (const float*)d_in[23];
  const float* bp1  = (const float*)d_in[24];
  const float* Wp2  = (const float*)d_in[25];
  const float* bp2  = (const float*)d_in[26];
  const float* Wout = (const float*)d_in[27];
  const float* bout = (const float*)d_in[28];
  float* out = (float*)d_out;

  char* ws = (char*)d_ws;
  size_t off = 0;
  auto alloc = [&](size_t bytes) -> char* {
    char* p = ws + off; off += (bytes + 255) & ~(size_t)255; return p;
  };
  short* wbilT   = (short*)alloc(56623104ULL * 2);
  short* tmp     = (short*)alloc(256ULL * 147456 * 2);
  short* inter   = (short*)alloc(256ULL * 98304 * 2);
  float* x       = (float*)alloc(98304 * 4);
  short* xb      = (short*)alloc(98304 * 2);
  float* qkv     = (float*)alloc(294912 * 4);
  short* attnb   = (short*)alloc(98304 * 2);
  short* deltab  = (short*)alloc(98304 * 2);
  short* ff1b    = (short*)alloc(393216 * 2);
  float* rstate  = (float*)alloc(768 * 4);      // ping-pong pair
  float* partial = (float*)alloc(8 * 384 * 4);
  float* gi      = (float*)alloc(1152 * 4);
  float* gh      = (float*)alloc(1152 * 4);
  float* p1buf   = (float*)alloc(384 * 4);
  short* wc1b    = (short*)alloc(147456 * 2);
  short* wqkvb   = (short*)alloc(884736ULL * 2);
  short* wob     = (short*)alloc(294912ULL * 2);
  short* w1b     = (short*)alloc(1179648ULL * 2);
  short* w2b     = (short*)alloc(1179648ULL * 2);
  short* woutb   = (short*)alloc(147456 * 2);
  (void)ws_size; (void)in_sizes; (void)n_in; (void)out_size;

  dim3 B256(256);
  dim3 B512(512);

  init_k<<<dim3(384), B256, 0, stream>>>(hs, x, xb, rstate);
  transpose_k<<<dim3(6, 6, 384), B256, 0, stream>>>(Wbil, wbilT);
  convall_k<<<dim3(3744), B256, 0, stream>>>(Wc1, Wqkv, Wo, W1, W2, Wout,
                                             wc1b, wqkvb, wob, w1b, w2b, woutb);

  for (int s = 0; s < 2; ++s) {
    float* rs0 = rstate + (s & 1) * 384;
    float* rs1 = rstate + ((s + 1) & 1) * 384;
    for (int l = 0; l < 2; ++l) {
      gemm64_k<true, false, false><<<dim3(18, 4), B256, 0, stream>>>(
          xb, wqkvb + l * 442368, bqkv + l * 1152, qkv, 256, 1152, 384);
      attn_k<<<dim3(8, 8), B256, 0, stream>>>(qkv, attnb);
      gemm64_k<true, false, true><<<dim3(6, 4), B256, 0, stream>>>(
          attnb, wob + l * 147456, bo + l * 384, deltab, 256, 384, 384);
      ln_k<<<dim3(256), dim3(128), 0, stream>>>(x, deltab, g1 + l * 384, be1 + l * 384, x, xb);
      gemm64_k<true, true, true><<<dim3(24, 4), B256, 0, stream>>>(
          xb, w1b + l * 589824, b1 + l * 1536, ff1b, 256, 1536, 384);
      gemm64_k<true, false, true><<<dim3(6, 4), B256, 0, stream>>>(
          ff1b, w2b + l * 589824, b2 + l * 384, deltab, 256, 384, 1536);
      ln_k<<<dim3(256), dim3(128), 0, stream>>>(x, deltab, g2 + l * 384, be2 + l * 384, x, xb);
    }
    // tmp GEMM (1152 blocks) + piggybacked pool1 (8 blocks)
    gemm256pool_k<false, true><<<dim3(1160), B512, 0, stream>>>(
        xb, wbilT, (const float*)nullptr, tmp, 147456, 384, 1152, x, partial);
    // inter[i][j][o] = sum_y X[j,y] * tmp_i[o,y] + bbil[o]
    gemm256_k<true, true><<<dim3(3, 1, 256), B512, 0, stream>>>(
        xb, tmp, bbil, inter, 384, 384, 0, 147456LL, 98304LL);
    // fused h1 + logits (256 blocks) + piggybacked gih (144 blocks)
    h1log256_k<<<dim3(400), B512, 0, stream>>>(inter, wc1b, bc1, Wc2, bc2,
                                               out + 98304 + s * 65536,
                                               Wih, bih, Whh, bhh, partial, rs0, gi, gh);
    // merged GRU gates + p1; then cont
    p1m_k<<<dim3(96), B256, 0, stream>>>(gi, gh, rs0, rs1, Wp1, bp1, p1buf);
    cont_k<<<dim3(1), dim3(64), 0, stream>>>(p1buf, Wp2, bp2, out + 98304 + 131072 + s);
  }
  gemm64_k<true, false, false><<<dim3(6, 4), B256, 0, stream>>>(
      xb, woutb, bout, out, 256, 384, 384);
}

// Round 15
// 581.172 us; speedup vs baseline: 1.3883x; 1.0215x over previous
//
#include <hip/hip_runtime.h>

typedef __attribute__((ext_vector_type(4))) float f32x4;
typedef __attribute__((ext_vector_type(8))) short s16x8;

#define DEVI __device__ __forceinline__

DEVI float b2f(short s) {
  union { float f; unsigned u; } v; v.u = ((unsigned)(unsigned short)s) << 16; return v.f;
}
DEVI short f2b(float f) {
  union { float f; unsigned u; } v; v.f = f;
  unsigned u = v.u;
  u += 0x7FFFu + ((u >> 16) & 1u);   // RNE
  return (short)(u >> 16);
}
// fast GELU: tanh form, exp-based; overflow-safe. err ~4e-4 max, ~1e-5 here.
DEVI float gelu_f(float x) {
  float z2 = 1.5957691216f * x * (1.0f + 0.044715f * x * x);
  float e = __expf(z2);
  float th = 1.0f - 2.0f / (e + 1.0f);
  return 0.5f * x * (1.0f + th);
}
DEVI float sigm_f(float x) { return 1.0f / (1.0f + expf(-x)); }

// async global->LDS, 16B per lane; LDS dest = wave-uniform base + lane*16
DEVI void gld16(const short* g, const short* l) {
  __builtin_amdgcn_global_load_lds((const __attribute__((address_space(1))) void*)g,
                                   (__attribute__((address_space(3))) void*)l, 16, 0, 0);
}

// ---------------------------------------------------------------------------
// BM=256 bf16 GEMM + piggybacked pool1 (blocks >= nblk).
// ---------------------------------------------------------------------------
template<bool BIAS, bool OUT_BF16>
__global__ __launch_bounds__(512)
void gemm256pool_k(const short* __restrict__ A, const short* __restrict__ B,
                   const float* __restrict__ bias, void* __restrict__ Cv,
                   int N, int K, int nblk,
                   const float* __restrict__ xfull, float* __restrict__ partial)
{
  const int t = threadIdx.x;
  if ((int)blockIdx.x >= nblk) {
    const int p = blockIdx.x - nblk;
    if (t < 384) {
      float s = 0.f;
      const float* xr = xfull + p * 32 * 384;
#pragma unroll 4
      for (int i = 0; i < 32; ++i) s += xr[i * 384 + t];
      partial[p * 384 + t] = s;
    }
    return;
  }
  __shared__ short As[2][256 * 32];
  __shared__ short Bs[2][128 * 32];
  const int n0 = blockIdx.x * 128;
  const int lane = t & 63, wave = t >> 6;
  const int wm = wave >> 1, wn = wave & 1;
  const int lr = lane >> 2;
  const int lc = (lane & 3) * 8;
  const int fr = lane & 15, fs = lane >> 4;

  f32x4 acc[4][4];
#pragma unroll
  for (int i = 0; i < 4; ++i)
#pragma unroll
    for (int j = 0; j < 4; ++j) acc[i][j] = f32x4{0.f, 0.f, 0.f, 0.f};

  auto stage = [&](int b, int k0) {
#pragma unroll
    for (int q = 0; q < 2; ++q)
      gld16(A + (long long)(q * 128 + wave * 16 + lr) * K + k0 + lc,
            &As[b][(q * 128 + wave * 16) * 32]);
    gld16(B + (long long)(n0 + wave * 16 + lr) * K + k0 + lc,
          &Bs[b][wave * 16 * 32]);
  };

  const int NT = K >> 5;
  stage(0, 0);
  __syncthreads();
  for (int tt = 0; tt < NT; ++tt) {
    const int cur = tt & 1;
    if (tt + 1 < NT) stage(cur ^ 1, (tt + 1) << 5);
    s16x8 af[4], bfv[4];
#pragma unroll
    for (int i = 0; i < 4; ++i) af[i]  = *(const s16x8*)&As[cur][(wm * 64 + i * 16 + fr) * 32 + fs * 8];
#pragma unroll
    for (int j = 0; j < 4; ++j) bfv[j] = *(const s16x8*)&Bs[cur][(wn * 64 + j * 16 + fr) * 32 + fs * 8];
#pragma unroll
    for (int i = 0; i < 4; ++i)
#pragma unroll
      for (int j = 0; j < 4; ++j)
        acc[i][j] = __builtin_amdgcn_mfma_f32_16x16x32_bf16(af[i], bfv[j], acc[i][j], 0, 0, 0);
    if (tt + 1 < NT) __syncthreads();
  }

#pragma unroll
  for (int i = 0; i < 4; ++i) {
    int rowb = wm * 64 + i * 16 + fs * 4;
#pragma unroll
    for (int j = 0; j < 4; ++j) {
      int col = n0 + wn * 64 + j * 16 + fr;
      float bb = BIAS ? bias[col] : 0.0f;
#pragma unroll
      for (int u = 0; u < 4; ++u) {
        float v = acc[i][j][u] + bb;
        long long off = (long long)(rowb + u) * N + col;
        if constexpr (OUT_BF16) ((short*)Cv)[off] = f2b(v);
        else                    ((float*)Cv)[off] = v;
      }
    }
  }
}

// ---------------------------------------------------------------------------
// BM=256 bf16 GEMM (batched, for inter). 512 thr, BK=32.
// ---------------------------------------------------------------------------
template<bool BIAS, bool OUT_BF16>
__global__ __launch_bounds__(512)
void gemm256_k(const short* __restrict__ A, const short* __restrict__ B,
               const float* __restrict__ bias, void* __restrict__ Cv,
               int N, int K,
               long long sA, long long sB, long long sC)
{
  __shared__ short As[2][256 * 32];
  __shared__ short Bs[2][128 * 32];
  const int bz = blockIdx.z;
  const int n0 = blockIdx.x * 128;
  const int t = threadIdx.x, lane = t & 63, wave = t >> 6;
  const int wm = wave >> 1, wn = wave & 1;
  const short* Ab = A + bz * sA;
  const short* Bb = B + bz * sB;
  const int lr = lane >> 2;
  const int lc = (lane & 3) * 8;
  const int fr = lane & 15, fs = lane >> 4;

  f32x4 acc[4][4];
#pragma unroll
  for (int i = 0; i < 4; ++i)
#pragma unroll
    for (int j = 0; j < 4; ++j) acc[i][j] = f32x4{0.f, 0.f, 0.f, 0.f};

  auto stage = [&](int b, int k0) {
#pragma unroll
    for (int q = 0; q < 2; ++q)
      gld16(Ab + (long long)(q * 128 + wave * 16 + lr) * K + k0 + lc,
            &As[b][(q * 128 + wave * 16) * 32]);
    gld16(Bb + (long long)(n0 + wave * 16 + lr) * K + k0 + lc,
          &Bs[b][wave * 16 * 32]);
  };

  const int NT = K >> 5;
  stage(0, 0);
  __syncthreads();
  for (int tt = 0; tt < NT; ++tt) {
    const int cur = tt & 1;
    if (tt + 1 < NT) stage(cur ^ 1, (tt + 1) << 5);
    s16x8 af[4], bfv[4];
#pragma unroll
    for (int i = 0; i < 4; ++i) af[i]  = *(const s16x8*)&As[cur][(wm * 64 + i * 16 + fr) * 32 + fs * 8];
#pragma unroll
    for (int j = 0; j < 4; ++j) bfv[j] = *(const s16x8*)&Bs[cur][(wn * 64 + j * 16 + fr) * 32 + fs * 8];
#pragma unroll
    for (int i = 0; i < 4; ++i)
#pragma unroll
      for (int j = 0; j < 4; ++j)
        acc[i][j] = __builtin_amdgcn_mfma_f32_16x16x32_bf16(af[i], bfv[j], acc[i][j], 0, 0, 0);
    if (tt + 1 < NT) __syncthreads();
  }

#pragma unroll
  for (int i = 0; i < 4; ++i) {
    int rowb = wm * 64 + i * 16 + fs * 4;
#pragma unroll
    for (int j = 0; j < 4; ++j) {
      int col = n0 + wn * 64 + j * 16 + fr;
      float bb = BIAS ? bias[col] : 0.0f;
#pragma unroll
      for (int u = 0; u < 4; ++u) {
        float v = acc[i][j][u] + bb;
        long long off = bz * sC + (long long)(rowb + u) * N + col;
        if constexpr (OUT_BF16) ((short*)Cv)[off] = f2b(v);
        else                    ((float*)Cv)[off] = v;
      }
    }
  }
}

// ---------------------------------------------------------------------------
// Fused h1+logits (blocks 0..255, BK=64 swizzled) + piggybacked gih
// (blocks 256..399).
// ---------------------------------------------------------------------------
__global__ __launch_bounds__(512)
void h1log256_k(const short* __restrict__ inter, const short* __restrict__ Wc1b,
                const float* __restrict__ bc1, const float* __restrict__ Wc2,
                const float* __restrict__ bc2, float* __restrict__ outp,
                const float* __restrict__ Wih, const float* __restrict__ bih,
                const float* __restrict__ Whh, const float* __restrict__ bhh,
                const float* __restrict__ partial, const float* __restrict__ rs0,
                float* __restrict__ gi, float* __restrict__ gh)
{
  const int t = threadIdx.x, lane = t & 63, wave = t >> 6;
  if ((int)blockIdx.x >= 256) {
    const int r = (blockIdx.x - 256) * 8 + wave;   // 0..1151
    float a = 0.f, b = 0.f;
#pragma unroll
    for (int e = 0; e < 6; ++e) {
      int c = lane + 64 * e;
      float pc = 0.f;
#pragma unroll
      for (int p = 0; p < 8; ++p) pc += partial[p * 384 + c];
      pc *= (1.f / 256.f);
      a += Wih[r * 384 + c] * pc;
      b += Whh[r * 384 + c] * rs0[c];
    }
#pragma unroll
    for (int m = 1; m < 64; m <<= 1) { a += __shfl_xor(a, m); b += __shfl_xor(b, m); }
    if (lane == 0) { gi[r] = a + bih[r]; gh[r] = b + bhh[r]; }
    return;
  }
  __shared__ short As[2][256 * 64];
  __shared__ short Bs[2][128 * 64];
  __shared__ float part[256][2];
  const int ib = blockIdx.x;
  const int wm = wave >> 1, wn = wave & 1;
  const short* Ab = inter + (long long)ib * 98304;
  const int srow = lane >> 3;
  const int scol = ((lane & 7) ^ srow) * 8;
  const int fr = lane & 15, fs = lane >> 4;

  float lp[16];
#pragma unroll
  for (int e = 0; e < 16; ++e) lp[e] = 0.f;

  for (int n0 = 0; n0 < 384; n0 += 128) {
    f32x4 acc[4][4];
#pragma unroll
    for (int i = 0; i < 4; ++i)
#pragma unroll
      for (int j = 0; j < 4; ++j) acc[i][j] = f32x4{0.f, 0.f, 0.f, 0.f};

    auto stage = [&](int b, int k0) {
#pragma unroll
      for (int q = 0; q < 4; ++q) {
        int c = wave * 4 + q;
        gld16(Ab + (long long)(c * 8 + srow) * 384 + k0 + scol, &As[b][c * 512]);
      }
#pragma unroll
      for (int q = 0; q < 2; ++q) {
        int c = wave * 2 + q;
        gld16(Wc1b + (long long)(n0 + c * 8 + srow) * 384 + k0 + scol, &Bs[b][c * 512]);
      }
    };

    stage(0, 0);
    __syncthreads();
    for (int tt = 0; tt < 6; ++tt) {
      const int cur = tt & 1;
      if (tt + 1 < 6) stage(cur ^ 1, (tt + 1) << 6);
      s16x8 af[4][2], bfv[4][2];
#pragma unroll
      for (int i = 0; i < 4; ++i) {
        int row = wm * 64 + i * 16 + fr;
#pragma unroll
        for (int s = 0; s < 2; ++s)
          af[i][s] = *(const s16x8*)&As[cur][row * 64 + (((s * 4 + fs) ^ (fr & 7)) * 8)];
      }
#pragma unroll
      for (int j = 0; j < 4; ++j) {
        int row = wn * 64 + j * 16 + fr;
#pragma unroll
        for (int s = 0; s < 2; ++s)
          bfv[j][s] = *(const s16x8*)&Bs[cur][row * 64 + (((s * 4 + fs) ^ (fr & 7)) * 8)];
      }
#pragma unroll
      for (int s = 0; s < 2; ++s)
#pragma unroll
        for (int i = 0; i < 4; ++i)
#pragma unroll
          for (int j = 0; j < 4; ++j)
            acc[i][j] = __builtin_amdgcn_mfma_f32_16x16x32_bf16(af[i][s], bfv[j][s], acc[i][j], 0, 0, 0);
      __syncthreads();
    }
#pragma unroll
    for (int i = 0; i < 4; ++i)
#pragma unroll
      for (int j = 0; j < 4; ++j) {
        int col = n0 + wn * 64 + j * 16 + fr;
        float w2 = Wc2[col], b1v = bc1[col];
#pragma unroll
        for (int u = 0; u < 4; ++u)
          lp[i * 4 + u] += gelu_f(acc[i][j][u] + b1v) * w2;
      }
  }
#pragma unroll
  for (int m = 1; m < 16; m <<= 1)
#pragma unroll
    for (int e = 0; e < 16; ++e) lp[e] += __shfl_xor(lp[e], m);
  if (fr == 0) {
#pragma unroll
    for (int e = 0; e < 16; ++e)
      part[wm * 64 + (e >> 2) * 16 + fs * 4 + (e & 3)][wn] = lp[e];
  }
  __syncthreads();
  if (t < 256) outp[ib * 256 + t] = sigm_f(part[t][0] + part[t][1] + bc2[0]);
}

// ---------------------------------------------------------------------------
// 64x64-tile bf16 GEMM, BK=64, XOR-swizzled LDS. Optional cont-finish role:
// block (0,0) reduces contp[0..95] + bias -> sigmoid -> outc BEFORE its GEMM.
// ---------------------------------------------------------------------------
template<bool BIAS, bool GELU_ACT, bool OUT_BF16>
__global__ __launch_bounds__(256)
void gemm64_k(const short* __restrict__ A, const short* __restrict__ B,
              const float* __restrict__ bias, void* __restrict__ Cv,
              int M, int N, int K,
              const float* __restrict__ contp, const float* __restrict__ bp2c,
              float* __restrict__ outc)
{
  const int t = threadIdx.x;
  if (outc != nullptr && blockIdx.x == 0 && blockIdx.y == 0 && t < 64) {
    float a = 0.f;
    if (t < 32) a = contp[t] + contp[t + 32] + contp[t + 64];
#pragma unroll
    for (int m = 1; m < 32; m <<= 1) a += __shfl_xor(a, m);
    if (t == 0) outc[0] = sigm_f(a + bp2c[0]);
  }
  __shared__ short As[2][64 * 64];
  __shared__ short Bs[2][64 * 64];
  const int n0 = blockIdx.x * 64;
  const int m0 = blockIdx.y * 64;
  const int lane = t & 63, wave = t >> 6;
  const int wm = wave >> 1, wn = wave & 1;
  const int srow = lane >> 3;
  const int scol = ((lane & 7) ^ srow) * 8;
  const int fr = lane & 15, fs = lane >> 4;

  f32x4 acc[2][2];
#pragma unroll
  for (int i = 0; i < 2; ++i)
#pragma unroll
    for (int j = 0; j < 2; ++j) acc[i][j] = f32x4{0.f, 0.f, 0.f, 0.f};

  auto stage = [&](int b, int k0) {
#pragma unroll
    for (int q = 0; q < 2; ++q) {
      int c = wave * 2 + q;
      gld16(A + (long long)(m0 + c * 8 + srow) * K + k0 + scol, &As[b][c * 512]);
      gld16(B + (long long)(n0 + c * 8 + srow) * K + k0 + scol, &Bs[b][c * 512]);
    }
  };

  const int NT = K >> 6;
  stage(0, 0);
  __syncthreads();
  for (int tt = 0; tt < NT; ++tt) {
    const int cur = tt & 1;
    if (tt + 1 < NT) stage(cur ^ 1, (tt + 1) << 6);
    s16x8 af[2][2], bfv[2][2];
#pragma unroll
    for (int i = 0; i < 2; ++i) {
      int row = wm * 32 + i * 16 + fr;
#pragma unroll
      for (int s = 0; s < 2; ++s)
        af[i][s] = *(const s16x8*)&As[cur][row * 64 + (((s * 4 + fs) ^ (fr & 7)) * 8)];
    }
#pragma unroll
    for (int j = 0; j < 2; ++j) {
      int row = wn * 32 + j * 16 + fr;
#pragma unroll
      for (int s = 0; s < 2; ++s)
        bfv[j][s] = *(const s16x8*)&Bs[cur][row * 64 + (((s * 4 + fs) ^ (fr & 7)) * 8)];
    }
#pragma unroll
    for (int s = 0; s < 2; ++s)
#pragma unroll
      for (int i = 0; i < 2; ++i)
#pragma unroll
        for (int j = 0; j < 2; ++j)
          acc[i][j] = __builtin_amdgcn_mfma_f32_16x16x32_bf16(af[i][s], bfv[j][s], acc[i][j], 0, 0, 0);
    if (tt + 1 < NT) __syncthreads();
  }

#pragma unroll
  for (int i = 0; i < 2; ++i) {
    int rowb = m0 + wm * 32 + i * 16 + fs * 4;
#pragma unroll
    for (int j = 0; j < 2; ++j) {
      int col = n0 + wn * 32 + j * 16 + fr;
      float bb = BIAS ? bias[col] : 0.0f;
#pragma unroll
      for (int u = 0; u < 4; ++u) {
        float v = acc[i][j][u] + bb;
        if constexpr (GELU_ACT) v = gelu_f(v);
        long long off = (long long)(rowb + u) * N + col;
        if constexpr (OUT_BF16) ((short*)Cv)[off] = f2b(v);
        else                    ((float*)Cv)[off] = v;
      }
    }
  }
}

// ---------------------------------------------------------------------------
// ONE-TIME PREP, single launch: transpose (13824 blk) + convall (3744 blk)
// + init (384 blk). All roles read only inputs, write disjoint ws buffers.
// ---------------------------------------------------------------------------
__global__ __launch_bounds__(256)
void prep_k(const float* __restrict__ Wbil, short* __restrict__ WT,
            const float* __restrict__ Wc1, const float* __restrict__ Wqkv,
            const float* __restrict__ Wo, const float* __restrict__ W1,
            const float* __restrict__ W2, const float* __restrict__ Wout,
            short* __restrict__ Dc1, short* __restrict__ Dqkv,
            short* __restrict__ Do, short* __restrict__ D1,
            short* __restrict__ D2, short* __restrict__ Dout,
            const float* __restrict__ hs, float* __restrict__ x,
            short* __restrict__ xb, float* __restrict__ rstate)
{
  const int b = blockIdx.x, t = threadIdx.x;
  if (b < 13824) {
    // transpose role: Wbil [o][x][y] -> WT [o][y][x] bf16, 64x64 tiles
    __shared__ short L[64 * 68];
    const int o  = b / 36, rem = b - o * 36;
    const int x0 = (rem / 6) * 64, y0 = (rem - (rem / 6) * 6) * 64;
    const float* Wo_ = Wbil + (long long)o * 147456;
    short*      WTo  = WT   + (long long)o * 147456;
    const int rr = t >> 4;
    const int cc = (t & 15) * 4;
#pragma unroll
    for (int q = 0; q < 4; ++q) {
      int xl = rr + 16 * q;
      float4 v = *(const float4*)(Wo_ + (x0 + xl) * 384 + y0 + cc);
      short4 p; p.x = f2b(v.x); p.y = f2b(v.y); p.z = f2b(v.z); p.w = f2b(v.w);
      *(short4*)&L[xl * 68 + cc] = p;
    }
    __syncthreads();
#pragma unroll
    for (int q = 0; q < 4; ++q) {
      int yl = rr + 16 * q;
      short4 p;
      p.x = L[(cc + 0) * 68 + yl];
      p.y = L[(cc + 1) * 68 + yl];
      p.z = L[(cc + 2) * 68 + yl];
      p.w = L[(cc + 3) * 68 + yl];
      *(short4*)(WTo + (y0 + yl) * 384 + x0 + cc) = p;
    }
    return;
  }
  if (b < 13824 + 3744) {
    long long i4 = ((long long)(b - 13824) * 256 + t) * 4;
    const float* s; short* d; long long off;
    if      (i4 <  147456) { s = Wc1;  d = Dc1;  off = 0; }
    else if (i4 < 1032192) { s = Wqkv; d = Dqkv; off = 147456; }
    else if (i4 < 1327104) { s = Wo;   d = Do;   off = 1032192; }
    else if (i4 < 2506752) { s = W1;   d = D1;   off = 1327104; }
    else if (i4 < 3686400) { s = W2;   d = D2;   off = 2506752; }
    else if (i4 < 3833856) { s = Wout; d = Dout; off = 3686400; }
    else return;
    long long l = i4 - off;
    float4 v = *(const float4*)(s + l);
    short4 p; p.x = f2b(v.x); p.y = f2b(v.y); p.z = f2b(v.z); p.w = f2b(v.w);
    *(short4*)(d + l) = p;
    return;
  }
  // init role
  int i = (b - 13824 - 3744) * 256 + t;
  if (i < 98304) { float v = hs[i]; x[i] = v; xb[i] = f2b(v); }
  if (i < 768) rstate[i] = 0.f;
}

// ---------------------------------------------------------------------------
// Attention: qkv fp32 [256][1152] -> out bf16 [256][384]. d=48, NH=8.
// ---------------------------------------------------------------------------
__global__ __launch_bounds__(256)
void attn_k(const float* __restrict__ qkv, short* __restrict__ outb)
{
  __shared__ short Ks[256 * 48];
  __shared__ short Vs[256 * 48];
  __shared__ float Ps[32][258];
  const int h  = blockIdx.y;
  const int q0 = blockIdx.x * 32;
  const int t = threadIdx.x, lane = t & 63, wave = t >> 6;
  for (int idx = t; idx < 3072; idx += 256) {
    int j = idx / 12, d4 = (idx - (idx / 12) * 12) * 4;
    const float* base = qkv + j * 1152 + h * 48 + d4;
    float4 kv = *(const float4*)(base + 384);
    float4 vv = *(const float4*)(base + 768);
    short4 pk; pk.x = f2b(kv.x); pk.y = f2b(kv.y); pk.z = f2b(kv.z); pk.w = f2b(kv.w);
    short4 pv; pv.x = f2b(vv.x); pv.y = f2b(vv.y); pv.z = f2b(vv.z); pv.w = f2b(vv.w);
    *(short4*)&Ks[j * 48 + d4] = pk;
    *(short4*)&Vs[j * 48 + d4] = pv;
  }
  __syncthreads();
  const int part = lane & 7;
  const int rl   = wave * 8 + (lane >> 3);
  const int row  = q0 + rl;
  float q[48];
#pragma unroll
  for (int d = 0; d < 48; ++d) q[d] = qkv[row * 1152 + h * 48 + d] * 0.14433756729740644f;
  float mx = -1e30f;
  for (int jj = 0; jj < 32; ++jj) {
    int j = jj * 8 + part;
    float a = 0.f;
#pragma unroll
    for (int dd = 0; dd < 12; ++dd) {
      short4 kk = *(const short4*)&Ks[j * 48 + dd * 4];
      a += q[dd*4+0]*b2f(kk.x) + q[dd*4+1]*b2f(kk.y) + q[dd*4+2]*b2f(kk.z) + q[dd*4+3]*b2f(kk.w);
    }
    Ps[rl][j] = a;
    mx = fmaxf(mx, a);
  }
  mx = fmaxf(mx, __shfl_xor(mx, 1));
  mx = fmaxf(mx, __shfl_xor(mx, 2));
  mx = fmaxf(mx, __shfl_xor(mx, 4));
  float sum = 0.f;
  for (int jj = 0; jj < 32; ++jj) {
    int j = jj * 8 + part;
    float e = expf(Ps[rl][j] - mx);
    Ps[rl][j] = e;
    sum += e;
  }
  sum += __shfl_xor(sum, 1); sum += __shfl_xor(sum, 2); sum += __shfl_xor(sum, 4);
  const float inv = 1.f / sum;
  __syncthreads();
  float o[6] = {0.f, 0.f, 0.f, 0.f, 0.f, 0.f};
  const int vb = part * 6;
  for (int j = 0; j < 256; ++j) {
    float p = Ps[rl][j];
    int base = j * 48 + vb;
#pragma unroll
    for (int dd = 0; dd < 3; ++dd) {
      short2 vv = *(const short2*)&Vs[base + dd * 2];
      o[dd*2]   += p * b2f(vv.x);
      o[dd*2+1] += p * b2f(vv.y);
    }
  }
#pragma unroll
  for (int d = 0; d < 6; ++d) outb[row * 384 + h * 48 + vb + d] = f2b(o[d] * inv);
}

// ---------------------------------------------------------------------------
// LayerNorm(x + delta_bf16)*g + b  -> xo fp32, xob bf16.  256 blocks x 128 thr.
// ---------------------------------------------------------------------------
__global__ __launch_bounds__(128)
void ln_k(const float* __restrict__ x, const short* __restrict__ d,
          const float* __restrict__ g, const float* __restrict__ b,
          float* __restrict__ xo, short* __restrict__ xob)
{
  const int row = blockIdx.x, t = threadIdx.x;
  float v[3]; float s = 0.f, ss = 0.f;
#pragma unroll
  for (int i = 0; i < 3; ++i) {
    int c = t + 128 * i;
    float u = x[row * 384 + c] + b2f(d[row * 384 + c]);
    v[i] = u; s += u; ss += u * u;
  }
#pragma unroll
  for (int m = 1; m < 64; m <<= 1) { s += __shfl_xor(s, m); ss += __shfl_xor(ss, m); }
  __shared__ float sh[4];
  if ((t & 63) == 0) { sh[(t >> 6) * 2] = s; sh[(t >> 6) * 2 + 1] = ss; }
  __syncthreads();
  s = sh[0] + sh[2]; ss = sh[1] + sh[3];
  float mean = s * (1.f / 384.f);
  float var  = ss * (1.f / 384.f) - mean * mean;
  float rstd = rsqrtf(var + 1e-5f);
#pragma unroll
  for (int i = 0; i < 3; ++i) {
    int c = t + 128 * i;
    float y = (v[i] - mean) * rstd * g[c] + b[c];
    xo[row * 384 + c]  = y;
    xob[row * 384 + c] = f2b(y);
  }
}

// ---------------------------------------------------------------------------
// p1m: merged GRU gates + p1 + cont partials. Block recomputes hnew in LDS;
// wave computes p1 row; contp[blk] = sum over block's 4 rows of p1*Wp2.
// Block 0 writes rs1.
// ---------------------------------------------------------------------------
__global__ __launch_bounds__(256)
void p1m_k(const float* __restrict__ gi, const float* __restrict__ gh,
           const float* __restrict__ rs0, float* __restrict__ rs1,
           const float* __restrict__ Wp1, const float* __restrict__ bp1,
           const float* __restrict__ Wp2, float* __restrict__ contp)
{
  __shared__ float hn[384];
  __shared__ float cpart[4];
  const int t = threadIdx.x, lane = t & 63, wave = t >> 6;
  for (int c = t; c < 384; c += 256) {
    float r = sigm_f(gi[c] + gh[c]);
    float z = sigm_f(gi[384 + c] + gh[384 + c]);
    float n = tanhf(gi[768 + c] + r * gh[768 + c]);
    hn[c] = (1.f - z) * n + z * rs0[c];
  }
  __syncthreads();
  const int r = blockIdx.x * 4 + wave;
  float a = 0.f;
#pragma unroll
  for (int e = 0; e < 6; ++e) { int c = lane + 64 * e; a += Wp1[r * 384 + c] * hn[c]; }
#pragma unroll
  for (int m = 1; m < 64; m <<= 1) a += __shfl_xor(a, m);
  if (lane == 0) cpart[wave] = gelu_f(a + bp1[r]) * Wp2[r];
  __syncthreads();
  if (t == 0) contp[blockIdx.x] = cpart[0] + cpart[1] + cpart[2] + cpart[3];
  if (blockIdx.x == 0)
    for (int c = t; c < 384; c += 256) rs1[c] = hn[c];
}

// ---------------------------------------------------------------------------
extern "C" void kernel_launch(void* const* d_in, const int* in_sizes, int n_in,
                              void* d_out, int out_size, void* d_ws, size_t ws_size,
                              hipStream_t stream)
{
  const float* hs   = (const float*)d_in[0];
  const float* Wqkv = (const float*)d_in[1];
  const float* bqkv = (const float*)d_in[2];
  const float* Wo   = (const float*)d_in[3];
  const float* bo   = (const float*)d_in[4];
  const float* W1   = (const float*)d_in[5];
  const float* b1   = (const float*)d_in[6];
  const float* W2   = (const float*)d_in[7];
  const float* b2   = (const float*)d_in[8];
  const float* g1   = (const float*)d_in[9];
  const float* be1  = (const float*)d_in[10];
  const float* g2   = (const float*)d_in[11];
  const float* be2  = (const float*)d_in[12];
  const float* Wbil = (const float*)d_in[13];
  const float* bbil = (const float*)d_in[14];
  const float* Wc1  = (const float*)d_in[15];
  const float* bc1  = (const float*)d_in[16];
  const float* Wc2  = (const float*)d_in[17];
  const float* bc2  = (const float*)d_in[18];
  const float* Wih  = (const float*)d_in[19];
  const float* bih  = (const float*)d_in[20];
  const float* Whh  = (const float*)d_in[21];
  const float* bhh  = (const float*)d_in[22];
  const float* Wp1  = (const float*)d_in[23];
  const float* bp1  = (const float*)d_in[24];
  const float* Wp2  = (const float*)d_in[25];
  const float* bp2  = (const float*)d_in[26];
  const float* Wout = (const float*)d_in[27];
  const float* bout = (const float*)d_in[28];
  float* out = (float*)d_out;

  char* ws = (char*)d_ws;
  size_t off = 0;
  auto alloc = [&](size_t bytes) -> char* {
    char* p = ws + off; off += (bytes + 255) & ~(size_t)255; return p;
  };
  short* wbilT   = (short*)alloc(56623104ULL * 2);
  short* tmp     = (short*)alloc(256ULL * 147456 * 2);
  short* inter   = (short*)alloc(256ULL * 98304 * 2);
  float* x       = (float*)alloc(98304 * 4);
  short* xb      = (short*)alloc(98304 * 2);
  float* qkv     = (float*)alloc(294912 * 4);
  short* attnb   = (short*)alloc(98304 * 2);
  short* deltab  = (short*)alloc(98304 * 2);
  short* ff1b    = (short*)alloc(393216 * 2);
  float* rstate  = (float*)alloc(768 * 4);      // ping-pong pair
  float* partial = (float*)alloc(8 * 384 * 4);
  float* gi      = (float*)alloc(1152 * 4);
  float* gh      = (float*)alloc(1152 * 4);
  float* contp   = (float*)alloc(96 * 4);
  short* wc1b    = (short*)alloc(147456 * 2);
  short* wqkvb   = (short*)alloc(884736ULL * 2);
  short* wob     = (short*)alloc(294912ULL * 2);
  short* w1b     = (short*)alloc(1179648ULL * 2);
  short* w2b     = (short*)alloc(1179648ULL * 2);
  short* woutb   = (short*)alloc(147456 * 2);
  (void)ws_size; (void)in_sizes; (void)n_in; (void)out_size;

  dim3 B256(256);
  dim3 B512(512);
  const float* NF = nullptr;

  // one-time prep: transpose + weight conversion + init, co-launched
  prep_k<<<dim3(13824 + 3744 + 384), B256, 0, stream>>>(
      Wbil, wbilT, Wc1, Wqkv, Wo, W1, W2, Wout,
      wc1b, wqkvb, wob, w1b, w2b, woutb, hs, x, xb, rstate);

  for (int s = 0; s < 2; ++s) {
    float* rs0 = rstate + (s & 1) * 384;
    float* rs1 = rstate + ((s + 1) & 1) * 384;
    for (int l = 0; l < 2; ++l) {
      // step-1 layer-0 qkv launch also finishes step-0's cont reduce
      const float* cp = (s == 1 && l == 0) ? contp : NF;
      float* oc = (s == 1 && l == 0) ? (out + 98304 + 131072 + 0) : nullptr;
      gemm64_k<true, false, false><<<dim3(18, 4), B256, 0, stream>>>(
          xb, wqkvb + l * 442368, bqkv + l * 1152, qkv, 256, 1152, 384,
          cp, bp2, oc);
      attn_k<<<dim3(8, 8), B256, 0, stream>>>(qkv, attnb);
      gemm64_k<true, false, true><<<dim3(6, 4), B256, 0, stream>>>(
          attnb, wob + l * 147456, bo + l * 384, deltab, 256, 384, 384,
          NF, NF, nullptr);
      ln_k<<<dim3(256), dim3(128), 0, stream>>>(x, deltab, g1 + l * 384, be1 + l * 384, x, xb);
      gemm64_k<true, true, true><<<dim3(24, 4), B256, 0, stream>>>(
          xb, w1b + l * 589824, b1 + l * 1536, ff1b, 256, 1536, 384,
          NF, NF, nullptr);
      gemm64_k<true, false, true><<<dim3(6, 4), B256, 0, stream>>>(
          ff1b, w2b + l * 589824, b2 + l * 384, deltab, 256, 384, 1536,
          NF, NF, nullptr);
      ln_k<<<dim3(256), dim3(128), 0, stream>>>(x, deltab, g2 + l * 384, be2 + l * 384, x, xb);
    }
    // tmp GEMM (1152 blocks) + piggybacked pool1 (8 blocks)
    gemm256pool_k<false, true><<<dim3(1160), B512, 0, stream>>>(
        xb, wbilT, NF, tmp, 147456, 384, 1152, x, partial);
    // inter[i][j][o] = sum_y X[j,y] * tmp_i[o,y] + bbil[o]
    gemm256_k<true, true><<<dim3(3, 1, 256), B512, 0, stream>>>(
        xb, tmp, bbil, inter, 384, 384, 0, 147456LL, 98304LL);
    // fused h1 + logits (256 blocks) + piggybacked gih (144 blocks)
    h1log256_k<<<dim3(400), B512, 0, stream>>>(inter, wc1b, bc1, Wc2, bc2,
                                               out + 98304 + s * 65536,
                                               Wih, bih, Whh, bhh, partial, rs0, gi, gh);
    // merged GRU gates + p1 + cont partials
    p1m_k<<<dim3(96), B256, 0, stream>>>(gi, gh, rs0, rs1, Wp1, bp1, Wp2, contp);
  }
  // final GEMM also finishes step-1's cont reduce
  gemm64_k<true, false, false><<<dim3(6, 4), B256, 0, stream>>>(
      xb, woutb, bout, out, 256, 384, 384,
      contp, bp2, out + 98304 + 131072 + 1);
}